// Round 1
// baseline (638.084 us; speedup 1.0000x reference)
//
#include <hip/hip_runtime.h>
#include <math.h>

#define NPTS 4096
#define NEPS 4.096e-4f                 // 4096 * 1e-7
#define E2   7.3890560989306495f       // exp(2)
#define E2M1 6.3890560989306495f       // exp(2) - 1

// ---------------------------------------------------------------------------
// GEMM: C[4096][N] = A[4096][K] @ W[N][K]^T  (+bias [+extras]) [+relu]
// 64x64 tile, BK=16, 256 threads, 4x4 micro-tile per thread.
// ---------------------------------------------------------------------------
template<bool EXTRAS, bool RELU>
__global__ __launch_bounds__(256) void gemm_xwt(
    const float* __restrict__ A, int lda,
    const float* __restrict__ W, int ldw,
    const float* __restrict__ bias,
    float* __restrict__ C, int ldc,
    int K,
    const float* __restrict__ del, const float* __restrict__ Wd,
    const float* __restrict__ bd,
    const float* __restrict__ sc,  const float* __restrict__ Wsc,
    const float* __restrict__ bs)
{
    __shared__ __align__(16) float As[16][64];
    __shared__ __align__(16) float Bs[16][64];
    const int tid  = threadIdx.x;
    const int tx   = tid & 15, ty = tid >> 4;
    const int row0 = blockIdx.y * 64;
    const int col0 = blockIdx.x * 64;
    const int lrow = tid >> 2;          // 0..63
    const int lk   = (tid & 3) << 2;    // 0,4,8,12

    float acc[4][4] = {};
    const float* Ap = A + (size_t)(row0 + lrow) * lda + lk;
    const float* Wp = W + (size_t)(col0 + lrow) * ldw + lk;

    for (int k0 = 0; k0 < K; k0 += 16) {
        const float4 av = *(const float4*)(Ap + k0);
        const float4 wv = *(const float4*)(Wp + k0);
        __syncthreads();
        As[lk+0][lrow]=av.x; As[lk+1][lrow]=av.y; As[lk+2][lrow]=av.z; As[lk+3][lrow]=av.w;
        Bs[lk+0][lrow]=wv.x; Bs[lk+1][lrow]=wv.y; Bs[lk+2][lrow]=wv.z; Bs[lk+3][lrow]=wv.w;
        __syncthreads();
#pragma unroll
        for (int kk = 0; kk < 16; ++kk) {
            const float4 a4 = *(const float4*)&As[kk][ty << 2];
            const float4 w4 = *(const float4*)&Bs[kk][tx << 2];
            const float avv[4] = {a4.x, a4.y, a4.z, a4.w};
            const float wvv[4] = {w4.x, w4.y, w4.z, w4.w};
#pragma unroll
            for (int i = 0; i < 4; ++i)
#pragma unroll
                for (int j = 0; j < 4; ++j)
                    acc[i][j] = fmaf(avv[i], wvv[j], acc[i][j]);
        }
    }

    const int cb = col0 + (tx << 2);
    const int rb = row0 + (ty << 2);
    float badd[4], wd_[4][4], wsc_[4];
#pragma unroll
    for (int j = 0; j < 4; ++j) {
        const int n = cb + j;
        if (EXTRAS) {
            badd[j] = bias[n] + bd[n] + bs[n];
            const float4 w4 = *(const float4*)&Wd[n * 4];
            wd_[j][0]=w4.x; wd_[j][1]=w4.y; wd_[j][2]=w4.z; wd_[j][3]=w4.w;
            wsc_[j] = Wsc[n];
        } else {
            badd[j] = bias[n];
        }
    }
#pragma unroll
    for (int i = 0; i < 4; ++i) {
        const int m = rb + i;
        float add[4];
        if (EXTRAS) {
            const float4 dm = *(const float4*)&del[m * 4];
            const float scm = sc[m];
#pragma unroll
            for (int j = 0; j < 4; ++j)
                add[j] = badd[j] + dm.x*wd_[j][0] + dm.y*wd_[j][1]
                       + dm.z*wd_[j][2] + dm.w*wd_[j][3] + scm*wsc_[j];
        } else {
#pragma unroll
            for (int j = 0; j < 4; ++j) add[j] = badd[j];
        }
        float4 v;
        v.x = acc[i][0] + add[0];
        v.y = acc[i][1] + add[1];
        v.z = acc[i][2] + add[2];
        v.w = acc[i][3] + add[3];
        if (RELU) {
            v.x = fmaxf(v.x, 0.f); v.y = fmaxf(v.y, 0.f);
            v.z = fmaxf(v.z, 0.f); v.w = fmaxf(v.w, 0.f);
        }
        *(float4*)&C[(size_t)m * ldc + cb] = v;
    }
}

// ---------------------------------------------------------------------------
// Per-row: logits = (h @ W2^T + b2)/temp ; softmax -> alphas[row][8]
// one wave (64 threads) per row
// ---------------------------------------------------------------------------
__global__ __launch_bounds__(64) void alphas_kernel(
    const float* __restrict__ Hm, int Hd,
    const float* __restrict__ W2, const float* __restrict__ b2,
    const int* __restrict__ iter_ptr, float* __restrict__ Aout)
{
    const int row = blockIdx.x;
    const int l = threadIdx.x;
    float acc[8] = {};
    for (int m = l; m < Hd; m += 64) {
        const float hv = Hm[(size_t)row * Hd + m];
#pragma unroll
        for (int o = 0; o < 8; ++o)
            acc[o] = fmaf(W2[o * Hd + m], hv, acc[o]);
    }
#pragma unroll
    for (int o = 0; o < 8; ++o)
        for (int off = 32; off; off >>= 1)
            acc[o] += __shfl_xor(acc[o], off, 64);

    const int it = *iter_ptr;
    const float temp = fmaxf(1.0f, 30.0f * (float)(90000 - it) / 90000.0f);
    float lg[8], mx = -1e30f;
#pragma unroll
    for (int o = 0; o < 8; ++o) { lg[o] = (acc[o] + b2[o]) / temp; mx = fmaxf(mx, lg[o]); }
    float s = 0.f;
#pragma unroll
    for (int o = 0; o < 8; ++o) { lg[o] = expf(lg[o] - mx); s += lg[o]; }
    if (l < 8) Aout[(size_t)row * 8 + l] = lg[l] / s;
}

// ---------------------------------------------------------------------------
// Small reductions: per-class sums/counts, totals, means -> out[0:184]
// block 0: rpn_cls (S,T,cnt + out[0:8]); block 1: roi_cls (S,T,cnt + out[16:176])
// block 2: rpn_bbox mean -> out[8:16];   block 3: roi_bbox mean -> out[176:184]
// ---------------------------------------------------------------------------
__global__ __launch_bounds__(256) void smalls_kernel(
    const float* __restrict__ A_rpn_c, const float* __restrict__ A_rpn_b,
    const float* __restrict__ A_roi_c, const float* __restrict__ A_roi_b,
    const int* __restrict__ rpn_class, const int* __restrict__ roi_class,
    float* __restrict__ S_rpn, float* __restrict__ T_rpn, float* __restrict__ c_rpn,
    float* __restrict__ S_roi, float* __restrict__ T_roi, float* __restrict__ c_roi,
    float* __restrict__ out)
{
    __shared__ float S[20][8];
    __shared__ float cnt[20];
    __shared__ float red[4][8];
    const int b = blockIdx.x, t = threadIdx.x;

    if (b < 2) {
        const float* A = b ? A_roi_c : A_rpn_c;
        const int* cls = b ? roi_class : rpn_class;
        if (t < 160) ((float*)S)[t] = 0.f;
        if (t < 20) cnt[t] = 0.f;
        __syncthreads();
        for (int r = t; r < NPTS; r += 256) {
            const int c = cls[r];
            atomicAdd(&cnt[c], 1.0f);
            const float4 v0 = *(const float4*)&A[(size_t)r * 8];
            const float4 v1 = *(const float4*)&A[(size_t)r * 8 + 4];
            atomicAdd(&S[c][0], v0.x); atomicAdd(&S[c][1], v0.y);
            atomicAdd(&S[c][2], v0.z); atomicAdd(&S[c][3], v0.w);
            atomicAdd(&S[c][4], v1.x); atomicAdd(&S[c][5], v1.y);
            atomicAdd(&S[c][6], v1.z); atomicAdd(&S[c][7], v1.w);
        }
        __syncthreads();
        float* Sg = b ? S_roi : S_rpn;
        float* Tg = b ? T_roi : T_rpn;
        float* cg = b ? c_roi : c_rpn;
        if (t < 160) Sg[t] = ((const float*)S)[t];
        if (t < 20) cg[t] = cnt[t];
        if (t < 8) {
            float s = 0.f;
            for (int c = 0; c < 20; ++c) s += S[c][t];
            Tg[t] = s;
            if (b == 0) out[t] = s * (1.f / 4096.f);
        }
        if (b == 1 && t < 160) {
            const int c = t >> 3;
            out[16 + t] = S[c][t & 7] / fmaxf(cnt[c], 1.f);
        }
    } else {
        const float* A = (b == 2) ? A_rpn_b : A_roi_b;
        float acc[8] = {};
        for (int r = t; r < NPTS; r += 256) {
            const float4 v0 = *(const float4*)&A[(size_t)r * 8];
            const float4 v1 = *(const float4*)&A[(size_t)r * 8 + 4];
            acc[0]+=v0.x; acc[1]+=v0.y; acc[2]+=v0.z; acc[3]+=v0.w;
            acc[4]+=v1.x; acc[5]+=v1.y; acc[6]+=v1.z; acc[7]+=v1.w;
        }
        const int lane = t & 63, w = t >> 6;
#pragma unroll
        for (int o = 0; o < 8; ++o) {
            float v = acc[o];
            for (int off = 32; off; off >>= 1) v += __shfl_xor(v, off, 64);
            if (lane == 0) red[w][o] = v;
        }
        __syncthreads();
        if (t < 8) {
            const float s = red[0][t] + red[1][t] + red[2][t] + red[3][t];
            out[((b == 2) ? 8 : 176) + t] = s * (1.f / 4096.f);
        }
    }
}

// ---------------------------------------------------------------------------
// cls loss: needs Sx[j] = sum_k exp(2*a_j.a_k); Sg/U from class counts & sums.
// block: 16 j's (4 j per thread-group of 64 lanes), streams all k.
// ---------------------------------------------------------------------------
__global__ __launch_bounds__(256) void cls_loss_kernel(
    const float* __restrict__ A, const int* __restrict__ cls,
    const float* __restrict__ S, const float* __restrict__ T,
    const float* __restrict__ cnt, float* __restrict__ out)
{
    const int t = threadIdx.x;
    const int j0 = blockIdx.x * 16;
    const int jg = t >> 6, lane = t & 63;
    float aj[4][8];
#pragma unroll
    for (int r = 0; r < 4; ++r) {
        const int j = j0 + jg * 4 + r;
        const float4 v0 = *(const float4*)&A[(size_t)j * 8];
        const float4 v1 = *(const float4*)&A[(size_t)j * 8 + 4];
        aj[r][0]=v0.x; aj[r][1]=v0.y; aj[r][2]=v0.z; aj[r][3]=v0.w;
        aj[r][4]=v1.x; aj[r][5]=v1.y; aj[r][6]=v1.z; aj[r][7]=v1.w;
    }
    float Sx[4] = {};
    for (int k = lane; k < NPTS; k += 64) {
        const float4 b0 = *(const float4*)&A[(size_t)k * 8];
        const float4 b1 = *(const float4*)&A[(size_t)k * 8 + 4];
#pragma unroll
        for (int r = 0; r < 4; ++r) {
            const float d = aj[r][0]*b0.x + aj[r][1]*b0.y + aj[r][2]*b0.z + aj[r][3]*b0.w
                          + aj[r][4]*b1.x + aj[r][5]*b1.y + aj[r][6]*b1.z + aj[r][7]*b1.w;
            Sx[r] += expf(2.f * d);
        }
    }
    __shared__ float SxL[16];
#pragma unroll
    for (int r = 0; r < 4; ++r) {
        float v = Sx[r];
        for (int off = 32; off; off >>= 1) v += __shfl_xor(v, off, 64);
        if (lane == 0) SxL[jg * 4 + r] = v;
    }
    __syncthreads();
    __shared__ float lsum[16];
    if (t < 16) {
        const int j = j0 + t;
        const float Sxj = SxL[t] + NEPS;
        const int c = cls[j];
        const float m = cnt[c];
        const float Sg = (4096.f - m) + m * E2 + NEPS;
        const float Cg = Sg - NEPS;
        const float4 a0 = *(const float4*)&A[(size_t)j * 8];
        const float4 a1 = *(const float4*)&A[(size_t)j * 8 + 4];
        const float av[8] = {a0.x,a0.y,a0.z,a0.w,a1.x,a1.y,a1.z,a1.w};
        float U = 0.f;
#pragma unroll
        for (int o = 0; o < 8; ++o)
            U += av[o] * (T[o] + E2M1 * S[c * 8 + o]);
        lsum[t] = (2.f * U - logf(Sxj) * Cg) / Sg;
    }
    __syncthreads();
    if (t == 0) {
        float s = 0.f;
        for (int i = 0; i < 16; ++i) s += lsum[i];
        atomicAdd(out, -s / 4096.f);
    }
}

// ---------------------------------------------------------------------------
// bbox loss: fused N^2 pass. Per (j,k): exp(2*a.a) for Sx; exp(2*d.d) for Sg;
// U += exp(2*d.d)*(a.a).  16 j per block, 4 j per thread.
// ---------------------------------------------------------------------------
__global__ __launch_bounds__(256) void bbox_loss_kernel(
    const float* __restrict__ A, const float* __restrict__ D, float* __restrict__ out)
{
    const int t = threadIdx.x;
    const int j0 = blockIdx.x * 16;
    const int jg = t >> 6, lane = t & 63;
    float aj[4][8], dj[4][4];
#pragma unroll
    for (int r = 0; r < 4; ++r) {
        const int j = j0 + jg * 4 + r;
        const float4 v0 = *(const float4*)&A[(size_t)j * 8];
        const float4 v1 = *(const float4*)&A[(size_t)j * 8 + 4];
        aj[r][0]=v0.x; aj[r][1]=v0.y; aj[r][2]=v0.z; aj[r][3]=v0.w;
        aj[r][4]=v1.x; aj[r][5]=v1.y; aj[r][6]=v1.z; aj[r][7]=v1.w;
        const float4 dv = *(const float4*)&D[(size_t)j * 4];
        dj[r][0]=dv.x; dj[r][1]=dv.y; dj[r][2]=dv.z; dj[r][3]=dv.w;
    }
    float Sx[4] = {}, Sg[4] = {}, U[4] = {};
    for (int k = lane; k < NPTS; k += 64) {
        const float4 b0 = *(const float4*)&A[(size_t)k * 8];
        const float4 b1 = *(const float4*)&A[(size_t)k * 8 + 4];
        const float4 dk = *(const float4*)&D[(size_t)k * 4];
#pragma unroll
        for (int r = 0; r < 4; ++r) {
            const float aa = aj[r][0]*b0.x + aj[r][1]*b0.y + aj[r][2]*b0.z + aj[r][3]*b0.w
                           + aj[r][4]*b1.x + aj[r][5]*b1.y + aj[r][6]*b1.z + aj[r][7]*b1.w;
            const float dd = dj[r][0]*dk.x + dj[r][1]*dk.y + dj[r][2]*dk.z + dj[r][3]*dk.w;
            const float ex = expf(2.f * aa);
            const float ed = expf(2.f * dd);
            Sx[r] += ex;
            Sg[r] += ed;
            U[r] = fmaf(ed, aa, U[r]);
        }
    }
    __shared__ float red[16][3];
#pragma unroll
    for (int r = 0; r < 4; ++r) {
        float vx = Sx[r], vg = Sg[r], vu = U[r];
        for (int off = 32; off; off >>= 1) {
            vx += __shfl_xor(vx, off, 64);
            vg += __shfl_xor(vg, off, 64);
            vu += __shfl_xor(vu, off, 64);
        }
        if (lane == 0) { red[jg*4+r][0] = vx; red[jg*4+r][1] = vg; red[jg*4+r][2] = vu; }
    }
    __syncthreads();
    __shared__ float lsum[16];
    if (t < 16) {
        const float Sxf = red[t][0] + NEPS;
        const float SgS = red[t][1];          // Cg = colsum = rowsum (symmetric gt)
        const float Sgf = SgS + NEPS;
        const float Uj  = red[t][2];
        lsum[t] = (2.f * Uj - logf(Sxf) * SgS) / Sgf;
    }
    __syncthreads();
    if (t == 0) {
        float s = 0.f;
        for (int i = 0; i < 16; ++i) s += lsum[i];
        atomicAdd(out, -s / 4096.f);
    }
}

__global__ void zero_loss_kernel(float* __restrict__ out)
{
    if (threadIdx.x < 4) out[184 + threadIdx.x] = 0.f;
}

// ---------------------------------------------------------------------------
extern "C" void kernel_launch(void* const* d_in, const int* in_sizes, int n_in,
                              void* d_out, int out_size, void* d_ws, size_t ws_size,
                              hipStream_t stream)
{
    const float* rpn_feat  = (const float*)d_in[0];
    const float* rpn_del   = (const float*)d_in[1];
    const float* rpn_scale = (const float*)d_in[2];
    const float* roi_feat  = (const float*)d_in[3];
    const float* roi_del   = (const float*)d_in[4];
    const float* roi_scale = (const float*)d_in[5];
    const int*   rpn_class = (const int*)d_in[6];
    const int*   roi_class = (const int*)d_in[7];
    const float* W_rpn_feat = (const float*)d_in[8];  const float* b_rpn_feat = (const float*)d_in[9];
    const float* W_rpn_del  = (const float*)d_in[10]; const float* b_rpn_del  = (const float*)d_in[11];
    const float* W_rpn_sc   = (const float*)d_in[12]; const float* b_rpn_sc   = (const float*)d_in[13];
    const float* W_roi_feat = (const float*)d_in[14]; const float* b_roi_feat = (const float*)d_in[15];
    const float* W_roi_del  = (const float*)d_in[16]; const float* b_roi_del  = (const float*)d_in[17];
    const float* W_roi_sc   = (const float*)d_in[18]; const float* b_roi_sc   = (const float*)d_in[19];
    const float* rpn_cls_W1  = (const float*)d_in[20]; const float* rpn_cls_b1  = (const float*)d_in[21];
    const float* rpn_cls_W2  = (const float*)d_in[22]; const float* rpn_cls_b2  = (const float*)d_in[23];
    const float* rpn_bbox_W1 = (const float*)d_in[24]; const float* rpn_bbox_b1 = (const float*)d_in[25];
    const float* rpn_bbox_W2 = (const float*)d_in[26]; const float* rpn_bbox_b2 = (const float*)d_in[27];
    const float* roi_cls_W1  = (const float*)d_in[28]; const float* roi_cls_b1  = (const float*)d_in[29];
    const float* roi_cls_W2  = (const float*)d_in[30]; const float* roi_cls_b2  = (const float*)d_in[31];
    const int* iter_ptr = (const int*)d_in[32];
    float* out = (float*)d_out;
    float* ws  = (float*)d_ws;

    // workspace layout (floats)
    float* rpn_sum = ws + 0;                 // 4096*512   (region reused later)
    float* roi_sum = ws + 2097152;           // 4096*2048
    float* h_rpn_c = ws + 10485760;          // 4096*64
    float* h_rpn_b = ws + 10747904;          // 4096*64
    float* A_rpn_c = ws + 11010048;          // 4096*8
    float* A_rpn_b = ws + 11042816;
    float* A_roi_c = ws + 11075584;
    float* A_roi_b = ws + 11108352;
    float* S_rpn   = ws + 11141120;          // [20][8]
    float* T_rpn   = S_rpn + 160;            // [8]
    float* c_rpn   = T_rpn + 8;              // [20]
    float* S_roi   = c_rpn + 20;             // [20][8]
    float* T_roi   = S_roi + 160;
    float* c_roi   = T_roi + 8;
    // rpn_sum region reused for roi hidden activations (rpn path done by then)
    float* h_roi_c = ws + 0;                 // 4096*256
    float* h_roi_b = ws + 1048576;           // 4096*256

    zero_loss_kernel<<<dim3(1), dim3(64), 0, stream>>>(out);

    // ---- RPN path ----
    gemm_xwt<true, false><<<dim3(8, 64), 256, 0, stream>>>(
        rpn_feat, 256, W_rpn_feat, 256, b_rpn_feat, rpn_sum, 512, 256,
        rpn_del, W_rpn_del, b_rpn_del, rpn_scale, W_rpn_sc, b_rpn_sc);
    gemm_xwt<false, true><<<dim3(1, 64), 256, 0, stream>>>(
        rpn_sum, 512, rpn_cls_W1, 256, rpn_cls_b1, h_rpn_c, 64, 256,
        nullptr, nullptr, nullptr, nullptr, nullptr, nullptr);
    gemm_xwt<false, true><<<dim3(1, 64), 256, 0, stream>>>(
        rpn_sum + 256, 512, rpn_bbox_W1, 256, rpn_bbox_b1, h_rpn_b, 64, 256,
        nullptr, nullptr, nullptr, nullptr, nullptr, nullptr);
    alphas_kernel<<<dim3(4096), dim3(64), 0, stream>>>(h_rpn_c, 64, rpn_cls_W2,  rpn_cls_b2,  iter_ptr, A_rpn_c);
    alphas_kernel<<<dim3(4096), dim3(64), 0, stream>>>(h_rpn_b, 64, rpn_bbox_W2, rpn_bbox_b2, iter_ptr, A_rpn_b);

    // ---- ROI path ----
    gemm_xwt<true, false><<<dim3(32, 64), 256, 0, stream>>>(
        roi_feat, 1024, W_roi_feat, 1024, b_roi_feat, roi_sum, 2048, 1024,
        roi_del, W_roi_del, b_roi_del, roi_scale, W_roi_sc, b_roi_sc);
    gemm_xwt<false, true><<<dim3(4, 64), 256, 0, stream>>>(
        roi_sum, 2048, roi_cls_W1, 1024, roi_cls_b1, h_roi_c, 256, 1024,
        nullptr, nullptr, nullptr, nullptr, nullptr, nullptr);
    // NOTE: reference bug — bbox half also uses roi_cls_W1/b1 (and W2/b2 below)
    gemm_xwt<false, true><<<dim3(4, 64), 256, 0, stream>>>(
        roi_sum + 1024, 2048, roi_cls_W1, 1024, roi_cls_b1, h_roi_b, 256, 1024,
        nullptr, nullptr, nullptr, nullptr, nullptr, nullptr);
    alphas_kernel<<<dim3(4096), dim3(64), 0, stream>>>(h_roi_c, 256, roi_cls_W2, roi_cls_b2, iter_ptr, A_roi_c);
    alphas_kernel<<<dim3(4096), dim3(64), 0, stream>>>(h_roi_b, 256, roi_cls_W2, roi_cls_b2, iter_ptr, A_roi_b);

    // ---- small reductions / direct outputs ----
    smalls_kernel<<<dim3(4), dim3(256), 0, stream>>>(
        A_rpn_c, A_rpn_b, A_roi_c, A_roi_b, rpn_class, roi_class,
        S_rpn, T_rpn, c_rpn, S_roi, T_roi, c_roi, out);

    // ---- losses ----
    cls_loss_kernel<<<dim3(256), dim3(256), 0, stream>>>(A_roi_c, roi_class, S_roi, T_roi, c_roi, out + 184);
    cls_loss_kernel<<<dim3(256), dim3(256), 0, stream>>>(A_rpn_c, rpn_class, S_rpn, T_rpn, c_rpn, out + 185);
    bbox_loss_kernel<<<dim3(256), dim3(256), 0, stream>>>(A_roi_b, roi_del, out + 186);
    bbox_loss_kernel<<<dim3(256), dim3(256), 0, stream>>>(A_rpn_b, rpn_del, out + 187);
}

// Round 2
// 398.303 us; speedup vs baseline: 1.6020x; 1.6020x over previous
//
#include <hip/hip_runtime.h>
#include <math.h>

#define NPTS 4096
#define NEPS 4.096e-4f                 // 4096 * 1e-7
#define E2   7.3890560989306495f       // exp(2)
#define E2M1 6.3890560989306495f       // exp(2) - 1

typedef float  f32x4 __attribute__((ext_vector_type(4)));
typedef short  s16x8 __attribute__((ext_vector_type(8)));

static __device__ __forceinline__ unsigned short f2b(float x) {
    unsigned u = __builtin_bit_cast(unsigned, x);
    return (unsigned short)((u + 0x7fffu + ((u >> 16) & 1u)) >> 16);
}
static __device__ __forceinline__ float b2f(unsigned short h) {
    return __builtin_bit_cast(float, (unsigned)h << 16);
}

// ---------------------------------------------------------------------------
// f32 -> bf16 convert (n multiple of 1024; grid = n/1024, 256 thr, 4 elem/thr)
// ---------------------------------------------------------------------------
__global__ __launch_bounds__(256) void cvt_bf16(
    const float* __restrict__ in, unsigned short* __restrict__ out)
{
    const int i = (blockIdx.x * 256 + threadIdx.x) * 4;
    const float4 v = *(const float4*)&in[i];
    ushort4 o;
    o.x = f2b(v.x); o.y = f2b(v.y); o.z = f2b(v.z); o.w = f2b(v.w);
    *(ushort4*)&out[i] = o;
}

// pad rpn W1 (64x256 f32) -> (128x256 bf16, rows 64..127 = 0); bias 64 -> 128
__global__ __launch_bounds__(256) void pad_w1(
    const float* __restrict__ W, const float* __restrict__ b,
    unsigned short* __restrict__ Wout, float* __restrict__ bout)
{
    const int i = blockIdx.x * 256 + threadIdx.x;   // grid 128 -> 32768
    const int r = i >> 8, c = i & 255;
    Wout[i] = (r < 64) ? f2b(W[r * 256 + c]) : (unsigned short)0;
    if (blockIdx.x == 0 && threadIdx.x < 128)
        bout[threadIdx.x] = (threadIdx.x < 64) ? b[threadIdx.x] : 0.f;
}

// ---------------------------------------------------------------------------
// MFMA GEMM: C[M][N](bf16) = A[M][K](bf16) @ W[N][K]^T(bf16) + bias [+extras][relu]
// 128x128 tile, BK=32, 256 thr (4 waves as 2x2 of 64x64), 16x16x32 bf16 MFMA.
// ---------------------------------------------------------------------------
template<bool EXTRAS, bool RELU>
__global__ __launch_bounds__(256) void gemm_mfma(
    const unsigned short* __restrict__ A, int lda,
    const unsigned short* __restrict__ W, int ldw,
    const float* __restrict__ bias,
    unsigned short* __restrict__ C, int ldc, int K,
    const float* __restrict__ del, const float* __restrict__ Wd,
    const float* __restrict__ bd,
    const float* __restrict__ sc,  const float* __restrict__ Wsc,
    const float* __restrict__ bs)
{
    __shared__ __align__(16) unsigned short As[128 * 32];
    __shared__ __align__(16) unsigned short Bs[128 * 32];
    const int t = threadIdx.x;
    const int l = t & 63, w = t >> 6;
    const int wr = w >> 1, wc = w & 1;
    const int row0 = blockIdx.y * 128, col0 = blockIdx.x * 128;

    // staging: thread t covers rows (t>>2) and (t>>2)+64, col-group (t&3)*8
    const int srow = t >> 2;
    const int scol = (t & 3) * 8;
    const unsigned short* Ap0 = A + (size_t)(row0 + srow) * lda + scol;
    const unsigned short* Ap1 = A + (size_t)(row0 + srow + 64) * lda + scol;
    const unsigned short* Wp0 = W + (size_t)(col0 + srow) * ldw + scol;
    const unsigned short* Wp1 = W + (size_t)(col0 + srow + 64) * ldw + scol;
    unsigned short* AsP0 = &As[srow * 32 + scol];
    unsigned short* AsP1 = &As[(srow + 64) * 32 + scol];
    unsigned short* BsP0 = &Bs[srow * 32 + scol];
    unsigned short* BsP1 = &Bs[(srow + 64) * 32 + scol];

    const int fr = l & 15, fq = l >> 4;
    const int koff = fq * 8;

    f32x4 acc[4][4] = {};

    for (int k0 = 0; k0 < K; k0 += 32) {
        const s16x8 a0 = *(const s16x8*)(Ap0 + k0);
        const s16x8 a1 = *(const s16x8*)(Ap1 + k0);
        const s16x8 b0 = *(const s16x8*)(Wp0 + k0);
        const s16x8 b1 = *(const s16x8*)(Wp1 + k0);
        __syncthreads();
        *(s16x8*)AsP0 = a0; *(s16x8*)AsP1 = a1;
        *(s16x8*)BsP0 = b0; *(s16x8*)BsP1 = b1;
        __syncthreads();
        s16x8 af[4], bf[4];
#pragma unroll
        for (int m = 0; m < 4; ++m)
            af[m] = *(const s16x8*)&As[(wr * 64 + m * 16 + fr) * 32 + koff];
#pragma unroll
        for (int n = 0; n < 4; ++n)
            bf[n] = *(const s16x8*)&Bs[(wc * 64 + n * 16 + fr) * 32 + koff];
#pragma unroll
        for (int m = 0; m < 4; ++m)
#pragma unroll
            for (int n = 0; n < 4; ++n)
                acc[m][n] = __builtin_amdgcn_mfma_f32_16x16x32_bf16(
                    af[m], bf[n], acc[m][n], 0, 0, 0);
    }

    // epilogue: row = row0+wr*64+m*16+fq*4+j ; col = col0+wc*64+n*16+fr
#pragma unroll
    for (int n = 0; n < 4; ++n) {
        const int col = col0 + wc * 64 + n * 16 + fr;
        float cadd = bias[col];
        float wd0 = 0.f, wd1 = 0.f, wd2 = 0.f, wd3 = 0.f, wscv = 0.f;
        if (EXTRAS) {
            cadd += bd[col] + bs[col];
            const float4 w4 = *(const float4*)&Wd[col * 4];
            wd0 = w4.x; wd1 = w4.y; wd2 = w4.z; wd3 = w4.w;
            wscv = Wsc[col];
        }
#pragma unroll
        for (int m = 0; m < 4; ++m) {
#pragma unroll
            for (int j = 0; j < 4; ++j) {
                const int row = row0 + wr * 64 + m * 16 + fq * 4 + j;
                float v = acc[m][n][j] + cadd;
                if (EXTRAS) {
                    const float4 dm = *(const float4*)&del[row * 4];
                    v += dm.x * wd0 + dm.y * wd1 + dm.z * wd2 + dm.w * wd3
                       + sc[row] * wscv;
                }
                if (RELU) v = fmaxf(v, 0.f);
                C[(size_t)row * ldc + col] = f2b(v);
            }
        }
    }
}

// ---------------------------------------------------------------------------
// Per-row: logits = (h @ W2^T + b2)/temp ; softmax -> alphas[row][8]
// one wave per row; h is bf16 with stride ldh, true width Hd
// ---------------------------------------------------------------------------
__global__ __launch_bounds__(64) void alphas_kernel(
    const unsigned short* __restrict__ Hm, int ldh, int Hd,
    const float* __restrict__ W2, const float* __restrict__ b2,
    const int* __restrict__ iter_ptr, float* __restrict__ Aout)
{
    const int row = blockIdx.x;
    const int l = threadIdx.x;
    float acc[8] = {};
    for (int m = l; m < Hd; m += 64) {
        const float hv = b2f(Hm[(size_t)row * ldh + m]);
#pragma unroll
        for (int o = 0; o < 8; ++o)
            acc[o] = fmaf(W2[o * Hd + m], hv, acc[o]);
    }
#pragma unroll
    for (int o = 0; o < 8; ++o)
        for (int off = 32; off; off >>= 1)
            acc[o] += __shfl_xor(acc[o], off, 64);

    const int it = *iter_ptr;
    const float temp = fmaxf(1.0f, 30.0f * (float)(90000 - it) / 90000.0f);
    float lg[8], mx = -1e30f;
#pragma unroll
    for (int o = 0; o < 8; ++o) { lg[o] = (acc[o] + b2[o]) / temp; mx = fmaxf(mx, lg[o]); }
    float s = 0.f;
#pragma unroll
    for (int o = 0; o < 8; ++o) { lg[o] = expf(lg[o] - mx); s += lg[o]; }
    if (l < 8) Aout[(size_t)row * 8 + l] = lg[l] / s;
}

// ---------------------------------------------------------------------------
// Small reductions (unchanged from R1)
// ---------------------------------------------------------------------------
__global__ __launch_bounds__(256) void smalls_kernel(
    const float* __restrict__ A_rpn_c, const float* __restrict__ A_rpn_b,
    const float* __restrict__ A_roi_c, const float* __restrict__ A_roi_b,
    const int* __restrict__ rpn_class, const int* __restrict__ roi_class,
    float* __restrict__ S_rpn, float* __restrict__ T_rpn, float* __restrict__ c_rpn,
    float* __restrict__ S_roi, float* __restrict__ T_roi, float* __restrict__ c_roi,
    float* __restrict__ out)
{
    __shared__ float S[20][8];
    __shared__ float cnt[20];
    __shared__ float red[4][8];
    const int b = blockIdx.x, t = threadIdx.x;

    if (b < 2) {
        const float* A = b ? A_roi_c : A_rpn_c;
        const int* cls = b ? roi_class : rpn_class;
        if (t < 160) ((float*)S)[t] = 0.f;
        if (t < 20) cnt[t] = 0.f;
        __syncthreads();
        for (int r = t; r < NPTS; r += 256) {
            const int c = cls[r];
            atomicAdd(&cnt[c], 1.0f);
            const float4 v0 = *(const float4*)&A[(size_t)r * 8];
            const float4 v1 = *(const float4*)&A[(size_t)r * 8 + 4];
            atomicAdd(&S[c][0], v0.x); atomicAdd(&S[c][1], v0.y);
            atomicAdd(&S[c][2], v0.z); atomicAdd(&S[c][3], v0.w);
            atomicAdd(&S[c][4], v1.x); atomicAdd(&S[c][5], v1.y);
            atomicAdd(&S[c][6], v1.z); atomicAdd(&S[c][7], v1.w);
        }
        __syncthreads();
        float* Sg = b ? S_roi : S_rpn;
        float* Tg = b ? T_roi : T_rpn;
        float* cg = b ? c_roi : c_rpn;
        if (t < 160) Sg[t] = ((const float*)S)[t];
        if (t < 20) cg[t] = cnt[t];
        if (t < 8) {
            float s = 0.f;
            for (int c = 0; c < 20; ++c) s += S[c][t];
            Tg[t] = s;
            if (b == 0) out[t] = s * (1.f / 4096.f);
        }
        if (b == 1 && t < 160) {
            const int c = t >> 3;
            out[16 + t] = S[c][t & 7] / fmaxf(cnt[c], 1.f);
        }
    } else {
        const float* A = (b == 2) ? A_rpn_b : A_roi_b;
        float acc[8] = {};
        for (int r = t; r < NPTS; r += 256) {
            const float4 v0 = *(const float4*)&A[(size_t)r * 8];
            const float4 v1 = *(const float4*)&A[(size_t)r * 8 + 4];
            acc[0]+=v0.x; acc[1]+=v0.y; acc[2]+=v0.z; acc[3]+=v0.w;
            acc[4]+=v1.x; acc[5]+=v1.y; acc[6]+=v1.z; acc[7]+=v1.w;
        }
        const int lane = t & 63, wv = t >> 6;
#pragma unroll
        for (int o = 0; o < 8; ++o) {
            float v = acc[o];
            for (int off = 32; off; off >>= 1) v += __shfl_xor(v, off, 64);
            if (lane == 0) red[wv][o] = v;
        }
        __syncthreads();
        if (t < 8) {
            const float s = red[0][t] + red[1][t] + red[2][t] + red[3][t];
            out[((b == 2) ? 8 : 176) + t] = s * (1.f / 4096.f);
        }
    }
}

// ---------------------------------------------------------------------------
// cls loss (unchanged from R1)
// ---------------------------------------------------------------------------
__global__ __launch_bounds__(256) void cls_loss_kernel(
    const float* __restrict__ A, const int* __restrict__ cls,
    const float* __restrict__ S, const float* __restrict__ T,
    const float* __restrict__ cnt, float* __restrict__ out)
{
    const int t = threadIdx.x;
    const int j0 = blockIdx.x * 16;
    const int jg = t >> 6, lane = t & 63;
    float aj[4][8];
#pragma unroll
    for (int r = 0; r < 4; ++r) {
        const int j = j0 + jg * 4 + r;
        const float4 v0 = *(const float4*)&A[(size_t)j * 8];
        const float4 v1 = *(const float4*)&A[(size_t)j * 8 + 4];
        aj[r][0]=v0.x; aj[r][1]=v0.y; aj[r][2]=v0.z; aj[r][3]=v0.w;
        aj[r][4]=v1.x; aj[r][5]=v1.y; aj[r][6]=v1.z; aj[r][7]=v1.w;
    }
    float Sx[4] = {};
    for (int k = lane; k < NPTS; k += 64) {
        const float4 b0 = *(const float4*)&A[(size_t)k * 8];
        const float4 b1 = *(const float4*)&A[(size_t)k * 8 + 4];
#pragma unroll
        for (int r = 0; r < 4; ++r) {
            const float d = aj[r][0]*b0.x + aj[r][1]*b0.y + aj[r][2]*b0.z + aj[r][3]*b0.w
                          + aj[r][4]*b1.x + aj[r][5]*b1.y + aj[r][6]*b1.z + aj[r][7]*b1.w;
            Sx[r] += expf(2.f * d);
        }
    }
    __shared__ float SxL[16];
#pragma unroll
    for (int r = 0; r < 4; ++r) {
        float v = Sx[r];
        for (int off = 32; off; off >>= 1) v += __shfl_xor(v, off, 64);
        if (lane == 0) SxL[jg * 4 + r] = v;
    }
    __syncthreads();
    __shared__ float lsum[16];
    if (t < 16) {
        const int j = j0 + t;
        const float Sxj = SxL[t] + NEPS;
        const int c = cls[j];
        const float m = cnt[c];
        const float Sg = (4096.f - m) + m * E2 + NEPS;
        const float Cg = Sg - NEPS;
        const float4 a0 = *(const float4*)&A[(size_t)j * 8];
        const float4 a1 = *(const float4*)&A[(size_t)j * 8 + 4];
        const float av[8] = {a0.x,a0.y,a0.z,a0.w,a1.x,a1.y,a1.z,a1.w};
        float U = 0.f;
#pragma unroll
        for (int o = 0; o < 8; ++o)
            U += av[o] * (T[o] + E2M1 * S[c * 8 + o]);
        lsum[t] = (2.f * U - logf(Sxj) * Cg) / Sg;
    }
    __syncthreads();
    if (t == 0) {
        float s = 0.f;
        for (int i = 0; i < 16; ++i) s += lsum[i];
        atomicAdd(out, -s / 4096.f);
    }
}

// ---------------------------------------------------------------------------
// bbox loss (unchanged from R1)
// ---------------------------------------------------------------------------
__global__ __launch_bounds__(256) void bbox_loss_kernel(
    const float* __restrict__ A, const float* __restrict__ D, float* __restrict__ out)
{
    const int t = threadIdx.x;
    const int j0 = blockIdx.x * 16;
    const int jg = t >> 6, lane = t & 63;
    float aj[4][8], dj[4][4];
#pragma unroll
    for (int r = 0; r < 4; ++r) {
        const int j = j0 + jg * 4 + r;
        const float4 v0 = *(const float4*)&A[(size_t)j * 8];
        const float4 v1 = *(const float4*)&A[(size_t)j * 8 + 4];
        aj[r][0]=v0.x; aj[r][1]=v0.y; aj[r][2]=v0.z; aj[r][3]=v0.w;
        aj[r][4]=v1.x; aj[r][5]=v1.y; aj[r][6]=v1.z; aj[r][7]=v1.w;
        const float4 dv = *(const float4*)&D[(size_t)j * 4];
        dj[r][0]=dv.x; dj[r][1]=dv.y; dj[r][2]=dv.z; dj[r][3]=dv.w;
    }
    float Sx[4] = {}, Sg[4] = {}, U[4] = {};
    for (int k = lane; k < NPTS; k += 64) {
        const float4 b0 = *(const float4*)&A[(size_t)k * 8];
        const float4 b1 = *(const float4*)&A[(size_t)k * 8 + 4];
        const float4 dk = *(const float4*)&D[(size_t)k * 4];
#pragma unroll
        for (int r = 0; r < 4; ++r) {
            const float aa = aj[r][0]*b0.x + aj[r][1]*b0.y + aj[r][2]*b0.z + aj[r][3]*b0.w
                           + aj[r][4]*b1.x + aj[r][5]*b1.y + aj[r][6]*b1.z + aj[r][7]*b1.w;
            const float dd = dj[r][0]*dk.x + dj[r][1]*dk.y + dj[r][2]*dk.z + dj[r][3]*dk.w;
            const float ex = expf(2.f * aa);
            const float ed = expf(2.f * dd);
            Sx[r] += ex;
            Sg[r] += ed;
            U[r] = fmaf(ed, aa, U[r]);
        }
    }
    __shared__ float red[16][3];
#pragma unroll
    for (int r = 0; r < 4; ++r) {
        float vx = Sx[r], vg = Sg[r], vu = U[r];
        for (int off = 32; off; off >>= 1) {
            vx += __shfl_xor(vx, off, 64);
            vg += __shfl_xor(vg, off, 64);
            vu += __shfl_xor(vu, off, 64);
        }
        if (lane == 0) { red[jg*4+r][0] = vx; red[jg*4+r][1] = vg; red[jg*4+r][2] = vu; }
    }
    __syncthreads();
    __shared__ float lsum[16];
    if (t < 16) {
        const float Sxf = red[t][0] + NEPS;
        const float SgS = red[t][1];
        const float Sgf = SgS + NEPS;
        const float Uj  = red[t][2];
        lsum[t] = (2.f * Uj - logf(Sxf) * SgS) / Sgf;
    }
    __syncthreads();
    if (t == 0) {
        float s = 0.f;
        for (int i = 0; i < 16; ++i) s += lsum[i];
        atomicAdd(out, -s / 4096.f);
    }
}

__global__ void zero_loss_kernel(float* __restrict__ out)
{
    if (threadIdx.x < 4) out[184 + threadIdx.x] = 0.f;
}

// ---------------------------------------------------------------------------
extern "C" void kernel_launch(void* const* d_in, const int* in_sizes, int n_in,
                              void* d_out, int out_size, void* d_ws, size_t ws_size,
                              hipStream_t stream)
{
    const float* rpn_feat  = (const float*)d_in[0];
    const float* rpn_del   = (const float*)d_in[1];
    const float* rpn_scale = (const float*)d_in[2];
    const float* roi_feat  = (const float*)d_in[3];
    const float* roi_del   = (const float*)d_in[4];
    const float* roi_scale = (const float*)d_in[5];
    const int*   rpn_class = (const int*)d_in[6];
    const int*   roi_class = (const int*)d_in[7];
    const float* W_rpn_feat = (const float*)d_in[8];  const float* b_rpn_feat = (const float*)d_in[9];
    const float* W_rpn_del  = (const float*)d_in[10]; const float* b_rpn_del  = (const float*)d_in[11];
    const float* W_rpn_sc   = (const float*)d_in[12]; const float* b_rpn_sc   = (const float*)d_in[13];
    const float* W_roi_feat = (const float*)d_in[14]; const float* b_roi_feat = (const float*)d_in[15];
    const float* W_roi_del  = (const float*)d_in[16]; const float* b_roi_del  = (const float*)d_in[17];
    const float* W_roi_sc   = (const float*)d_in[18]; const float* b_roi_sc   = (const float*)d_in[19];
    const float* rpn_cls_W1  = (const float*)d_in[20]; const float* rpn_cls_b1  = (const float*)d_in[21];
    const float* rpn_cls_W2  = (const float*)d_in[22]; const float* rpn_cls_b2  = (const float*)d_in[23];
    const float* rpn_bbox_W1 = (const float*)d_in[24]; const float* rpn_bbox_b1 = (const float*)d_in[25];
    const float* rpn_bbox_W2 = (const float*)d_in[26]; const float* rpn_bbox_b2 = (const float*)d_in[27];
    const float* roi_cls_W1  = (const float*)d_in[28]; const float* roi_cls_b1  = (const float*)d_in[29];
    const float* roi_cls_W2  = (const float*)d_in[30]; const float* roi_cls_b2  = (const float*)d_in[31];
    const int* iter_ptr = (const int*)d_in[32];
    float* out = (float*)d_out;
    char*  wsb = (char*)d_ws;

    // ---- workspace layout (byte offsets) ----
    unsigned short* roi_feat_b   = (unsigned short*)(wsb + 0);          // 4096x1024
    unsigned short* W_roi_feat_b = (unsigned short*)(wsb + 8388608);    // 2048x1024
    unsigned short* roi_sum_b    = (unsigned short*)(wsb + 12582912);   // 4096x2048
    unsigned short* roi_W1_b     = (unsigned short*)(wsb + 29360128);   // 256x1024
    unsigned short* h_roi_c      = (unsigned short*)(wsb + 29884416);   // 4096x256
    unsigned short* h_roi_b      = (unsigned short*)(wsb + 31981568);   // 4096x256
    unsigned short* rpn_feat_b   = (unsigned short*)(wsb + 34078720);   // 4096x256
    unsigned short* W_rpn_feat_b = (unsigned short*)(wsb + 36175872);   // 512x256
    unsigned short* rpn_sum_b    = (unsigned short*)(wsb + 36438016);   // 4096x512
    unsigned short* rpn_cW1_b    = (unsigned short*)(wsb + 40632320);   // 128x256 padded
    unsigned short* rpn_bW1_b    = (unsigned short*)(wsb + 40697856);   // 128x256 padded
    unsigned short* h_rpn_c      = (unsigned short*)(wsb + 40763392);   // 4096x128
    unsigned short* h_rpn_b      = (unsigned short*)(wsb + 41811968);   // 4096x128
    float* bias_pad_c = (float*)(wsb + 42860544);                       // 128
    float* bias_pad_b = (float*)(wsb + 42861056);                       // 128
    float* A_rpn_c    = (float*)(wsb + 42861568);                       // 4096x8
    float* A_rpn_b    = (float*)(wsb + 42992640);
    float* A_roi_c    = (float*)(wsb + 43123712);
    float* A_roi_b    = (float*)(wsb + 43254784);
    float* S_rpn      = (float*)(wsb + 43385856);   // [20][8]
    float* T_rpn = S_rpn + 160; float* c_rpn = T_rpn + 8;
    float* S_roi = c_rpn + 20;  float* T_roi = S_roi + 160; float* c_roi = T_roi + 8;

    zero_loss_kernel<<<dim3(1), dim3(64), 0, stream>>>(out);

    // ---- converts ----
    cvt_bf16<<<dim3(4096), 256, 0, stream>>>(roi_feat,   roi_feat_b);
    cvt_bf16<<<dim3(2048), 256, 0, stream>>>(W_roi_feat, W_roi_feat_b);
    cvt_bf16<<<dim3(256),  256, 0, stream>>>(roi_cls_W1, roi_W1_b);
    cvt_bf16<<<dim3(1024), 256, 0, stream>>>(rpn_feat,   rpn_feat_b);
    cvt_bf16<<<dim3(128),  256, 0, stream>>>(W_rpn_feat, W_rpn_feat_b);
    pad_w1<<<dim3(128), 256, 0, stream>>>(rpn_cls_W1,  rpn_cls_b1,  rpn_cW1_b, bias_pad_c);
    pad_w1<<<dim3(128), 256, 0, stream>>>(rpn_bbox_W1, rpn_bbox_b1, rpn_bW1_b, bias_pad_b);

    // ---- RPN path ----
    gemm_mfma<true, false><<<dim3(4, 32), 256, 0, stream>>>(
        rpn_feat_b, 256, W_rpn_feat_b, 256, b_rpn_feat, rpn_sum_b, 512, 256,
        rpn_del, W_rpn_del, b_rpn_del, rpn_scale, W_rpn_sc, b_rpn_sc);
    gemm_mfma<false, true><<<dim3(1, 32), 256, 0, stream>>>(
        rpn_sum_b, 512, rpn_cW1_b, 256, bias_pad_c, h_rpn_c, 128, 256,
        nullptr, nullptr, nullptr, nullptr, nullptr, nullptr);
    gemm_mfma<false, true><<<dim3(1, 32), 256, 0, stream>>>(
        rpn_sum_b + 256, 512, rpn_bW1_b, 256, bias_pad_b, h_rpn_b, 128, 256,
        nullptr, nullptr, nullptr, nullptr, nullptr, nullptr);
    alphas_kernel<<<dim3(4096), dim3(64), 0, stream>>>(h_rpn_c, 128, 64, rpn_cls_W2,  rpn_cls_b2,  iter_ptr, A_rpn_c);
    alphas_kernel<<<dim3(4096), dim3(64), 0, stream>>>(h_rpn_b, 128, 64, rpn_bbox_W2, rpn_bbox_b2, iter_ptr, A_rpn_b);

    // ---- ROI path ----
    gemm_mfma<true, false><<<dim3(16, 32), 256, 0, stream>>>(
        roi_feat_b, 1024, W_roi_feat_b, 1024, b_roi_feat, roi_sum_b, 2048, 1024,
        roi_del, W_roi_del, b_roi_del, roi_scale, W_roi_sc, b_roi_sc);
    gemm_mfma<false, true><<<dim3(2, 32), 256, 0, stream>>>(
        roi_sum_b, 2048, roi_W1_b, 1024, roi_cls_b1, h_roi_c, 256, 1024,
        nullptr, nullptr, nullptr, nullptr, nullptr, nullptr);
    // reference bug: bbox half also uses roi_cls_W1/b1 (and W2/b2 below)
    gemm_mfma<false, true><<<dim3(2, 32), 256, 0, stream>>>(
        roi_sum_b + 1024, 2048, roi_W1_b, 1024, roi_cls_b1, h_roi_b, 256, 1024,
        nullptr, nullptr, nullptr, nullptr, nullptr, nullptr);
    alphas_kernel<<<dim3(4096), dim3(64), 0, stream>>>(h_roi_c, 256, 256, roi_cls_W2, roi_cls_b2, iter_ptr, A_roi_c);
    alphas_kernel<<<dim3(4096), dim3(64), 0, stream>>>(h_roi_b, 256, 256, roi_cls_W2, roi_cls_b2, iter_ptr, A_roi_b);

    // ---- small reductions / direct outputs ----
    smalls_kernel<<<dim3(4), dim3(256), 0, stream>>>(
        A_rpn_c, A_rpn_b, A_roi_c, A_roi_b, rpn_class, roi_class,
        S_rpn, T_rpn, c_rpn, S_roi, T_roi, c_roi, out);

    // ---- losses ----
    cls_loss_kernel<<<dim3(256), dim3(256), 0, stream>>>(A_roi_c, roi_class, S_roi, T_roi, c_roi, out + 184);
    cls_loss_kernel<<<dim3(256), dim3(256), 0, stream>>>(A_rpn_c, rpn_class, S_rpn, T_rpn, c_rpn, out + 185);
    bbox_loss_kernel<<<dim3(256), dim3(256), 0, stream>>>(A_roi_b, roi_del, out + 186);
    bbox_loss_kernel<<<dim3(256), dim3(256), 0, stream>>>(A_rpn_b, rpn_del, out + 187);
}

// Round 3
// 345.592 us; speedup vs baseline: 1.8463x; 1.1525x over previous
//
#include <hip/hip_runtime.h>
#include <math.h>

#define NPTS 4096
#define NEPS 4.096e-4f                 // 4096 * 1e-7
#define E2   7.3890560989306495f       // exp(2)
#define E2M1 6.3890560989306495f       // exp(2) - 1

typedef float  f32x4 __attribute__((ext_vector_type(4)));
typedef short  s16x8 __attribute__((ext_vector_type(8)));

static __device__ __forceinline__ unsigned short f2b(float x) {
    unsigned u = __builtin_bit_cast(unsigned, x);
    return (unsigned short)((u + 0x7fffu + ((u >> 16) & 1u)) >> 16);
}
static __device__ __forceinline__ float b2f(unsigned short h) {
    return __builtin_bit_cast(float, (unsigned)h << 16);
}

static __device__ __forceinline__ void gload16(const unsigned short* g, unsigned short* lds) {
    __builtin_amdgcn_global_load_lds(
        (const __attribute__((address_space(1))) void*)g,
        (__attribute__((address_space(3))) void*)lds, 16, 0, 0);
}

// ---------------------------------------------------------------------------
// prep: all f32->bf16 converts + rpn W1 pads + bias pads + loss zero, 1 launch
// block = 1024 elements (256 thr x 4)
// ---------------------------------------------------------------------------
__global__ __launch_bounds__(256) void prep_kernel(
    const float* __restrict__ roi_feat, const float* __restrict__ W_roi_feat,
    const float* __restrict__ roi_cls_W1,
    const float* __restrict__ rpn_feat, const float* __restrict__ W_rpn_feat,
    const float* __restrict__ rpn_cls_W1, const float* __restrict__ rpn_bbox_W1,
    const float* __restrict__ rpn_cls_b1, const float* __restrict__ rpn_bbox_b1,
    unsigned short* __restrict__ roi_feat_b, unsigned short* __restrict__ W_roi_feat_b,
    unsigned short* __restrict__ roi_W1_b,
    unsigned short* __restrict__ rpn_feat_b, unsigned short* __restrict__ W_rpn_feat_b,
    unsigned short* __restrict__ rpn_cW1_b, unsigned short* __restrict__ rpn_bW1_b,
    float* __restrict__ bias_pad_c, float* __restrict__ bias_pad_b,
    float* __restrict__ out)
{
    const int b = blockIdx.x, t = threadIdx.x;
    if (b < 7552) {
        const float* in; unsigned short* o; int base;
        if      (b < 4096) { in = roi_feat;   o = roi_feat_b;   base = b; }
        else if (b < 6144) { in = W_roi_feat; o = W_roi_feat_b; base = b - 4096; }
        else if (b < 6400) { in = roi_cls_W1; o = roi_W1_b;     base = b - 6144; }
        else if (b < 7424) { in = rpn_feat;   o = rpn_feat_b;   base = b - 6400; }
        else               { in = W_rpn_feat; o = W_rpn_feat_b; base = b - 7424; }
        const int i = base * 1024 + t * 4;
        const float4 v = *(const float4*)&in[i];
        ushort4 ov;
        ov.x = f2b(v.x); ov.y = f2b(v.y); ov.z = f2b(v.z); ov.w = f2b(v.w);
        *(ushort4*)&o[i] = ov;
    } else if (b < 7616) {
        const bool cls = b < 7584;
        const float* W = cls ? rpn_cls_W1 : rpn_bbox_W1;
        unsigned short* o = cls ? rpn_cW1_b : rpn_bW1_b;
        const int local = b - (cls ? 7552 : 7584);
        const int i0 = local * 1024 + t * 4;
#pragma unroll
        for (int u = 0; u < 4; ++u) {
            const int i = i0 + u;
            const int r = i >> 8, c = i & 255;
            o[i] = (r < 64) ? f2b(W[r * 256 + c]) : (unsigned short)0;
        }
    } else {
        if (t < 128)      bias_pad_c[t] = (t < 64) ? rpn_cls_b1[t] : 0.f;
        else              bias_pad_b[t - 128] = ((t - 128) < 64) ? rpn_bbox_b1[t - 128] : 0.f;
        if (t < 4) out[184 + t] = 0.f;
    }
}

// ---------------------------------------------------------------------------
// MFMA GEMM, m97-style: 128x128 tile, BK=32, global_load_lds 16B, linear LDS.
// grid.z selects parameter set (for fused dual GEMM launches).
// C written bf16. Optional fused extras (deltas/scale) and ReLU.
// ---------------------------------------------------------------------------
template<bool EXTRAS, bool RELU>
__global__ __launch_bounds__(256) void gemm_mfma(
    const unsigned short* __restrict__ A0, const unsigned short* __restrict__ A1, int lda,
    const unsigned short* __restrict__ W0, const unsigned short* __restrict__ W1x, int ldw,
    const float* __restrict__ bias0, const float* __restrict__ bias1,
    unsigned short* __restrict__ C0, unsigned short* __restrict__ C1, int ldc, int K,
    const float* __restrict__ del, const float* __restrict__ Wd,
    const float* __restrict__ bd,
    const float* __restrict__ sc,  const float* __restrict__ Wsc,
    const float* __restrict__ bs)
{
    const unsigned short* A = blockIdx.z ? A1 : A0;
    const unsigned short* W = blockIdx.z ? W1x : W0;
    const float* bias = blockIdx.z ? bias1 : bias0;
    unsigned short* C = blockIdx.z ? C1 : C0;

    __shared__ __align__(16) unsigned short As[128 * 32];
    __shared__ __align__(16) unsigned short Bs[128 * 32];
    const int t = threadIdx.x;
    const int l = t & 63, w = t >> 6;
    const int wr = w >> 1, wc = w & 1;
    const int row0 = blockIdx.y * 128, col0 = blockIdx.x * 128;

    // staging: 512 chunks of 16B per tile; wave w covers [w*128, w*128+128)
    const int ch0 = w * 128 + l, ch1 = ch0 + 64;
    const int ar0 = ch0 >> 2, ac0 = (ch0 & 3) * 8;
    const int ar1 = ch1 >> 2, ac1 = (ch1 & 3) * 8;
    const unsigned short* gA0 = A + (size_t)(row0 + ar0) * lda + ac0;
    const unsigned short* gA1 = A + (size_t)(row0 + ar1) * lda + ac1;
    const unsigned short* gW0 = W + (size_t)(col0 + ar0) * ldw + ac0;
    const unsigned short* gW1 = W + (size_t)(col0 + ar1) * ldw + ac1;
    unsigned short* lA0 = As + w * 1024;         // wave-uniform LDS bases
    unsigned short* lA1 = As + w * 1024 + 512;
    unsigned short* lB0 = Bs + w * 1024;
    unsigned short* lB1 = Bs + w * 1024 + 512;

    const int fr = l & 15, fq = l >> 4;
    const int koff = fq * 8;

    f32x4 acc[4][4] = {};

    for (int k0 = 0; k0 < K; k0 += 32) {
        __syncthreads();                     // prev-iter LDS reads complete
        gload16(gA0 + k0, lA0);
        gload16(gA1 + k0, lA1);
        gload16(gW0 + k0, lB0);
        gload16(gW1 + k0, lB1);
        __syncthreads();                     // vmcnt(0) drain + barrier
        s16x8 af[4], bf[4];
#pragma unroll
        for (int m = 0; m < 4; ++m)
            af[m] = *(const s16x8*)&As[(wr * 64 + m * 16 + fr) * 32 + koff];
#pragma unroll
        for (int n = 0; n < 4; ++n)
            bf[n] = *(const s16x8*)&Bs[(wc * 64 + n * 16 + fr) * 32 + koff];
#pragma unroll
        for (int m = 0; m < 4; ++m)
#pragma unroll
            for (int n = 0; n < 4; ++n)
                acc[m][n] = __builtin_amdgcn_mfma_f32_16x16x32_bf16(
                    af[m], bf[n], acc[m][n], 0, 0, 0);
    }

    // epilogue: row = row0+wr*64+m*16+fq*4+j ; col = col0+wc*64+n*16+fr
#pragma unroll
    for (int n = 0; n < 4; ++n) {
        const int col = col0 + wc * 64 + n * 16 + fr;
        float cadd = bias[col];
        float wd0 = 0.f, wd1 = 0.f, wd2 = 0.f, wd3 = 0.f, wscv = 0.f;
        if (EXTRAS) {
            cadd += bd[col] + bs[col];
            const float4 w4 = *(const float4*)&Wd[col * 4];
            wd0 = w4.x; wd1 = w4.y; wd2 = w4.z; wd3 = w4.w;
            wscv = Wsc[col];
        }
#pragma unroll
        for (int m = 0; m < 4; ++m) {
#pragma unroll
            for (int j = 0; j < 4; ++j) {
                const int row = row0 + wr * 64 + m * 16 + fq * 4 + j;
                float v = acc[m][n][j] + cadd;
                if (EXTRAS) {
                    const float4 dm = *(const float4*)&del[row * 4];
                    v += dm.x * wd0 + dm.y * wd1 + dm.z * wd2 + dm.w * wd3
                       + sc[row] * wscv;
                }
                if (RELU) v = fmaxf(v, 0.f);
                C[(size_t)row * ldc + col] = f2b(v);
            }
        }
    }
}

// ---------------------------------------------------------------------------
// alphas (fused pair): grid(1024, 2); 256 thr = 4 rows, one wave per row.
// logits = (h @ W2^T + b2)/temp ; softmax -> alphas[row][8]
// ---------------------------------------------------------------------------
__global__ __launch_bounds__(256) void alphas2_kernel(
    const unsigned short* __restrict__ H0, const unsigned short* __restrict__ H1,
    int ldh, int Hd,
    const float* __restrict__ W2a, const float* __restrict__ W2b,
    const float* __restrict__ b2a, const float* __restrict__ b2b,
    const int* __restrict__ iter_ptr,
    float* __restrict__ Out0, float* __restrict__ Out1)
{
    const int y = blockIdx.y;
    const unsigned short* Hm = y ? H1 : H0;
    const float* W2 = y ? W2b : W2a;
    const float* b2 = y ? b2b : b2a;
    float* Aout = y ? Out1 : Out0;

    const int row = blockIdx.x * 4 + (threadIdx.x >> 6);
    const int l = threadIdx.x & 63;
    float acc[8] = {};
    for (int m = l; m < Hd; m += 64) {
        const float hv = b2f(Hm[(size_t)row * ldh + m]);
#pragma unroll
        for (int o = 0; o < 8; ++o)
            acc[o] = fmaf(W2[o * Hd + m], hv, acc[o]);
    }
#pragma unroll
    for (int o = 0; o < 8; ++o)
        for (int off = 32; off; off >>= 1)
            acc[o] += __shfl_xor(acc[o], off, 64);

    const int it = *iter_ptr;
    const float temp = fmaxf(1.0f, 30.0f * (float)(90000 - it) / 90000.0f);
    float lg[8], mx = -1e30f;
#pragma unroll
    for (int o = 0; o < 8; ++o) { lg[o] = (acc[o] + b2[o]) / temp; mx = fmaxf(mx, lg[o]); }
    float s = 0.f;
#pragma unroll
    for (int o = 0; o < 8; ++o) { lg[o] = expf(lg[o] - mx); s += lg[o]; }
    if (l < 8) Aout[(size_t)row * 8 + l] = lg[l] / s;
}

// ---------------------------------------------------------------------------
// Small reductions
// ---------------------------------------------------------------------------
__global__ __launch_bounds__(256) void smalls_kernel(
    const float* __restrict__ A_rpn_c, const float* __restrict__ A_rpn_b,
    const float* __restrict__ A_roi_c, const float* __restrict__ A_roi_b,
    const int* __restrict__ rpn_class, const int* __restrict__ roi_class,
    float* __restrict__ S_rpn, float* __restrict__ T_rpn, float* __restrict__ c_rpn,
    float* __restrict__ S_roi, float* __restrict__ T_roi, float* __restrict__ c_roi,
    float* __restrict__ out)
{
    __shared__ float S[20][8];
    __shared__ float cnt[20];
    __shared__ float red[4][8];
    const int b = blockIdx.x, t = threadIdx.x;

    if (b < 2) {
        const float* A = b ? A_roi_c : A_rpn_c;
        const int* cls = b ? roi_class : rpn_class;
        if (t < 160) ((float*)S)[t] = 0.f;
        if (t < 20) cnt[t] = 0.f;
        __syncthreads();
        for (int r = t; r < NPTS; r += 256) {
            const int c = cls[r];
            atomicAdd(&cnt[c], 1.0f);
            const float4 v0 = *(const float4*)&A[(size_t)r * 8];
            const float4 v1 = *(const float4*)&A[(size_t)r * 8 + 4];
            atomicAdd(&S[c][0], v0.x); atomicAdd(&S[c][1], v0.y);
            atomicAdd(&S[c][2], v0.z); atomicAdd(&S[c][3], v0.w);
            atomicAdd(&S[c][4], v1.x); atomicAdd(&S[c][5], v1.y);
            atomicAdd(&S[c][6], v1.z); atomicAdd(&S[c][7], v1.w);
        }
        __syncthreads();
        float* Sg = b ? S_roi : S_rpn;
        float* Tg = b ? T_roi : T_rpn;
        float* cg = b ? c_roi : c_rpn;
        if (t < 160) Sg[t] = ((const float*)S)[t];
        if (t < 20) cg[t] = cnt[t];
        if (t < 8) {
            float s = 0.f;
            for (int c = 0; c < 20; ++c) s += S[c][t];
            Tg[t] = s;
            if (b == 0) out[t] = s * (1.f / 4096.f);
        }
        if (b == 1 && t < 160) {
            const int c = t >> 3;
            out[16 + t] = S[c][t & 7] / fmaxf(cnt[c], 1.f);
        }
    } else {
        const float* A = (b == 2) ? A_rpn_b : A_roi_b;
        float acc[8] = {};
        for (int r = t; r < NPTS; r += 256) {
            const float4 v0 = *(const float4*)&A[(size_t)r * 8];
            const float4 v1 = *(const float4*)&A[(size_t)r * 8 + 4];
            acc[0]+=v0.x; acc[1]+=v0.y; acc[2]+=v0.z; acc[3]+=v0.w;
            acc[4]+=v1.x; acc[5]+=v1.y; acc[6]+=v1.z; acc[7]+=v1.w;
        }
        const int lane = t & 63, wv = t >> 6;
#pragma unroll
        for (int o = 0; o < 8; ++o) {
            float v = acc[o];
            for (int off = 32; off; off >>= 1) v += __shfl_xor(v, off, 64);
            if (lane == 0) red[wv][o] = v;
        }
        __syncthreads();
        if (t < 8) {
            const float s = red[0][t] + red[1][t] + red[2][t] + red[3][t];
            out[((b == 2) ? 8 : 176) + t] = s * (1.f / 4096.f);
        }
    }
}

// ---------------------------------------------------------------------------
// cls loss
// ---------------------------------------------------------------------------
__global__ __launch_bounds__(256) void cls_loss_kernel(
    const float* __restrict__ A, const int* __restrict__ cls,
    const float* __restrict__ S, const float* __restrict__ T,
    const float* __restrict__ cnt, float* __restrict__ out)
{
    const int t = threadIdx.x;
    const int j0 = blockIdx.x * 16;
    const int jg = t >> 6, lane = t & 63;
    float aj[4][8];
#pragma unroll
    for (int r = 0; r < 4; ++r) {
        const int j = j0 + jg * 4 + r;
        const float4 v0 = *(const float4*)&A[(size_t)j * 8];
        const float4 v1 = *(const float4*)&A[(size_t)j * 8 + 4];
        aj[r][0]=v0.x; aj[r][1]=v0.y; aj[r][2]=v0.z; aj[r][3]=v0.w;
        aj[r][4]=v1.x; aj[r][5]=v1.y; aj[r][6]=v1.z; aj[r][7]=v1.w;
    }
    float Sx[4] = {};
    for (int k = lane; k < NPTS; k += 64) {
        const float4 b0 = *(const float4*)&A[(size_t)k * 8];
        const float4 b1 = *(const float4*)&A[(size_t)k * 8 + 4];
#pragma unroll
        for (int r = 0; r < 4; ++r) {
            const float d = aj[r][0]*b0.x + aj[r][1]*b0.y + aj[r][2]*b0.z + aj[r][3]*b0.w
                          + aj[r][4]*b1.x + aj[r][5]*b1.y + aj[r][6]*b1.z + aj[r][7]*b1.w;
            Sx[r] += expf(2.f * d);
        }
    }
    __shared__ float SxL[16];
#pragma unroll
    for (int r = 0; r < 4; ++r) {
        float v = Sx[r];
        for (int off = 32; off; off >>= 1) v += __shfl_xor(v, off, 64);
        if (lane == 0) SxL[jg * 4 + r] = v;
    }
    __syncthreads();
    __shared__ float lsum[16];
    if (t < 16) {
        const int j = j0 + t;
        const float Sxj = SxL[t] + NEPS;
        const int c = cls[j];
        const float m = cnt[c];
        const float Sg = (4096.f - m) + m * E2 + NEPS;
        const float Cg = Sg - NEPS;
        const float4 a0 = *(const float4*)&A[(size_t)j * 8];
        const float4 a1 = *(const float4*)&A[(size_t)j * 8 + 4];
        const float av[8] = {a0.x,a0.y,a0.z,a0.w,a1.x,a1.y,a1.z,a1.w};
        float U = 0.f;
#pragma unroll
        for (int o = 0; o < 8; ++o)
            U += av[o] * (T[o] + E2M1 * S[c * 8 + o]);
        lsum[t] = (2.f * U - logf(Sxj) * Cg) / Sg;
    }
    __syncthreads();
    if (t == 0) {
        float s = 0.f;
        for (int i = 0; i < 16; ++i) s += lsum[i];
        atomicAdd(out, -s / 4096.f);
    }
}

// ---------------------------------------------------------------------------
// bbox loss
// ---------------------------------------------------------------------------
__global__ __launch_bounds__(256) void bbox_loss_kernel(
    const float* __restrict__ A, const float* __restrict__ D, float* __restrict__ out)
{
    const int t = threadIdx.x;
    const int j0 = blockIdx.x * 16;
    const int jg = t >> 6, lane = t & 63;
    float aj[4][8], dj[4][4];
#pragma unroll
    for (int r = 0; r < 4; ++r) {
        const int j = j0 + jg * 4 + r;
        const float4 v0 = *(const float4*)&A[(size_t)j * 8];
        const float4 v1 = *(const float4*)&A[(size_t)j * 8 + 4];
        aj[r][0]=v0.x; aj[r][1]=v0.y; aj[r][2]=v0.z; aj[r][3]=v0.w;
        aj[r][4]=v1.x; aj[r][5]=v1.y; aj[r][6]=v1.z; aj[r][7]=v1.w;
        const float4 dv = *(const float4*)&D[(size_t)j * 4];
        dj[r][0]=dv.x; dj[r][1]=dv.y; dj[r][2]=dv.z; dj[r][3]=dv.w;
    }
    float Sx[4] = {}, Sg[4] = {}, U[4] = {};
    for (int k = lane; k < NPTS; k += 64) {
        const float4 b0 = *(const float4*)&A[(size_t)k * 8];
        const float4 b1 = *(const float4*)&A[(size_t)k * 8 + 4];
        const float4 dk = *(const float4*)&D[(size_t)k * 4];
#pragma unroll
        for (int r = 0; r < 4; ++r) {
            const float aa = aj[r][0]*b0.x + aj[r][1]*b0.y + aj[r][2]*b0.z + aj[r][3]*b0.w
                           + aj[r][4]*b1.x + aj[r][5]*b1.y + aj[r][6]*b1.z + aj[r][7]*b1.w;
            const float dd = dj[r][0]*dk.x + dj[r][1]*dk.y + dj[r][2]*dk.z + dj[r][3]*dk.w;
            const float ex = expf(2.f * aa);
            const float ed = expf(2.f * dd);
            Sx[r] += ex;
            Sg[r] += ed;
            U[r] = fmaf(ed, aa, U[r]);
        }
    }
    __shared__ float red[16][3];
#pragma unroll
    for (int r = 0; r < 4; ++r) {
        float vx = Sx[r], vg = Sg[r], vu = U[r];
        for (int off = 32; off; off >>= 1) {
            vx += __shfl_xor(vx, off, 64);
            vg += __shfl_xor(vg, off, 64);
            vu += __shfl_xor(vu, off, 64);
        }
        if (lane == 0) { red[jg*4+r][0] = vx; red[jg*4+r][1] = vg; red[jg*4+r][2] = vu; }
    }
    __syncthreads();
    __shared__ float lsum[16];
    if (t < 16) {
        const float Sxf = red[t][0] + NEPS;
        const float SgS = red[t][1];
        const float Sgf = SgS + NEPS;
        const float Uj  = red[t][2];
        lsum[t] = (2.f * Uj - logf(Sxf) * SgS) / Sgf;
    }
    __syncthreads();
    if (t == 0) {
        float s = 0.f;
        for (int i = 0; i < 16; ++i) s += lsum[i];
        atomicAdd(out, -s / 4096.f);
    }
}

// ---------------------------------------------------------------------------
extern "C" void kernel_launch(void* const* d_in, const int* in_sizes, int n_in,
                              void* d_out, int out_size, void* d_ws, size_t ws_size,
                              hipStream_t stream)
{
    const float* rpn_feat  = (const float*)d_in[0];
    const float* rpn_del   = (const float*)d_in[1];
    const float* rpn_scale = (const float*)d_in[2];
    const float* roi_feat  = (const float*)d_in[3];
    const float* roi_del   = (const float*)d_in[4];
    const float* roi_scale = (const float*)d_in[5];
    const int*   rpn_class = (const int*)d_in[6];
    const int*   roi_class = (const int*)d_in[7];
    const float* W_rpn_feat = (const float*)d_in[8];  const float* b_rpn_feat = (const float*)d_in[9];
    const float* W_rpn_del  = (const float*)d_in[10]; const float* b_rpn_del  = (const float*)d_in[11];
    const float* W_rpn_sc   = (const float*)d_in[12]; const float* b_rpn_sc   = (const float*)d_in[13];
    const float* W_roi_feat = (const float*)d_in[14]; const float* b_roi_feat = (const float*)d_in[15];
    const float* W_roi_del  = (const float*)d_in[16]; const float* b_roi_del  = (const float*)d_in[17];
    const float* W_roi_sc   = (const float*)d_in[18]; const float* b_roi_sc   = (const float*)d_in[19];
    const float* rpn_cls_W1  = (const float*)d_in[20]; const float* rpn_cls_b1  = (const float*)d_in[21];
    const float* rpn_cls_W2  = (const float*)d_in[22]; const float* rpn_cls_b2  = (const float*)d_in[23];
    const float* rpn_bbox_W1 = (const float*)d_in[24]; const float* rpn_bbox_b1 = (const float*)d_in[25];
    const float* rpn_bbox_W2 = (const float*)d_in[26]; const float* rpn_bbox_b2 = (const float*)d_in[27];
    const float* roi_cls_W1  = (const float*)d_in[28]; const float* roi_cls_b1  = (const float*)d_in[29];
    const float* roi_cls_W2  = (const float*)d_in[30]; const float* roi_cls_b2  = (const float*)d_in[31];
    const int* iter_ptr = (const int*)d_in[32];
    float* out = (float*)d_out;
    char*  wsb = (char*)d_ws;

    // ---- workspace layout (byte offsets) ----
    unsigned short* roi_feat_b   = (unsigned short*)(wsb + 0);          // 4096x1024
    unsigned short* W_roi_feat_b = (unsigned short*)(wsb + 8388608);    // 2048x1024
    unsigned short* roi_sum_b    = (unsigned short*)(wsb + 12582912);   // 4096x2048
    unsigned short* roi_W1_b     = (unsigned short*)(wsb + 29360128);   // 256x1024
    unsigned short* h_roi_c      = (unsigned short*)(wsb + 29884416);   // 4096x256
    unsigned short* h_roi_b      = (unsigned short*)(wsb + 31981568);   // 4096x256
    unsigned short* rpn_feat_b   = (unsigned short*)(wsb + 34078720);   // 4096x256
    unsigned short* W_rpn_feat_b = (unsigned short*)(wsb + 36175872);   // 512x256
    unsigned short* rpn_sum_b    = (unsigned short*)(wsb + 36438016);   // 4096x512
    unsigned short* rpn_cW1_b    = (unsigned short*)(wsb + 40632320);   // 128x256 padded
    unsigned short* rpn_bW1_b    = (unsigned short*)(wsb + 40697856);   // 128x256 padded
    unsigned short* h_rpn_c      = (unsigned short*)(wsb + 40763392);   // 4096x128
    unsigned short* h_rpn_b      = (unsigned short*)(wsb + 41811968);   // 4096x128
    float* bias_pad_c = (float*)(wsb + 42860544);                       // 128
    float* bias_pad_b = (float*)(wsb + 42861056);                       // 128
    float* A_rpn_c    = (float*)(wsb + 42861568);                       // 4096x8
    float* A_rpn_b    = (float*)(wsb + 42992640);
    float* A_roi_c    = (float*)(wsb + 43123712);
    float* A_roi_b    = (float*)(wsb + 43254784);
    float* S_rpn      = (float*)(wsb + 43385856);   // [20][8]
    float* T_rpn = S_rpn + 160; float* c_rpn = T_rpn + 8;
    float* S_roi = c_rpn + 20;  float* T_roi = S_roi + 160; float* c_roi = T_roi + 8;

    // ---- prep (all converts/pads/zeros) ----
    prep_kernel<<<dim3(7617), 256, 0, stream>>>(
        roi_feat, W_roi_feat, roi_cls_W1, rpn_feat, W_rpn_feat,
        rpn_cls_W1, rpn_bbox_W1, rpn_cls_b1, rpn_bbox_b1,
        roi_feat_b, W_roi_feat_b, roi_W1_b, rpn_feat_b, W_rpn_feat_b,
        rpn_cW1_b, rpn_bW1_b, bias_pad_c, bias_pad_b, out);

    // ---- RPN path ----
    gemm_mfma<true, false><<<dim3(4, 32, 1), 256, 0, stream>>>(
        rpn_feat_b, rpn_feat_b, 256, W_rpn_feat_b, W_rpn_feat_b, 256,
        b_rpn_feat, b_rpn_feat, rpn_sum_b, rpn_sum_b, 512, 256,
        rpn_del, W_rpn_del, b_rpn_del, rpn_scale, W_rpn_sc, b_rpn_sc);
    gemm_mfma<false, true><<<dim3(1, 32, 2), 256, 0, stream>>>(
        rpn_sum_b, rpn_sum_b + 256, 512, rpn_cW1_b, rpn_bW1_b, 256,
        bias_pad_c, bias_pad_b, h_rpn_c, h_rpn_b, 128, 256,
        nullptr, nullptr, nullptr, nullptr, nullptr, nullptr);
    alphas2_kernel<<<dim3(1024, 2), 256, 0, stream>>>(
        h_rpn_c, h_rpn_b, 128, 64, rpn_cls_W2, rpn_bbox_W2, rpn_cls_b2, rpn_bbox_b2,
        iter_ptr, A_rpn_c, A_rpn_b);

    // ---- ROI path ----
    gemm_mfma<true, false><<<dim3(16, 32, 1), 256, 0, stream>>>(
        roi_feat_b, roi_feat_b, 1024, W_roi_feat_b, W_roi_feat_b, 1024,
        b_roi_feat, b_roi_feat, roi_sum_b, roi_sum_b, 2048, 1024,
        roi_del, W_roi_del, b_roi_del, roi_scale, W_roi_sc, b_roi_sc);
    // reference bug: bbox half also uses roi_cls_W1/b1 (and W2/b2 below)
    gemm_mfma<false, true><<<dim3(2, 32, 2), 256, 0, stream>>>(
        roi_sum_b, roi_sum_b + 1024, 2048, roi_W1_b, roi_W1_b, 1024,
        roi_cls_b1, roi_cls_b1, h_roi_c, h_roi_b, 256, 1024,
        nullptr, nullptr, nullptr, nullptr, nullptr, nullptr);
    alphas2_kernel<<<dim3(1024, 2), 256, 0, stream>>>(
        h_roi_c, h_roi_b, 256, 256, roi_cls_W2, roi_cls_W2, roi_cls_b2, roi_cls_b2,
        iter_ptr, A_roi_c, A_roi_b);

    // ---- small reductions / direct outputs ----
    smalls_kernel<<<dim3(4), dim3(256), 0, stream>>>(
        A_rpn_c, A_rpn_b, A_roi_c, A_roi_b, rpn_class, roi_class,
        S_rpn, T_rpn, c_rpn, S_roi, T_roi, c_roi, out);

    // ---- losses ----
    cls_loss_kernel<<<dim3(256), dim3(256), 0, stream>>>(A_roi_c, roi_class, S_roi, T_roi, c_roi, out + 184);
    cls_loss_kernel<<<dim3(256), dim3(256), 0, stream>>>(A_rpn_c, rpn_class, S_rpn, T_rpn, c_rpn, out + 185);
    bbox_loss_kernel<<<dim3(256), dim3(256), 0, stream>>>(A_roi_b, roi_del, out + 186);
    bbox_loss_kernel<<<dim3(256), dim3(256), 0, stream>>>(A_rpn_b, rpn_del, out + 187);
}

// Round 4
// 210.324 us; speedup vs baseline: 3.0338x; 1.6431x over previous
//
#include <hip/hip_runtime.h>
#include <math.h>

#define NPTS 4096
#define NEPS 4.096e-4f                 // 4096 * 1e-7
#define E2   7.3890560989306495f       // exp(2)

typedef float  f32x4 __attribute__((ext_vector_type(4)));
typedef short  s16x8 __attribute__((ext_vector_type(8)));

static __device__ __forceinline__ unsigned short f2b(float x) {
    unsigned u = __builtin_bit_cast(unsigned, x);
    return (unsigned short)((u + 0x7fffu + ((u >> 16) & 1u)) >> 16);
}
static __device__ __forceinline__ float b2f(unsigned short h) {
    return __builtin_bit_cast(float, (unsigned)h << 16);
}

static __device__ __forceinline__ void gload16(const unsigned short* g, unsigned short* lds) {
    __builtin_amdgcn_global_load_lds(
        (const __attribute__((address_space(1))) void*)g,
        (__attribute__((address_space(3))) void*)lds, 16, 0, 0);
}

// ---------------------------------------------------------------------------
// prep: all f32->bf16 converts + rpn W1 pads + bias pads + loss zero, 1 launch
// ---------------------------------------------------------------------------
__global__ __launch_bounds__(256) void prep_kernel(
    const float* __restrict__ roi_feat, const float* __restrict__ W_roi_feat,
    const float* __restrict__ roi_cls_W1,
    const float* __restrict__ rpn_feat, const float* __restrict__ W_rpn_feat,
    const float* __restrict__ rpn_cls_W1, const float* __restrict__ rpn_bbox_W1,
    const float* __restrict__ rpn_cls_b1, const float* __restrict__ rpn_bbox_b1,
    unsigned short* __restrict__ roi_feat_b, unsigned short* __restrict__ W_roi_feat_b,
    unsigned short* __restrict__ roi_W1_b,
    unsigned short* __restrict__ rpn_feat_b, unsigned short* __restrict__ W_rpn_feat_b,
    unsigned short* __restrict__ rpn_cW1_b, unsigned short* __restrict__ rpn_bW1_b,
    float* __restrict__ bias_pad_c, float* __restrict__ bias_pad_b,
    float* __restrict__ out)
{
    const int b = blockIdx.x, t = threadIdx.x;
    if (b < 7552) {
        const float* in; unsigned short* o; int base;
        if      (b < 4096) { in = roi_feat;   o = roi_feat_b;   base = b; }
        else if (b < 6144) { in = W_roi_feat; o = W_roi_feat_b; base = b - 4096; }
        else if (b < 6400) { in = roi_cls_W1; o = roi_W1_b;     base = b - 6144; }
        else if (b < 7424) { in = rpn_feat;   o = rpn_feat_b;   base = b - 6400; }
        else               { in = W_rpn_feat; o = W_rpn_feat_b; base = b - 7424; }
        const int i = base * 1024 + t * 4;
        const float4 v = *(const float4*)&in[i];
        ushort4 ov;
        ov.x = f2b(v.x); ov.y = f2b(v.y); ov.z = f2b(v.z); ov.w = f2b(v.w);
        *(ushort4*)&o[i] = ov;
    } else if (b < 7616) {
        const bool cls = b < 7584;
        const float* W = cls ? rpn_cls_W1 : rpn_bbox_W1;
        unsigned short* o = cls ? rpn_cW1_b : rpn_bW1_b;
        const int local = b - (cls ? 7552 : 7584);
        const int i0 = local * 1024 + t * 4;
#pragma unroll
        for (int u = 0; u < 4; ++u) {
            const int i = i0 + u;
            const int r = i >> 8, c = i & 255;
            o[i] = (r < 64) ? f2b(W[r * 256 + c]) : (unsigned short)0;
        }
    } else {
        if (t < 128)      bias_pad_c[t] = (t < 64) ? rpn_cls_b1[t] : 0.f;
        else              bias_pad_b[t - 128] = ((t - 128) < 64) ? rpn_bbox_b1[t - 128] : 0.f;
        if (t < 4) out[184 + t] = 0.f;
    }
}

// ---------------------------------------------------------------------------
// MFMA GEMM with job table. 128x128 tile, BK=32, conflict-free subtile LDS:
// subtile s (16 rows x 32 cols) stored as 64 lane-chunks of 16B; chunk l =
// T[s*16 + (l&15)][(l>>4)*8 .. +8). global_load_lds writes lane-linear,
// fragment read is 64 contiguous 16B chunks (zero bank conflicts).
// ---------------------------------------------------------------------------
struct GemmJob {
    const unsigned short *A, *W;
    unsigned short *C;
    const float *bias;
    const float *del, *Wd, *bd, *sc, *Wsc, *bs;
    int lda, ldw, ldc, K, nbx, bstart;
};
struct GemmJobs { GemmJob j[4]; int n; };

template<bool EXTRAS, bool RELU>
__global__ __launch_bounds__(256) void gemm_mfma(GemmJobs jobs)
{
    __shared__ __align__(16) unsigned short As[4096];   // 8 subtiles * 512
    __shared__ __align__(16) unsigned short Bs[4096];
    const int bid = blockIdx.x;
    int ji = 0;
#pragma unroll
    for (int i = 1; i < 4; ++i)
        if (i < jobs.n && bid >= jobs.j[i].bstart) ji = i;
    const GemmJob jb = jobs.j[ji];
    const int local = bid - jb.bstart;
    const int bx = local % jb.nbx, by = local / jb.nbx;
    const int row0 = by * 128, col0 = bx * 128;

    const int t = threadIdx.x, l = t & 63, w = t >> 6;
    const int wr = w >> 1, wc = w & 1;
    const int fr = l & 15, fq = l >> 4;

    // staging: wave w loads subtiles {2w, 2w+1} of A and of B
    const int s0 = 2 * w, s1 = 2 * w + 1;
    const unsigned short* gA0 = jb.A + (size_t)(row0 + s0 * 16 + fr) * jb.lda + fq * 8;
    const unsigned short* gA1 = jb.A + (size_t)(row0 + s1 * 16 + fr) * jb.lda + fq * 8;
    const unsigned short* gW0 = jb.W + (size_t)(col0 + s0 * 16 + fr) * jb.ldw + fq * 8;
    const unsigned short* gW1 = jb.W + (size_t)(col0 + s1 * 16 + fr) * jb.ldw + fq * 8;
    unsigned short* lA0 = As + s0 * 512;
    unsigned short* lA1 = As + s1 * 512;
    unsigned short* lB0 = Bs + s0 * 512;
    unsigned short* lB1 = Bs + s1 * 512;

    f32x4 acc[4][4] = {};

    for (int k0 = 0; k0 < jb.K; k0 += 32) {
        __syncthreads();                     // prev-iter LDS reads complete
        gload16(gA0 + k0, lA0);
        gload16(gA1 + k0, lA1);
        gload16(gW0 + k0, lB0);
        gload16(gW1 + k0, lB1);
        __syncthreads();                     // vmcnt(0) drain + barrier
        s16x8 af[4], bf[4];
#pragma unroll
        for (int m = 0; m < 4; ++m)
            af[m] = *(const s16x8*)&As[(wr * 4 + m) * 512 + l * 8];
#pragma unroll
        for (int n = 0; n < 4; ++n)
            bf[n] = *(const s16x8*)&Bs[(wc * 4 + n) * 512 + l * 8];
#pragma unroll
        for (int m = 0; m < 4; ++m)
#pragma unroll
            for (int n = 0; n < 4; ++n)
                acc[m][n] = __builtin_amdgcn_mfma_f32_16x16x32_bf16(
                    af[m], bf[n], acc[m][n], 0, 0, 0);
    }

    // epilogue: row = row0+wr*64+m*16+fq*4+j ; col = col0+wc*64+n*16+fr
#pragma unroll
    for (int n = 0; n < 4; ++n) {
        const int col = col0 + wc * 64 + n * 16 + fr;
        float cadd = jb.bias[col];
        float wd0 = 0.f, wd1 = 0.f, wd2 = 0.f, wd3 = 0.f, wscv = 0.f;
        if (EXTRAS) {
            cadd += jb.bd[col] + jb.bs[col];
            const float4 w4 = *(const float4*)&jb.Wd[col * 4];
            wd0 = w4.x; wd1 = w4.y; wd2 = w4.z; wd3 = w4.w;
            wscv = jb.Wsc[col];
        }
#pragma unroll
        for (int m = 0; m < 4; ++m) {
#pragma unroll
            for (int j = 0; j < 4; ++j) {
                const int row = row0 + wr * 64 + m * 16 + fq * 4 + j;
                float v = acc[m][n][j] + cadd;
                if (EXTRAS) {
                    const float4 dm = *(const float4*)&jb.del[row * 4];
                    v += dm.x * wd0 + dm.y * wd1 + dm.z * wd2 + dm.w * wd3
                       + jb.sc[row] * wscv;
                }
                if (RELU) v = fmaxf(v, 0.f);
                jb.C[(size_t)row * jb.ldc + col] = f2b(v);
            }
        }
    }
}

// ---------------------------------------------------------------------------
// alphas for all 4 matrices in one launch: 4096 blocks x 4 rows (1 wave/row)
// vrow = blockIdx*4 + (t>>6); matrix = vrow>>12, row = vrow&4095
// ---------------------------------------------------------------------------
__global__ __launch_bounds__(256) void alphas_all(
    const unsigned short* __restrict__ h_rpn_c, const unsigned short* __restrict__ h_rpn_b,
    const unsigned short* __restrict__ h_roi_c, const unsigned short* __restrict__ h_roi_b,
    const float* __restrict__ W2_rc, const float* __restrict__ W2_rb,
    const float* __restrict__ W2_oc,
    const float* __restrict__ b2_rc, const float* __restrict__ b2_rb,
    const float* __restrict__ b2_oc,
    const int* __restrict__ iter_ptr,
    float* __restrict__ A_rpn_c, float* __restrict__ A_rpn_b,
    float* __restrict__ A_roi_c, float* __restrict__ A_roi_b)
{
    const int vrow = blockIdx.x * 4 + (threadIdx.x >> 6);
    const int mat = vrow >> 12, row = vrow & 4095;
    const unsigned short* H; const float *W2, *b2; float* Ao; int ldh, Hd;
    if (mat == 0)      { H = h_rpn_c; W2 = W2_rc; b2 = b2_rc; Ao = A_rpn_c; ldh = 128; Hd = 64; }
    else if (mat == 1) { H = h_rpn_b; W2 = W2_rb; b2 = b2_rb; Ao = A_rpn_b; ldh = 128; Hd = 64; }
    else if (mat == 2) { H = h_roi_c; W2 = W2_oc; b2 = b2_oc; Ao = A_roi_c; ldh = 256; Hd = 256; }
    else               { H = h_roi_b; W2 = W2_oc; b2 = b2_oc; Ao = A_roi_b; ldh = 256; Hd = 256; }

    const int l = threadIdx.x & 63;
    float acc[8] = {};
    for (int m = l * 4; m < Hd; m += 256) {
        const ushort4 h4 = *(const ushort4*)&H[(size_t)row * ldh + m];
        const float h0 = b2f(h4.x), h1 = b2f(h4.y), h2 = b2f(h4.z), h3 = b2f(h4.w);
#pragma unroll
        for (int o = 0; o < 8; ++o) {
            const float4 w4 = *(const float4*)&W2[o * Hd + m];
            acc[o] += h0 * w4.x + h1 * w4.y + h2 * w4.z + h3 * w4.w;
        }
    }
#pragma unroll
    for (int o = 0; o < 8; ++o)
        for (int off = 32; off; off >>= 1)
            acc[o] += __shfl_xor(acc[o], off, 64);

    const int it = *iter_ptr;
    const float temp = fmaxf(1.0f, 30.0f * (float)(90000 - it) / 90000.0f);
    float lg[8], mx = -1e30f;
#pragma unroll
    for (int o = 0; o < 8; ++o) { lg[o] = (acc[o] + b2[o]) / temp; mx = fmaxf(mx, lg[o]); }
    float s = 0.f;
#pragma unroll
    for (int o = 0; o < 8; ++o) { lg[o] = __expf(lg[o] - mx); s += lg[o]; }
    if (l < 8) Ao[(size_t)row * 8 + l] = lg[l] / s;
}

// ---------------------------------------------------------------------------
// finale: all 4 losses + all output means in one launch (1028 blocks)
//  b <  256 : roi_cls loss -> out[184]
//  b <  512 : rpn_cls loss -> out[185]
//  b <  768 : roi_bbox loss -> out[186]
//  b < 1024 : rpn_bbox loss -> out[187]
//  b ==1024 : colmean A_rpn_c -> out[0:8]
//  b ==1025 : colmean A_rpn_b -> out[8:16]
//  b ==1026 : colmean A_roi_b -> out[176:184]
//  b ==1027 : per-class means A_roi_c -> out[16:176]
// ---------------------------------------------------------------------------
__global__ __launch_bounds__(256) void finale_kernel(
    const float* __restrict__ A_roi_c, const float* __restrict__ A_rpn_c,
    const float* __restrict__ A_roi_b, const float* __restrict__ A_rpn_b,
    const float* __restrict__ roi_del, const float* __restrict__ rpn_del,
    const int* __restrict__ roi_class, const int* __restrict__ rpn_class,
    float* __restrict__ out)
{
    __shared__ float red[16][3];
    __shared__ float lsum[16];
    __shared__ float S[20][8];
    __shared__ float cnt[20];
    const int b = blockIdx.x, t = threadIdx.x;
    const int jg = t >> 6, lane = t & 63;

    if (b < 512) {
        // -------- cls loss (self-contained) --------
        const float* A  = (b < 256) ? A_roi_c : A_rpn_c;
        const int* cls  = (b < 256) ? roi_class : rpn_class;
        float* outp     = (b < 256) ? out + 184 : out + 185;
        const int blk   = (b < 256) ? b : b - 256;
        float aj[4][8]; int cj[4];
#pragma unroll
        for (int r = 0; r < 4; ++r) {
            const int j = blk * 16 + jg * 4 + r;
            const float4 v0 = *(const float4*)&A[(size_t)j * 8];
            const float4 v1 = *(const float4*)&A[(size_t)j * 8 + 4];
            aj[r][0]=v0.x; aj[r][1]=v0.y; aj[r][2]=v0.z; aj[r][3]=v0.w;
            aj[r][4]=v1.x; aj[r][5]=v1.y; aj[r][6]=v1.z; aj[r][7]=v1.w;
            cj[r] = cls[j];
        }
        float Sx[4] = {}, Cg[4] = {}, U[4] = {};
        for (int k = lane; k < NPTS; k += 64) {
            const float4 b0 = *(const float4*)&A[(size_t)k * 8];
            const float4 b1 = *(const float4*)&A[(size_t)k * 8 + 4];
            const int ck = cls[k];
#pragma unroll
            for (int r = 0; r < 4; ++r) {
                const float d = aj[r][0]*b0.x + aj[r][1]*b0.y + aj[r][2]*b0.z + aj[r][3]*b0.w
                              + aj[r][4]*b1.x + aj[r][5]*b1.y + aj[r][6]*b1.z + aj[r][7]*b1.w;
                const float wgt = (ck == cj[r]) ? E2 : 1.0f;
                Sx[r] += __expf(2.f * d);
                U[r]  = fmaf(wgt, d, U[r]);
                Cg[r] += wgt;
            }
        }
#pragma unroll
        for (int r = 0; r < 4; ++r) {
            float vx = Sx[r], vg = Cg[r], vu = U[r];
            for (int off = 32; off; off >>= 1) {
                vx += __shfl_xor(vx, off, 64);
                vg += __shfl_xor(vg, off, 64);
                vu += __shfl_xor(vu, off, 64);
            }
            if (lane == 0) { red[jg*4+r][0] = vx; red[jg*4+r][1] = vg; red[jg*4+r][2] = vu; }
        }
        __syncthreads();
        if (t < 16) {
            const float Sxf = red[t][0] + NEPS;
            const float Cgv = red[t][1];
            lsum[t] = (2.f * red[t][2] - __logf(Sxf) * Cgv) / (Cgv + NEPS);
        }
        __syncthreads();
        if (t == 0) {
            float s = 0.f;
            for (int i = 0; i < 16; ++i) s += lsum[i];
            atomicAdd(outp, -s / 4096.f);
        }
    } else if (b < 1024) {
        // -------- bbox loss --------
        const float* A  = (b < 768) ? A_roi_b : A_rpn_b;
        const float* D  = (b < 768) ? roi_del : rpn_del;
        float* outp     = (b < 768) ? out + 186 : out + 187;
        const int blk   = (b < 768) ? b - 512 : b - 768;
        float aj[4][8], dj[4][4];
#pragma unroll
        for (int r = 0; r < 4; ++r) {
            const int j = blk * 16 + jg * 4 + r;
            const float4 v0 = *(const float4*)&A[(size_t)j * 8];
            const float4 v1 = *(const float4*)&A[(size_t)j * 8 + 4];
            aj[r][0]=v0.x; aj[r][1]=v0.y; aj[r][2]=v0.z; aj[r][3]=v0.w;
            aj[r][4]=v1.x; aj[r][5]=v1.y; aj[r][6]=v1.z; aj[r][7]=v1.w;
            const float4 dv = *(const float4*)&D[(size_t)j * 4];
            dj[r][0]=dv.x; dj[r][1]=dv.y; dj[r][2]=dv.z; dj[r][3]=dv.w;
        }
        float Sx[4] = {}, Sg[4] = {}, U[4] = {};
        for (int k = lane; k < NPTS; k += 64) {
            const float4 b0 = *(const float4*)&A[(size_t)k * 8];
            const float4 b1 = *(const float4*)&A[(size_t)k * 8 + 4];
            const float4 dk = *(const float4*)&D[(size_t)k * 4];
#pragma unroll
            for (int r = 0; r < 4; ++r) {
                const float aa = aj[r][0]*b0.x + aj[r][1]*b0.y + aj[r][2]*b0.z + aj[r][3]*b0.w
                               + aj[r][4]*b1.x + aj[r][5]*b1.y + aj[r][6]*b1.z + aj[r][7]*b1.w;
                const float dd = dj[r][0]*dk.x + dj[r][1]*dk.y + dj[r][2]*dk.z + dj[r][3]*dk.w;
                const float ex = __expf(2.f * aa);
                const float ed = __expf(2.f * dd);
                Sx[r] += ex;
                Sg[r] += ed;
                U[r] = fmaf(ed, aa, U[r]);
            }
        }
#pragma unroll
        for (int r = 0; r < 4; ++r) {
            float vx = Sx[r], vg = Sg[r], vu = U[r];
            for (int off = 32; off; off >>= 1) {
                vx += __shfl_xor(vx, off, 64);
                vg += __shfl_xor(vg, off, 64);
                vu += __shfl_xor(vu, off, 64);
            }
            if (lane == 0) { red[jg*4+r][0] = vx; red[jg*4+r][1] = vg; red[jg*4+r][2] = vu; }
        }
        __syncthreads();
        if (t < 16) {
            const float Sxf = red[t][0] + NEPS;
            const float SgS = red[t][1];
            lsum[t] = (2.f * red[t][2] - __logf(Sxf) * SgS) / (SgS + NEPS);
        }
        __syncthreads();
        if (t == 0) {
            float s = 0.f;
            for (int i = 0; i < 16; ++i) s += lsum[i];
            atomicAdd(outp, -s / 4096.f);
        }
    } else if (b < 1027) {
        // -------- column means --------
        const float* A = (b == 1024) ? A_rpn_c : (b == 1025) ? A_rpn_b : A_roi_b;
        const int off0 = (b == 1024) ? 0 : (b == 1025) ? 8 : 176;
        float acc[8] = {};
        for (int r = t; r < NPTS; r += 256) {
            const float4 v0 = *(const float4*)&A[(size_t)r * 8];
            const float4 v1 = *(const float4*)&A[(size_t)r * 8 + 4];
            acc[0]+=v0.x; acc[1]+=v0.y; acc[2]+=v0.z; acc[3]+=v0.w;
            acc[4]+=v1.x; acc[5]+=v1.y; acc[6]+=v1.z; acc[7]+=v1.w;
        }
#pragma unroll
        for (int o = 0; o < 8; ++o) {
            float v = acc[o];
            for (int offs = 32; offs; offs >>= 1) v += __shfl_xor(v, offs, 64);
            if (lane == 0) red[jg][o] = v;   // red[4][8] fits in red[16][3]+lsum region? no: reuse S
        }
        __syncthreads();
        if (t < 8) {
            float s = 0.f;
            for (int wv = 0; wv < 4; ++wv) s += red[wv][t % 3 == t ? 0 : 0]; // placeholder
        }
        // NOTE: simple version below (no placeholder): recompute via S array
        __syncthreads();
        if (lane == 0) { S[jg][0]=0; }  // unused
        // Correct reduction using S[4][8] region:
        __syncthreads();
#pragma unroll
        for (int o = 0; o < 8; ++o) {
            float v = acc[o];
            for (int offs = 32; offs; offs >>= 1) v += __shfl_xor(v, offs, 64);
            if (lane == 0) S[jg][o] = v;
        }
        __syncthreads();
        if (t < 8) {
            const float s = S[0][t] + S[1][t] + S[2][t] + S[3][t];
            out[off0 + t] = s * (1.f / 4096.f);
        }
    } else {
        // -------- per-class means of A_roi_c --------
        if (t < 160) ((float*)S)[t] = 0.f;
        if (t < 20) cnt[t] = 0.f;
        __syncthreads();
        for (int r = t; r < NPTS; r += 256) {
            const int c = roi_class[r];
            atomicAdd(&cnt[c], 1.0f);
            const float4 v0 = *(const float4*)&A_roi_c[(size_t)r * 8];
            const float4 v1 = *(const float4*)&A_roi_c[(size_t)r * 8 + 4];
            atomicAdd(&S[c][0], v0.x); atomicAdd(&S[c][1], v0.y);
            atomicAdd(&S[c][2], v0.z); atomicAdd(&S[c][3], v0.w);
            atomicAdd(&S[c][4], v1.x); atomicAdd(&S[c][5], v1.y);
            atomicAdd(&S[c][6], v1.z); atomicAdd(&S[c][7], v1.w);
        }
        __syncthreads();
        if (t < 160) {
            const int c = t >> 3;
            out[16 + t] = S[c][t & 7] / fmaxf(cnt[c], 1.f);
        }
    }
}

// ---------------------------------------------------------------------------
extern "C" void kernel_launch(void* const* d_in, const int* in_sizes, int n_in,
                              void* d_out, int out_size, void* d_ws, size_t ws_size,
                              hipStream_t stream)
{
    const float* rpn_feat  = (const float*)d_in[0];
    const float* rpn_del   = (const float*)d_in[1];
    const float* rpn_scale = (const float*)d_in[2];
    const float* roi_feat  = (const float*)d_in[3];
    const float* roi_del   = (const float*)d_in[4];
    const float* roi_scale = (const float*)d_in[5];
    const int*   rpn_class = (const int*)d_in[6];
    const int*   roi_class = (const int*)d_in[7];
    const float* W_rpn_feat = (const float*)d_in[8];  const float* b_rpn_feat = (const float*)d_in[9];
    const float* W_rpn_del  = (const float*)d_in[10]; const float* b_rpn_del  = (const float*)d_in[11];
    const float* W_rpn_sc   = (const float*)d_in[12]; const float* b_rpn_sc   = (const float*)d_in[13];
    const float* W_roi_feat = (const float*)d_in[14]; const float* b_roi_feat = (const float*)d_in[15];
    const float* W_roi_del  = (const float*)d_in[16]; const float* b_roi_del  = (const float*)d_in[17];
    const float* W_roi_sc   = (const float*)d_in[18]; const float* b_roi_sc   = (const float*)d_in[19];
    const float* rpn_cls_W1  = (const float*)d_in[20]; const float* rpn_cls_b1  = (const float*)d_in[21];
    const float* rpn_cls_W2  = (const float*)d_in[22]; const float* rpn_cls_b2  = (const float*)d_in[23];
    const float* rpn_bbox_W1 = (const float*)d_in[24]; const float* rpn_bbox_b1 = (const float*)d_in[25];
    const float* rpn_bbox_W2 = (const float*)d_in[26]; const float* rpn_bbox_b2 = (const float*)d_in[27];
    const float* roi_cls_W1  = (const float*)d_in[28]; const float* roi_cls_b1  = (const float*)d_in[29];
    const float* roi_cls_W2  = (const float*)d_in[30]; const float* roi_cls_b2  = (const float*)d_in[31];
    const int* iter_ptr = (const int*)d_in[32];
    float* out = (float*)d_out;
    char*  wsb = (char*)d_ws;

    // ---- workspace layout (byte offsets) ----
    unsigned short* roi_feat_b   = (unsigned short*)(wsb + 0);          // 4096x1024
    unsigned short* W_roi_feat_b = (unsigned short*)(wsb + 8388608);    // 2048x1024
    unsigned short* roi_sum_b    = (unsigned short*)(wsb + 12582912);   // 4096x2048
    unsigned short* roi_W1_b     = (unsigned short*)(wsb + 29360128);   // 256x1024
    unsigned short* h_roi_c      = (unsigned short*)(wsb + 29884416);   // 4096x256
    unsigned short* h_roi_b      = (unsigned short*)(wsb + 31981568);   // 4096x256
    unsigned short* rpn_feat_b   = (unsigned short*)(wsb + 34078720);   // 4096x256
    unsigned short* W_rpn_feat_b = (unsigned short*)(wsb + 36175872);   // 512x256
    unsigned short* rpn_sum_b    = (unsigned short*)(wsb + 36438016);   // 4096x512
    unsigned short* rpn_cW1_b    = (unsigned short*)(wsb + 40632320);   // 128x256 padded
    unsigned short* rpn_bW1_b    = (unsigned short*)(wsb + 40697856);   // 128x256 padded
    unsigned short* h_rpn_c      = (unsigned short*)(wsb + 40763392);   // 4096x128
    unsigned short* h_rpn_b      = (unsigned short*)(wsb + 41811968);   // 4096x128
    float* bias_pad_c = (float*)(wsb + 42860544);                       // 128
    float* bias_pad_b = (float*)(wsb + 42861056);                       // 128
    float* A_rpn_c    = (float*)(wsb + 42861568);                       // 4096x8
    float* A_rpn_b    = (float*)(wsb + 42992640);
    float* A_roi_c    = (float*)(wsb + 43123712);
    float* A_roi_b    = (float*)(wsb + 43254784);

    // ---- 1: prep ----
    prep_kernel<<<dim3(7617), 256, 0, stream>>>(
        roi_feat, W_roi_feat, roi_cls_W1, rpn_feat, W_rpn_feat,
        rpn_cls_W1, rpn_bbox_W1, rpn_cls_b1, rpn_bbox_b1,
        roi_feat_b, W_roi_feat_b, roi_W1_b, rpn_feat_b, W_rpn_feat_b,
        rpn_cW1_b, rpn_bW1_b, bias_pad_c, bias_pad_b, out);

    // ---- 2: both big GEMMs (extras fused) ----
    {
        GemmJobs js;
        js.n = 2;
        js.j[0] = { rpn_feat_b, W_rpn_feat_b, rpn_sum_b, b_rpn_feat,
                    rpn_del, W_rpn_del, b_rpn_del, rpn_scale, W_rpn_sc, b_rpn_sc,
                    256, 256, 512, 256, 4, 0 };
        js.j[1] = { roi_feat_b, W_roi_feat_b, roi_sum_b, b_roi_feat,
                    roi_del, W_roi_del, b_roi_del, roi_scale, W_roi_sc, b_roi_sc,
                    1024, 1024, 2048, 1024, 16, 128 };
        js.j[2] = js.j[0]; js.j[3] = js.j[0];
        gemm_mfma<true, false><<<dim3(640), 256, 0, stream>>>(js);
    }

    // ---- 3: all 4 hidden GEMMs (relu fused) ----
    {
        GemmJobs js;
        js.n = 4;
        js.j[0] = { rpn_sum_b,        rpn_cW1_b, h_rpn_c, bias_pad_c,
                    nullptr, nullptr, nullptr, nullptr, nullptr, nullptr,
                    512, 256, 128, 256, 1, 0 };
        js.j[1] = { rpn_sum_b + 256,  rpn_bW1_b, h_rpn_b, bias_pad_b,
                    nullptr, nullptr, nullptr, nullptr, nullptr, nullptr,
                    512, 256, 128, 256, 1, 32 };
        js.j[2] = { roi_sum_b,        roi_W1_b, h_roi_c, roi_cls_b1,
                    nullptr, nullptr, nullptr, nullptr, nullptr, nullptr,
                    2048, 1024, 256, 1024, 2, 64 };
        // reference bug: bbox half also uses roi_cls W1/b1 (and W2/b2 below)
        js.j[3] = { roi_sum_b + 1024, roi_W1_b, h_roi_b, roi_cls_b1,
                    nullptr, nullptr, nullptr, nullptr, nullptr, nullptr,
                    2048, 1024, 256, 1024, 2, 128 };
        gemm_mfma<false, true><<<dim3(192), 256, 0, stream>>>(js);
    }

    // ---- 4: all 4 alphas ----
    alphas_all<<<dim3(4096), 256, 0, stream>>>(
        h_rpn_c, h_rpn_b, h_roi_c, h_roi_b,
        rpn_cls_W2, rpn_bbox_W2, roi_cls_W2,
        rpn_cls_b2, rpn_bbox_b2, roi_cls_b2,
        iter_ptr, A_rpn_c, A_rpn_b, A_roi_c, A_roi_b);

    // ---- 5: losses + means ----
    finale_kernel<<<dim3(1028), 256, 0, stream>>>(
        A_roi_c, A_rpn_c, A_roi_b, A_rpn_b,
        roi_del, rpn_del, roi_class, rpn_class, out);
}

// Round 5
// 180.902 us; speedup vs baseline: 3.5272x; 1.1626x over previous
//
#include <hip/hip_runtime.h>
#include <math.h>

#define NPTS 4096
#define NEPS 4.096e-4f                 // 4096 * 1e-7
#define E2   7.3890560989306495f       // exp(2)

typedef float  f32x4 __attribute__((ext_vector_type(4)));
typedef short  s16x8 __attribute__((ext_vector_type(8)));

static __device__ __forceinline__ unsigned short f2b(float x) {
    unsigned u = __builtin_bit_cast(unsigned, x);
    return (unsigned short)((u + 0x7fffu + ((u >> 16) & 1u)) >> 16);
}
static __device__ __forceinline__ float b2f(unsigned short h) {
    return __builtin_bit_cast(float, (unsigned)h << 16);
}

static __device__ __forceinline__ void gload16(const unsigned short* g, unsigned short* lds) {
    __builtin_amdgcn_global_load_lds(
        (const __attribute__((address_space(1))) void*)g,
        (__attribute__((address_space(3))) void*)lds, 16, 0, 0);
}

// ---------------------------------------------------------------------------
// prep: f32->bf16 converts + rpn W1 pads + bias pads + delta pads + loss zero
// ---------------------------------------------------------------------------
__global__ __launch_bounds__(256) void prep_kernel(
    const float* __restrict__ roi_feat, const float* __restrict__ W_roi_feat,
    const float* __restrict__ roi_cls_W1,
    const float* __restrict__ rpn_feat, const float* __restrict__ W_rpn_feat,
    const float* __restrict__ rpn_cls_W1, const float* __restrict__ rpn_bbox_W1,
    const float* __restrict__ rpn_cls_b1, const float* __restrict__ rpn_bbox_b1,
    const float* __restrict__ roi_del, const float* __restrict__ rpn_del,
    unsigned short* __restrict__ roi_feat_b, unsigned short* __restrict__ W_roi_feat_b,
    unsigned short* __restrict__ roi_W1_b,
    unsigned short* __restrict__ rpn_feat_b, unsigned short* __restrict__ W_rpn_feat_b,
    unsigned short* __restrict__ rpn_cW1_b, unsigned short* __restrict__ rpn_bW1_b,
    unsigned short* __restrict__ Db_roi, unsigned short* __restrict__ Db_rpn,
    float* __restrict__ bias_pad_c, float* __restrict__ bias_pad_b,
    float* __restrict__ out)
{
    const int b = blockIdx.x, t = threadIdx.x;
    if (b < 7552) {
        const float* in; unsigned short* o; int base;
        if      (b < 4096) { in = roi_feat;   o = roi_feat_b;   base = b; }
        else if (b < 6144) { in = W_roi_feat; o = W_roi_feat_b; base = b - 4096; }
        else if (b < 6400) { in = roi_cls_W1; o = roi_W1_b;     base = b - 6144; }
        else if (b < 7424) { in = rpn_feat;   o = rpn_feat_b;   base = b - 6400; }
        else               { in = W_rpn_feat; o = W_rpn_feat_b; base = b - 7424; }
        const int i = base * 1024 + t * 4;
        const float4 v = *(const float4*)&in[i];
        ushort4 ov;
        ov.x = f2b(v.x); ov.y = f2b(v.y); ov.z = f2b(v.z); ov.w = f2b(v.w);
        *(ushort4*)&o[i] = ov;
    } else if (b < 7616) {
        const bool cls = b < 7584;
        const float* W = cls ? rpn_cls_W1 : rpn_bbox_W1;
        unsigned short* o = cls ? rpn_cW1_b : rpn_bW1_b;
        const int local = b - (cls ? 7552 : 7584);
        const int i0 = local * 1024 + t * 4;
#pragma unroll
        for (int u = 0; u < 4; ++u) {
            const int i = i0 + u;
            const int r = i >> 8, c = i & 255;
            o[i] = (r < 64) ? f2b(W[r * 256 + c]) : (unsigned short)0;
        }
    } else if (b == 7616) {
        if (t < 128)      bias_pad_c[t] = (t < 64) ? rpn_cls_b1[t] : 0.f;
        else              bias_pad_b[t - 128] = ((t - 128) < 64) ? rpn_bbox_b1[t - 128] : 0.f;
        if (t < 4) out[184 + t] = 0.f;
    } else {
        // delta pad: Db[4096][32] bf16, cols 0..3 = deltas, rest 0
        const int row = (b - 7617) * 256 + t;
        const int mat = row >> 12, r = row & 4095;
        const float* D = mat ? rpn_del : roi_del;
        unsigned short* o = mat ? Db_rpn : Db_roi;
        const float4 dv = *(const float4*)&D[(size_t)r * 4];
        ushort4 d4; d4.x = f2b(dv.x); d4.y = f2b(dv.y); d4.z = f2b(dv.z); d4.w = f2b(dv.w);
        unsigned short* p = o + (size_t)r * 32;
        *(ushort4*)p = d4;
        *(ushort4*)(p + 4) = ushort4{0,0,0,0};
        ushort4 z4 = {0,0,0,0};
        *(ushort4*)(p + 8)  = z4; *(ushort4*)(p + 12) = z4;
        *(ushort4*)(p + 16) = z4; *(ushort4*)(p + 20) = z4;
        *(ushort4*)(p + 24) = z4; *(ushort4*)(p + 28) = z4;
    }
}

// ---------------------------------------------------------------------------
// MFMA GEMM with job table (unchanged from R4: conflict-free subtile LDS)
// ---------------------------------------------------------------------------
struct GemmJob {
    const unsigned short *A, *W;
    unsigned short *C;
    const float *bias;
    const float *del, *Wd, *bd, *sc, *Wsc, *bs;
    int lda, ldw, ldc, K, nbx, bstart;
};
struct GemmJobs { GemmJob j[4]; int n; };

template<bool EXTRAS, bool RELU>
__global__ __launch_bounds__(256) void gemm_mfma(GemmJobs jobs)
{
    __shared__ __align__(16) unsigned short As[4096];
    __shared__ __align__(16) unsigned short Bs[4096];
    const int bid = blockIdx.x;
    int ji = 0;
#pragma unroll
    for (int i = 1; i < 4; ++i)
        if (i < jobs.n && bid >= jobs.j[i].bstart) ji = i;
    const GemmJob jb = jobs.j[ji];
    const int local = bid - jb.bstart;
    const int bx = local % jb.nbx, by = local / jb.nbx;
    const int row0 = by * 128, col0 = bx * 128;

    const int t = threadIdx.x, l = t & 63, w = t >> 6;
    const int wr = w >> 1, wc = w & 1;
    const int fr = l & 15, fq = l >> 4;

    const int s0 = 2 * w, s1 = 2 * w + 1;
    const unsigned short* gA0 = jb.A + (size_t)(row0 + s0 * 16 + fr) * jb.lda + fq * 8;
    const unsigned short* gA1 = jb.A + (size_t)(row0 + s1 * 16 + fr) * jb.lda + fq * 8;
    const unsigned short* gW0 = jb.W + (size_t)(col0 + s0 * 16 + fr) * jb.ldw + fq * 8;
    const unsigned short* gW1 = jb.W + (size_t)(col0 + s1 * 16 + fr) * jb.ldw + fq * 8;
    unsigned short* lA0 = As + s0 * 512;
    unsigned short* lA1 = As + s1 * 512;
    unsigned short* lB0 = Bs + s0 * 512;
    unsigned short* lB1 = Bs + s1 * 512;

    f32x4 acc[4][4] = {};

    for (int k0 = 0; k0 < jb.K; k0 += 32) {
        __syncthreads();
        gload16(gA0 + k0, lA0);
        gload16(gA1 + k0, lA1);
        gload16(gW0 + k0, lB0);
        gload16(gW1 + k0, lB1);
        __syncthreads();
        s16x8 af[4], bf[4];
#pragma unroll
        for (int m = 0; m < 4; ++m)
            af[m] = *(const s16x8*)&As[(wr * 4 + m) * 512 + l * 8];
#pragma unroll
        for (int n = 0; n < 4; ++n)
            bf[n] = *(const s16x8*)&Bs[(wc * 4 + n) * 512 + l * 8];
#pragma unroll
        for (int m = 0; m < 4; ++m)
#pragma unroll
            for (int n = 0; n < 4; ++n)
                acc[m][n] = __builtin_amdgcn_mfma_f32_16x16x32_bf16(
                    af[m], bf[n], acc[m][n], 0, 0, 0);
    }

#pragma unroll
    for (int n = 0; n < 4; ++n) {
        const int col = col0 + wc * 64 + n * 16 + fr;
        float cadd = jb.bias[col];
        float wd0 = 0.f, wd1 = 0.f, wd2 = 0.f, wd3 = 0.f, wscv = 0.f;
        if (EXTRAS) {
            cadd += jb.bd[col] + jb.bs[col];
            const float4 w4 = *(const float4*)&jb.Wd[col * 4];
            wd0 = w4.x; wd1 = w4.y; wd2 = w4.z; wd3 = w4.w;
            wscv = jb.Wsc[col];
        }
#pragma unroll
        for (int m = 0; m < 4; ++m) {
#pragma unroll
            for (int j = 0; j < 4; ++j) {
                const int row = row0 + wr * 64 + m * 16 + fq * 4 + j;
                float v = acc[m][n][j] + cadd;
                if (EXTRAS) {
                    const float4 dm = *(const float4*)&jb.del[row * 4];
                    v += dm.x * wd0 + dm.y * wd1 + dm.z * wd2 + dm.w * wd3
                       + jb.sc[row] * wscv;
                }
                if (RELU) v = fmaxf(v, 0.f);
                jb.C[(size_t)row * jb.ldc + col] = f2b(v);
            }
        }
    }
}

// ---------------------------------------------------------------------------
// alphas for all 4 matrices; writes f32 A[4096][8] and bf16 Ab[mat][4096][32]
// (cols 0..7 data, 8..31 zero — the MFMA fragment source for the losses)
// ---------------------------------------------------------------------------
__global__ __launch_bounds__(256) void alphas_all(
    const unsigned short* __restrict__ h_rpn_c, const unsigned short* __restrict__ h_rpn_b,
    const unsigned short* __restrict__ h_roi_c, const unsigned short* __restrict__ h_roi_b,
    const float* __restrict__ W2_rc, const float* __restrict__ W2_rb,
    const float* __restrict__ W2_oc,
    const float* __restrict__ b2_rc, const float* __restrict__ b2_rb,
    const float* __restrict__ b2_oc,
    const int* __restrict__ iter_ptr,
    float* __restrict__ A_rpn_c, float* __restrict__ A_rpn_b,
    float* __restrict__ A_roi_c, float* __restrict__ A_roi_b,
    unsigned short* __restrict__ Ab_all)
{
    const int vrow = blockIdx.x * 4 + (threadIdx.x >> 6);
    const int mat = vrow >> 12, row = vrow & 4095;
    const unsigned short* H; const float *W2, *b2; float* Ao; int ldh, Hd;
    if (mat == 0)      { H = h_rpn_c; W2 = W2_rc; b2 = b2_rc; Ao = A_rpn_c; ldh = 128; Hd = 64; }
    else if (mat == 1) { H = h_rpn_b; W2 = W2_rb; b2 = b2_rb; Ao = A_rpn_b; ldh = 128; Hd = 64; }
    else if (mat == 2) { H = h_roi_c; W2 = W2_oc; b2 = b2_oc; Ao = A_roi_c; ldh = 256; Hd = 256; }
    else               { H = h_roi_b; W2 = W2_oc; b2 = b2_oc; Ao = A_roi_b; ldh = 256; Hd = 256; }

    const int l = threadIdx.x & 63;
    float acc[8] = {};
    for (int m = l * 4; m < Hd; m += 256) {
        const ushort4 h4 = *(const ushort4*)&H[(size_t)row * ldh + m];
        const float h0 = b2f(h4.x), h1 = b2f(h4.y), h2 = b2f(h4.z), h3 = b2f(h4.w);
#pragma unroll
        for (int o = 0; o < 8; ++o) {
            const float4 w4 = *(const float4*)&W2[o * Hd + m];
            acc[o] += h0 * w4.x + h1 * w4.y + h2 * w4.z + h3 * w4.w;
        }
    }
#pragma unroll
    for (int o = 0; o < 8; ++o)
        for (int off = 32; off; off >>= 1)
            acc[o] += __shfl_xor(acc[o], off, 64);

    const int it = *iter_ptr;
    const float temp = fmaxf(1.0f, 30.0f * (float)(90000 - it) / 90000.0f);
    float lg[8], mx = -1e30f;
#pragma unroll
    for (int o = 0; o < 8; ++o) { lg[o] = (acc[o] + b2[o]) / temp; mx = fmaxf(mx, lg[o]); }
    float s = 0.f;
#pragma unroll
    for (int o = 0; o < 8; ++o) { lg[o] = __expf(lg[o] - mx); s += lg[o]; }
    const float inv = 1.0f / s;
    if (l < 8) Ao[(size_t)row * 8 + l] = lg[l] * inv;
    unsigned short* Ab = Ab_all + (size_t)mat * 131072 + (size_t)row * 32;
    if (l == 0) {
        ushort4 o0, o1;
        o0.x = f2b(lg[0]*inv); o0.y = f2b(lg[1]*inv); o0.z = f2b(lg[2]*inv); o0.w = f2b(lg[3]*inv);
        o1.x = f2b(lg[4]*inv); o1.y = f2b(lg[5]*inv); o1.z = f2b(lg[6]*inv); o1.w = f2b(lg[7]*inv);
        *(ushort4*)Ab = o0; *(ushort4*)(Ab + 4) = o1;
    } else if (l < 4) {
        ushort4 z = {0,0,0,0};
        *(ushort4*)(Ab + l * 8)     = z;
        *(ushort4*)(Ab + l * 8 + 4) = z;
    }
}

// ---------------------------------------------------------------------------
// finale: MFMA-driven losses + means.  516 blocks:
//   0..127   roi_cls  -> out[184]     128..255 rpn_cls  -> out[185]
//   256..383 roi_bbox -> out[186]     384..511 rpn_bbox -> out[187]
//   512..514 column means; 515 per-class means of A_roi_c
// Loss block: 2 j-tiles (32 j), 4 waves split k in quarters; per 16-k chunk
// one mfma(Ak_frag, Aj_frag, 0) gives G tile: lane=(fq,fr) holds
// G[k=kb+fq*4+r][j=j0+jt*16+fr], r=0..3.
// ---------------------------------------------------------------------------
__global__ __launch_bounds__(256) void finale_kernel(
    const unsigned short* __restrict__ Ab_all,
    const unsigned short* __restrict__ Db_roi, const unsigned short* __restrict__ Db_rpn,
    const float* __restrict__ A_roi_c, const float* __restrict__ A_rpn_c,
    const float* __restrict__ A_roi_b, const float* __restrict__ A_rpn_b,
    const int* __restrict__ roi_class, const int* __restrict__ rpn_class,
    float* __restrict__ out)
{
    const int b = blockIdx.x, t = threadIdx.x;
    const int w = t >> 6, l = t & 63;
    const int fr = l & 15, fq = l >> 4;

    if (b < 512) {
        __shared__ float sh[4][2][16][3];
        __shared__ float lsum[32];
        const bool is_cls = b < 256;
        const int li = b >> 7;                 // 0..3 loss index
        const int blk = b & 127;
        const int j0 = blk * 32;
        // mat index in Ab_all: roi_cls->2, rpn_cls->0, roi_bbox->3, rpn_bbox->1
        const int mat = (li == 0) ? 2 : (li == 1) ? 0 : (li == 2) ? 3 : 1;
        const unsigned short* Ab = Ab_all + (size_t)mat * 131072;
        const unsigned short* Db = (li == 2) ? Db_roi : Db_rpn;
        const int* cls = (li == 0) ? roi_class : rpn_class;
        float* outp = out + 184 + li;

        // j-side fragments (fixed per wave)
        s16x8 bj[2], dj[2];
        int cj[2];
#pragma unroll
        for (int jt = 0; jt < 2; ++jt) {
            const int j = j0 + jt * 16;
            bj[jt] = *(const s16x8*)&Ab[(size_t)(j + fr) * 32 + fq * 8];
            if (is_cls) cj[jt] = cls[j + fr];
            else        dj[jt] = *(const s16x8*)&Db[(size_t)(j + fr) * 32 + fq * 8];
        }

        float Sx[2] = {}, W2s[2] = {}, U[2] = {};   // W2s = Cg (cls) or Sg (bbox)
        const int kbase0 = w * 1024;
        const f32x4 zc = {0.f, 0.f, 0.f, 0.f};

        for (int ch = 0; ch < 64; ++ch) {
            const int kb = kbase0 + ch * 16;
            const s16x8 afr = *(const s16x8*)&Ab[(size_t)(kb + fr) * 32 + fq * 8];
            if (is_cls) {
                const int4 ck = *(const int4*)&cls[kb + fq * 4];
                const int ckr[4] = {ck.x, ck.y, ck.z, ck.w};
#pragma unroll
                for (int jt = 0; jt < 2; ++jt) {
                    const f32x4 g = __builtin_amdgcn_mfma_f32_16x16x32_bf16(afr, bj[jt], zc, 0, 0, 0);
#pragma unroll
                    for (int r = 0; r < 4; ++r) {
                        const float gv = g[r];
                        Sx[jt] += __expf(2.f * gv);
                        const float wgt = (ckr[r] == cj[jt]) ? E2 : 1.0f;
                        U[jt] = fmaf(wgt, gv, U[jt]);
                        W2s[jt] += wgt;
                    }
                }
            } else {
                const s16x8 dfr = *(const s16x8*)&Db[(size_t)(kb + fr) * 32 + fq * 8];
#pragma unroll
                for (int jt = 0; jt < 2; ++jt) {
                    const f32x4 g  = __builtin_amdgcn_mfma_f32_16x16x32_bf16(afr, bj[jt], zc, 0, 0, 0);
                    const f32x4 gd = __builtin_amdgcn_mfma_f32_16x16x32_bf16(dfr, dj[jt], zc, 0, 0, 0);
#pragma unroll
                    for (int r = 0; r < 4; ++r) {
                        const float gv = g[r];
                        const float ed = __expf(2.f * gd[r]);
                        Sx[jt] += __expf(2.f * gv);
                        W2s[jt] += ed;
                        U[jt] = fmaf(ed, gv, U[jt]);
                    }
                }
            }
        }

        // reduce the 4 lane-groups (disjoint k rows) for same j
#pragma unroll
        for (int jt = 0; jt < 2; ++jt) {
            float vx = Sx[jt], vg = W2s[jt], vu = U[jt];
            for (int off = 16; off <= 32; off <<= 1) {
                vx += __shfl_xor(vx, off, 64);
                vg += __shfl_xor(vg, off, 64);
                vu += __shfl_xor(vu, off, 64);
            }
            if (fq == 0) {
                sh[w][jt][fr][0] = vx; sh[w][jt][fr][1] = vg; sh[w][jt][fr][2] = vu;
            }
        }
        __syncthreads();
        if (t < 32) {
            const int jt = t >> 4, jl = t & 15;
            float vx = 0.f, vg = 0.f, vu = 0.f;
#pragma unroll
            for (int wv = 0; wv < 4; ++wv) {
                vx += sh[wv][jt][jl][0]; vg += sh[wv][jt][jl][1]; vu += sh[wv][jt][jl][2];
            }
            lsum[t] = (2.f * vu - __logf(vx + NEPS) * vg) / (vg + NEPS);
        }
        __syncthreads();
        if (t == 0) {
            float s = 0.f;
            for (int i = 0; i < 32; ++i) s += lsum[i];
            atomicAdd(outp, -s / 4096.f);
        }
    } else if (b < 515) {
        // -------- column means --------
        __shared__ float S4[4][8];
        const float* A = (b == 512) ? A_rpn_c : (b == 513) ? A_rpn_b : A_roi_b;
        const int off0 = (b == 512) ? 0 : (b == 513) ? 8 : 176;
        float acc[8] = {};
        for (int r = t; r < NPTS; r += 256) {
            const float4 v0 = *(const float4*)&A[(size_t)r * 8];
            const float4 v1 = *(const float4*)&A[(size_t)r * 8 + 4];
            acc[0]+=v0.x; acc[1]+=v0.y; acc[2]+=v0.z; acc[3]+=v0.w;
            acc[4]+=v1.x; acc[5]+=v1.y; acc[6]+=v1.z; acc[7]+=v1.w;
        }
#pragma unroll
        for (int o = 0; o < 8; ++o) {
            float v = acc[o];
            for (int offs = 32; offs; offs >>= 1) v += __shfl_xor(v, offs, 64);
            if (l == 0) S4[w][o] = v;
        }
        __syncthreads();
        if (t < 8) {
            const float s = S4[0][t] + S4[1][t] + S4[2][t] + S4[3][t];
            out[off0 + t] = s * (1.f / 4096.f);
        }
    } else {
        // -------- per-class means of A_roi_c --------
        __shared__ float S[20][8];
        __shared__ float cnt[20];
        if (t < 160) ((float*)S)[t] = 0.f;
        if (t < 20) cnt[t] = 0.f;
        __syncthreads();
        for (int r = t; r < NPTS; r += 256) {
            const int c = roi_class[r];
            atomicAdd(&cnt[c], 1.0f);
            const float4 v0 = *(const float4*)&A_roi_c[(size_t)r * 8];
            const float4 v1 = *(const float4*)&A_roi_c[(size_t)r * 8 + 4];
            atomicAdd(&S[c][0], v0.x); atomicAdd(&S[c][1], v0.y);
            atomicAdd(&S[c][2], v0.z); atomicAdd(&S[c][3], v0.w);
            atomicAdd(&S[c][4], v1.x); atomicAdd(&S[c][5], v1.y);
            atomicAdd(&S[c][6], v1.z); atomicAdd(&S[c][7], v1.w);
        }
        __syncthreads();
        if (t < 160) {
            const int c = t >> 3;
            out[16 + t] = S[c][t & 7] / fmaxf(cnt[c], 1.f);
        }
    }
}

// ---------------------------------------------------------------------------
extern "C" void kernel_launch(void* const* d_in, const int* in_sizes, int n_in,
                              void* d_out, int out_size, void* d_ws, size_t ws_size,
                              hipStream_t stream)
{
    const float* rpn_feat  = (const float*)d_in[0];
    const float* rpn_del   = (const float*)d_in[1];
    const float* rpn_scale = (const float*)d_in[2];
    const float* roi_feat  = (const float*)d_in[3];
    const float* roi_del   = (const float*)d_in[4];
    const float* roi_scale = (const float*)d_in[5];
    const int*   rpn_class = (const int*)d_in[6];
    const int*   roi_class = (const int*)d_in[7];
    const float* W_rpn_feat = (const float*)d_in[8];  const float* b_rpn_feat = (const float*)d_in[9];
    const float* W_rpn_del  = (const float*)d_in[10]; const float* b_rpn_del  = (const float*)d_in[11];
    const float* W_rpn_sc   = (const float*)d_in[12]; const float* b_rpn_sc   = (const float*)d_in[13];
    const float* W_roi_feat = (const float*)d_in[14]; const float* b_roi_feat = (const float*)d_in[15];
    const float* W_roi_del  = (const float*)d_in[16]; const float* b_roi_del  = (const float*)d_in[17];
    const float* W_roi_sc   = (const float*)d_in[18]; const float* b_roi_sc   = (const float*)d_in[19];
    const float* rpn_cls_W1  = (const float*)d_in[20]; const float* rpn_cls_b1  = (const float*)d_in[21];
    const float* rpn_cls_W2  = (const float*)d_in[22]; const float* rpn_cls_b2  = (const float*)d_in[23];
    const float* rpn_bbox_W1 = (const float*)d_in[24]; const float* rpn_bbox_b1 = (const float*)d_in[25];
    const float* rpn_bbox_W2 = (const float*)d_in[26]; const float* rpn_bbox_b2 = (const float*)d_in[27];
    const float* roi_cls_W1  = (const float*)d_in[28]; const float* roi_cls_b1  = (const float*)d_in[29];
    const float* roi_cls_W2  = (const float*)d_in[30]; const float* roi_cls_b2  = (const float*)d_in[31];
    const int* iter_ptr = (const int*)d_in[32];
    float* out = (float*)d_out;
    char*  wsb = (char*)d_ws;

    // ---- workspace layout (byte offsets) ----
    // Ab_all overlaps roi_feat_b region: roi_feat_b is dead after launch 2;
    // Ab_all is written in launch 4, read in launch 5.
    unsigned short* roi_feat_b   = (unsigned short*)(wsb + 0);          // 4096x1024
    unsigned short* Ab_all       = (unsigned short*)(wsb + 0);          // 4 x 4096x32 (launch 4+)
    unsigned short* W_roi_feat_b = (unsigned short*)(wsb + 8388608);    // 2048x1024
    unsigned short* roi_sum_b    = (unsigned short*)(wsb + 12582912);   // 4096x2048
    unsigned short* roi_W1_b     = (unsigned short*)(wsb + 29360128);   // 256x1024
    unsigned short* h_roi_c      = (unsigned short*)(wsb + 29884416);   // 4096x256
    unsigned short* h_roi_b      = (unsigned short*)(wsb + 31981568);   // 4096x256
    unsigned short* rpn_feat_b   = (unsigned short*)(wsb + 34078720);   // 4096x256
    unsigned short* W_rpn_feat_b = (unsigned short*)(wsb + 36175872);   // 512x256
    unsigned short* rpn_sum_b    = (unsigned short*)(wsb + 36438016);   // 4096x512
    unsigned short* rpn_cW1_b    = (unsigned short*)(wsb + 40632320);   // 128x256 padded
    unsigned short* rpn_bW1_b    = (unsigned short*)(wsb + 40697856);   // 128x256 padded
    unsigned short* h_rpn_c      = (unsigned short*)(wsb + 40763392);   // 4096x128
    unsigned short* h_rpn_b      = (unsigned short*)(wsb + 41811968);   // 4096x128
    float* bias_pad_c = (float*)(wsb + 42860544);                       // 128
    float* bias_pad_b = (float*)(wsb + 42861056);                       // 128
    float* A_rpn_c    = (float*)(wsb + 42861568);                       // 4096x8
    float* A_rpn_b    = (float*)(wsb + 42992640);
    float* A_roi_c    = (float*)(wsb + 43123712);
    float* A_roi_b    = (float*)(wsb + 43254784);
    unsigned short* Db_roi = (unsigned short*)(wsb + 43385856);         // 4096x32
    unsigned short* Db_rpn = (unsigned short*)(wsb + 43648000);         // 4096x32

    // ---- 1: prep ----
    prep_kernel<<<dim3(7649), 256, 0, stream>>>(
        roi_feat, W_roi_feat, roi_cls_W1, rpn_feat, W_rpn_feat,
        rpn_cls_W1, rpn_bbox_W1, rpn_cls_b1, rpn_bbox_b1,
        roi_del, rpn_del,
        roi_feat_b, W_roi_feat_b, roi_W1_b, rpn_feat_b, W_rpn_feat_b,
        rpn_cW1_b, rpn_bW1_b, Db_roi, Db_rpn, bias_pad_c, bias_pad_b, out);

    // ---- 2: both big GEMMs (extras fused) ----
    {
        GemmJobs js;
        js.n = 2;
        js.j[0] = { rpn_feat_b, W_rpn_feat_b, rpn_sum_b, b_rpn_feat,
                    rpn_del, W_rpn_del, b_rpn_del, rpn_scale, W_rpn_sc, b_rpn_sc,
                    256, 256, 512, 256, 4, 0 };
        js.j[1] = { roi_feat_b, W_roi_feat_b, roi_sum_b, b_roi_feat,
                    roi_del, W_roi_del, b_roi_del, roi_scale, W_roi_sc, b_roi_sc,
                    1024, 1024, 2048, 1024, 16, 128 };
        js.j[2] = js.j[0]; js.j[3] = js.j[0];
        gemm_mfma<true, false><<<dim3(640), 256, 0, stream>>>(js);
    }

    // ---- 3: all 4 hidden GEMMs (relu fused) ----
    {
        GemmJobs js;
        js.n = 4;
        js.j[0] = { rpn_sum_b,        rpn_cW1_b, h_rpn_c, bias_pad_c,
                    nullptr, nullptr, nullptr, nullptr, nullptr, nullptr,
                    512, 256, 128, 256, 1, 0 };
        js.j[1] = { rpn_sum_b + 256,  rpn_bW1_b, h_rpn_b, bias_pad_b,
                    nullptr, nullptr, nullptr, nullptr, nullptr, nullptr,
                    512, 256, 128, 256, 1, 32 };
        js.j[2] = { roi_sum_b,        roi_W1_b, h_roi_c, roi_cls_b1,
                    nullptr, nullptr, nullptr, nullptr, nullptr, nullptr,
                    2048, 1024, 256, 1024, 2, 64 };
        // reference bug: bbox half also uses roi_cls W1/b1 (and W2/b2 below)
        js.j[3] = { roi_sum_b + 1024, roi_W1_b, h_roi_b, roi_cls_b1,
                    nullptr, nullptr, nullptr, nullptr, nullptr, nullptr,
                    2048, 1024, 256, 1024, 2, 128 };
        gemm_mfma<false, true><<<dim3(192), 256, 0, stream>>>(js);
    }

    // ---- 4: all 4 alphas (f32 + padded bf16) ----
    alphas_all<<<dim3(4096), 256, 0, stream>>>(
        h_rpn_c, h_rpn_b, h_roi_c, h_roi_b,
        rpn_cls_W2, rpn_bbox_W2, roi_cls_W2,
        rpn_cls_b2, rpn_bbox_b2, roi_cls_b2,
        iter_ptr, A_rpn_c, A_rpn_b, A_roi_c, A_roi_b, Ab_all);

    // ---- 5: MFMA losses + means ----
    finale_kernel<<<dim3(516), 256, 0, stream>>>(
        Ab_all, Db_roi, Db_rpn,
        A_roi_c, A_rpn_c, A_roi_b, A_rpn_b,
        roi_class, rpn_class, out);
}

// Round 6
// 174.178 us; speedup vs baseline: 3.6634x; 1.0386x over previous
//
#include <hip/hip_runtime.h>
#include <math.h>

#define NPTS 4096
#define NEPS 4.096e-4f                 // 4096 * 1e-7
#define E2   7.3890560989306495f       // exp(2)

typedef float  f32x4 __attribute__((ext_vector_type(4)));
typedef short  s16x8 __attribute__((ext_vector_type(8)));

static __device__ __forceinline__ unsigned short f2b(float x) {
    unsigned u = __builtin_bit_cast(unsigned, x);
    return (unsigned short)((u + 0x7fffu + ((u >> 16) & 1u)) >> 16);
}
static __device__ __forceinline__ float b2f(unsigned short h) {
    return __builtin_bit_cast(float, (unsigned)h << 16);
}

static __device__ __forceinline__ void gload16(const unsigned short* g, unsigned short* lds) {
    __builtin_amdgcn_global_load_lds(
        (const __attribute__((address_space(1))) void*)g,
        (__attribute__((address_space(3))) void*)lds, 16, 0, 0);
}

// ---------------------------------------------------------------------------
// prep: f32->bf16 converts + rpn W1 pads + bias pads + delta pads + loss zero
// ---------------------------------------------------------------------------
__global__ __launch_bounds__(256) void prep_kernel(
    const float* __restrict__ roi_feat, const float* __restrict__ W_roi_feat,
    const float* __restrict__ roi_cls_W1,
    const float* __restrict__ rpn_feat, const float* __restrict__ W_rpn_feat,
    const float* __restrict__ rpn_cls_W1, const float* __restrict__ rpn_bbox_W1,
    const float* __restrict__ rpn_cls_b1, const float* __restrict__ rpn_bbox_b1,
    const float* __restrict__ roi_del, const float* __restrict__ rpn_del,
    unsigned short* __restrict__ roi_feat_b, unsigned short* __restrict__ W_roi_feat_b,
    unsigned short* __restrict__ roi_W1_b,
    unsigned short* __restrict__ rpn_feat_b, unsigned short* __restrict__ W_rpn_feat_b,
    unsigned short* __restrict__ rpn_cW1_b, unsigned short* __restrict__ rpn_bW1_b,
    unsigned short* __restrict__ Db_roi, unsigned short* __restrict__ Db_rpn,
    float* __restrict__ bias_pad_c, float* __restrict__ bias_pad_b,
    float* __restrict__ out)
{
    const int b = blockIdx.x, t = threadIdx.x;
    if (b < 7552) {
        const float* in; unsigned short* o; int base;
        if      (b < 4096) { in = roi_feat;   o = roi_feat_b;   base = b; }
        else if (b < 6144) { in = W_roi_feat; o = W_roi_feat_b; base = b - 4096; }
        else if (b < 6400) { in = roi_cls_W1; o = roi_W1_b;     base = b - 6144; }
        else if (b < 7424) { in = rpn_feat;   o = rpn_feat_b;   base = b - 6400; }
        else               { in = W_rpn_feat; o = W_rpn_feat_b; base = b - 7424; }
        const int i = base * 1024 + t * 4;
        const float4 v = *(const float4*)&in[i];
        ushort4 ov;
        ov.x = f2b(v.x); ov.y = f2b(v.y); ov.z = f2b(v.z); ov.w = f2b(v.w);
        *(ushort4*)&o[i] = ov;
    } else if (b < 7616) {
        const bool cls = b < 7584;
        const float* W = cls ? rpn_cls_W1 : rpn_bbox_W1;
        unsigned short* o = cls ? rpn_cW1_b : rpn_bW1_b;
        const int local = b - (cls ? 7552 : 7584);
        const int i0 = local * 1024 + t * 4;
#pragma unroll
        for (int u = 0; u < 4; ++u) {
            const int i = i0 + u;
            const int r = i >> 8, c = i & 255;
            o[i] = (r < 64) ? f2b(W[r * 256 + c]) : (unsigned short)0;
        }
    } else if (b == 7616) {
        if (t < 128)      bias_pad_c[t] = (t < 64) ? rpn_cls_b1[t] : 0.f;
        else              bias_pad_b[t - 128] = ((t - 128) < 64) ? rpn_bbox_b1[t - 128] : 0.f;
        if (t < 4) out[184 + t] = 0.f;
    } else {
        // delta pad: Db[4096][32] bf16, cols 0..3 = deltas, rest 0
        const int row = (b - 7617) * 256 + t;
        const int mat = row >> 12, r = row & 4095;
        const float* D = mat ? rpn_del : roi_del;
        unsigned short* o = mat ? Db_rpn : Db_roi;
        const float4 dv = *(const float4*)&D[(size_t)r * 4];
        ushort4 d4; d4.x = f2b(dv.x); d4.y = f2b(dv.y); d4.z = f2b(dv.z); d4.w = f2b(dv.w);
        unsigned short* p = o + (size_t)r * 32;
        ushort4 z4 = {0,0,0,0};
        *(ushort4*)p = d4;
        *(ushort4*)(p + 4)  = z4;
        *(ushort4*)(p + 8)  = z4; *(ushort4*)(p + 12) = z4;
        *(ushort4*)(p + 16) = z4; *(ushort4*)(p + 20) = z4;
        *(ushort4*)(p + 24) = z4; *(ushort4*)(p + 28) = z4;
    }
}

// ---------------------------------------------------------------------------
// MFMA GEMM, 2-phase double-buffered (T3 minimum recipe):
//   prologue STAGE(buf0); per K-step: STAGE(next -> buf^1) issued FIRST,
//   then ds_read+MFMA on buf[cur], then one __syncthreads (vmcnt drain).
// Conflict-free subtile LDS layout (chunk l = T[s*16+(l&15)][(l>>4)*8..+8)).
// ---------------------------------------------------------------------------
struct GemmJob {
    const unsigned short *A, *W;
    unsigned short *C;
    const float *bias;
    const float *del, *Wd, *bd, *sc, *Wsc, *bs;
    int lda, ldw, ldc, K, nbx, bstart;
};
struct GemmJobs { GemmJob j[4]; int n; };

template<bool EXTRAS, bool RELU>
__global__ __launch_bounds__(256) void gemm_mfma(GemmJobs jobs)
{
    __shared__ __align__(16) unsigned short As[8192];   // 2 bufs x 8 subtiles x 512
    __shared__ __align__(16) unsigned short Bs[8192];
    const int bid = blockIdx.x;
    int ji = 0;
#pragma unroll
    for (int i = 1; i < 4; ++i)
        if (i < jobs.n && bid >= jobs.j[i].bstart) ji = i;
    const GemmJob jb = jobs.j[ji];
    const int local = bid - jb.bstart;
    const int bx = local % jb.nbx, by = local / jb.nbx;
    const int row0 = by * 128, col0 = bx * 128;

    const int t = threadIdx.x, l = t & 63, w = t >> 6;
    const int wr = w >> 1, wc = w & 1;
    const int fr = l & 15, fq = l >> 4;

    const int s0 = 2 * w, s1 = 2 * w + 1;
    const unsigned short* gA0 = jb.A + (size_t)(row0 + s0 * 16 + fr) * jb.lda + fq * 8;
    const unsigned short* gA1 = jb.A + (size_t)(row0 + s1 * 16 + fr) * jb.lda + fq * 8;
    const unsigned short* gW0 = jb.W + (size_t)(col0 + s0 * 16 + fr) * jb.ldw + fq * 8;
    const unsigned short* gW1 = jb.W + (size_t)(col0 + s1 * 16 + fr) * jb.ldw + fq * 8;

    f32x4 acc[4][4] = {};

    // prologue: stage tile 0 into buffer 0
    gload16(gA0, As + s0 * 512);
    gload16(gA1, As + s1 * 512);
    gload16(gW0, Bs + s0 * 512);
    gload16(gW1, Bs + s1 * 512);
    __syncthreads();

    int cur = 0;
    for (int k0 = 0; k0 < jb.K; k0 += 32) {
        // issue next-tile stage FIRST (hides HBM latency under compute)
        if (k0 + 32 < jb.K) {
            const int nb = (cur ^ 1) * 4096;
            gload16(gA0 + k0 + 32, As + nb + s0 * 512);
            gload16(gA1 + k0 + 32, As + nb + s1 * 512);
            gload16(gW0 + k0 + 32, Bs + nb + s0 * 512);
            gload16(gW1 + k0 + 32, Bs + nb + s1 * 512);
        }
        const unsigned short* Asc = As + cur * 4096;
        const unsigned short* Bsc = Bs + cur * 4096;
        s16x8 af[4], bf[4];
#pragma unroll
        for (int m = 0; m < 4; ++m)
            af[m] = *(const s16x8*)&Asc[(wr * 4 + m) * 512 + l * 8];
#pragma unroll
        for (int n = 0; n < 4; ++n)
            bf[n] = *(const s16x8*)&Bsc[(wc * 4 + n) * 512 + l * 8];
#pragma unroll
        for (int m = 0; m < 4; ++m)
#pragma unroll
            for (int n = 0; n < 4; ++n)
                acc[m][n] = __builtin_amdgcn_mfma_f32_16x16x32_bf16(
                    af[m], bf[n], acc[m][n], 0, 0, 0);
        __syncthreads();   // drains stage (vmcnt0) + protects buf reuse
        cur ^= 1;
    }

    // epilogue: row = row0+wr*64+m*16+fq*4+j ; col = col0+wc*64+n*16+fr
#pragma unroll
    for (int n = 0; n < 4; ++n) {
        const int col = col0 + wc * 64 + n * 16 + fr;
        float cadd = jb.bias[col];
        float wd0 = 0.f, wd1 = 0.f, wd2 = 0.f, wd3 = 0.f, wscv = 0.f;
        if (EXTRAS) {
            cadd += jb.bd[col] + jb.bs[col];
            const float4 w4 = *(const float4*)&jb.Wd[col * 4];
            wd0 = w4.x; wd1 = w4.y; wd2 = w4.z; wd3 = w4.w;
            wscv = jb.Wsc[col];
        }
#pragma unroll
        for (int m = 0; m < 4; ++m) {
#pragma unroll
            for (int j = 0; j < 4; ++j) {
                const int row = row0 + wr * 64 + m * 16 + fq * 4 + j;
                float v = acc[m][n][j] + cadd;
                if (EXTRAS) {
                    const float4 dm = *(const float4*)&jb.del[row * 4];
                    v += dm.x * wd0 + dm.y * wd1 + dm.z * wd2 + dm.w * wd3
                       + jb.sc[row] * wscv;
                }
                if (RELU) v = fmaxf(v, 0.f);
                jb.C[(size_t)row * jb.ldc + col] = f2b(v);
            }
        }
    }
}

// ---------------------------------------------------------------------------
// alphas for all 4 matrices; writes f32 A[4096][8] and bf16 Ab[mat][4096][32]
// ---------------------------------------------------------------------------
__global__ __launch_bounds__(256) void alphas_all(
    const unsigned short* __restrict__ h_rpn_c, const unsigned short* __restrict__ h_rpn_b,
    const unsigned short* __restrict__ h_roi_c, const unsigned short* __restrict__ h_roi_b,
    const float* __restrict__ W2_rc, const float* __restrict__ W2_rb,
    const float* __restrict__ W2_oc,
    const float* __restrict__ b2_rc, const float* __restrict__ b2_rb,
    const float* __restrict__ b2_oc,
    const int* __restrict__ iter_ptr,
    float* __restrict__ A_rpn_c, float* __restrict__ A_rpn_b,
    float* __restrict__ A_roi_c, float* __restrict__ A_roi_b,
    unsigned short* __restrict__ Ab_all)
{
    const int vrow = blockIdx.x * 4 + (threadIdx.x >> 6);
    const int mat = vrow >> 12, row = vrow & 4095;
    const unsigned short* H; const float *W2, *b2; float* Ao; int ldh, Hd;
    if (mat == 0)      { H = h_rpn_c; W2 = W2_rc; b2 = b2_rc; Ao = A_rpn_c; ldh = 128; Hd = 64; }
    else if (mat == 1) { H = h_rpn_b; W2 = W2_rb; b2 = b2_rb; Ao = A_rpn_b; ldh = 128; Hd = 64; }
    else if (mat == 2) { H = h_roi_c; W2 = W2_oc; b2 = b2_oc; Ao = A_roi_c; ldh = 256; Hd = 256; }
    else               { H = h_roi_b; W2 = W2_oc; b2 = b2_oc; Ao = A_roi_b; ldh = 256; Hd = 256; }

    const int l = threadIdx.x & 63;
    float acc[8] = {};
    for (int m = l * 4; m < Hd; m += 256) {
        const ushort4 h4 = *(const ushort4*)&H[(size_t)row * ldh + m];
        const float h0 = b2f(h4.x), h1 = b2f(h4.y), h2 = b2f(h4.z), h3 = b2f(h4.w);
#pragma unroll
        for (int o = 0; o < 8; ++o) {
            const float4 w4 = *(const float4*)&W2[o * Hd + m];
            acc[o] += h0 * w4.x + h1 * w4.y + h2 * w4.z + h3 * w4.w;
        }
    }
#pragma unroll
    for (int o = 0; o < 8; ++o)
        for (int off = 32; off; off >>= 1)
            acc[o] += __shfl_xor(acc[o], off, 64);

    const int it = *iter_ptr;
    const float temp = fmaxf(1.0f, 30.0f * (float)(90000 - it) / 90000.0f);
    float lg[8], mx = -1e30f;
#pragma unroll
    for (int o = 0; o < 8; ++o) { lg[o] = (acc[o] + b2[o]) / temp; mx = fmaxf(mx, lg[o]); }
    float s = 0.f;
#pragma unroll
    for (int o = 0; o < 8; ++o) { lg[o] = __expf(lg[o] - mx); s += lg[o]; }
    const float inv = 1.0f / s;
    if (l < 8) Ao[(size_t)row * 8 + l] = lg[l] * inv;
    unsigned short* Ab = Ab_all + (size_t)mat * 131072 + (size_t)row * 32;
    if (l == 0) {
        ushort4 o0, o1;
        o0.x = f2b(lg[0]*inv); o0.y = f2b(lg[1]*inv); o0.z = f2b(lg[2]*inv); o0.w = f2b(lg[3]*inv);
        o1.x = f2b(lg[4]*inv); o1.y = f2b(lg[5]*inv); o1.z = f2b(lg[6]*inv); o1.w = f2b(lg[7]*inv);
        *(ushort4*)Ab = o0; *(ushort4*)(Ab + 4) = o1;
    } else if (l < 4) {
        ushort4 z = {0,0,0,0};
        *(ushort4*)(Ab + l * 8)     = z;
        *(ushort4*)(Ab + l * 8 + 4) = z;
    }
}

// ---------------------------------------------------------------------------
// finale: MFMA losses + means (unchanged from R5)
// ---------------------------------------------------------------------------
__global__ __launch_bounds__(256) void finale_kernel(
    const unsigned short* __restrict__ Ab_all,
    const unsigned short* __restrict__ Db_roi, const unsigned short* __restrict__ Db_rpn,
    const float* __restrict__ A_roi_c, const float* __restrict__ A_rpn_c,
    const float* __restrict__ A_roi_b, const float* __restrict__ A_rpn_b,
    const int* __restrict__ roi_class, const int* __restrict__ rpn_class,
    float* __restrict__ out)
{
    const int b = blockIdx.x, t = threadIdx.x;
    const int w = t >> 6, l = t & 63;
    const int fr = l & 15, fq = l >> 4;

    if (b < 512) {
        __shared__ float sh[4][2][16][3];
        __shared__ float lsum[32];
        const bool is_cls = b < 256;
        const int li = b >> 7;
        const int blk = b & 127;
        const int j0 = blk * 32;
        const int mat = (li == 0) ? 2 : (li == 1) ? 0 : (li == 2) ? 3 : 1;
        const unsigned short* Ab = Ab_all + (size_t)mat * 131072;
        const unsigned short* Db = (li == 2) ? Db_roi : Db_rpn;
        const int* cls = (li == 0) ? roi_class : rpn_class;
        float* outp = out + 184 + li;

        s16x8 bj[2], dj[2];
        int cj[2];
#pragma unroll
        for (int jt = 0; jt < 2; ++jt) {
            const int j = j0 + jt * 16;
            bj[jt] = *(const s16x8*)&Ab[(size_t)(j + fr) * 32 + fq * 8];
            if (is_cls) cj[jt] = cls[j + fr];
            else        dj[jt] = *(const s16x8*)&Db[(size_t)(j + fr) * 32 + fq * 8];
        }

        float Sx[2] = {}, W2s[2] = {}, U[2] = {};
        const int kbase0 = w * 1024;
        const f32x4 zc = {0.f, 0.f, 0.f, 0.f};

        for (int ch = 0; ch < 64; ++ch) {
            const int kb = kbase0 + ch * 16;
            const s16x8 afr = *(const s16x8*)&Ab[(size_t)(kb + fr) * 32 + fq * 8];
            if (is_cls) {
                const int4 ck = *(const int4*)&cls[kb + fq * 4];
                const int ckr[4] = {ck.x, ck.y, ck.z, ck.w};
#pragma unroll
                for (int jt = 0; jt < 2; ++jt) {
                    const f32x4 g = __builtin_amdgcn_mfma_f32_16x16x32_bf16(afr, bj[jt], zc, 0, 0, 0);
#pragma unroll
                    for (int r = 0; r < 4; ++r) {
                        const float gv = g[r];
                        Sx[jt] += __expf(2.f * gv);
                        const float wgt = (ckr[r] == cj[jt]) ? E2 : 1.0f;
                        U[jt] = fmaf(wgt, gv, U[jt]);
                        W2s[jt] += wgt;
                    }
                }
            } else {
                const s16x8 dfr = *(const s16x8*)&Db[(size_t)(kb + fr) * 32 + fq * 8];
#pragma unroll
                for (int jt = 0; jt < 2; ++jt) {
                    const f32x4 g  = __builtin_amdgcn_mfma_f32_16x16x32_bf16(afr, bj[jt], zc, 0, 0, 0);
                    const f32x4 gd = __builtin_amdgcn_mfma_f32_16x16x32_bf16(dfr, dj[jt], zc, 0, 0, 0);
#pragma unroll
                    for (int r = 0; r < 4; ++r) {
                        const float gv = g[r];
                        const float ed = __expf(2.f * gd[r]);
                        Sx[jt] += __expf(2.f * gv);
                        W2s[jt] += ed;
                        U[jt] = fmaf(ed, gv, U[jt]);
                    }
                }
            }
        }

#pragma unroll
        for (int jt = 0; jt < 2; ++jt) {
            float vx = Sx[jt], vg = W2s[jt], vu = U[jt];
            for (int off = 16; off <= 32; off <<= 1) {
                vx += __shfl_xor(vx, off, 64);
                vg += __shfl_xor(vg, off, 64);
                vu += __shfl_xor(vu, off, 64);
            }
            if (fq == 0) {
                sh[w][jt][fr][0] = vx; sh[w][jt][fr][1] = vg; sh[w][jt][fr][2] = vu;
            }
        }
        __syncthreads();
        if (t < 32) {
            const int jt = t >> 4, jl = t & 15;
            float vx = 0.f, vg = 0.f, vu = 0.f;
#pragma unroll
            for (int wv = 0; wv < 4; ++wv) {
                vx += sh[wv][jt][jl][0]; vg += sh[wv][jt][jl][1]; vu += sh[wv][jt][jl][2];
            }
            lsum[t] = (2.f * vu - __logf(vx + NEPS) * vg) / (vg + NEPS);
        }
        __syncthreads();
        if (t == 0) {
            float s = 0.f;
            for (int i = 0; i < 32; ++i) s += lsum[i];
            atomicAdd(outp, -s / 4096.f);
        }
    } else if (b < 515) {
        __shared__ float S4[4][8];
        const float* A = (b == 512) ? A_rpn_c : (b == 513) ? A_rpn_b : A_roi_b;
        const int off0 = (b == 512) ? 0 : (b == 513) ? 8 : 176;
        float acc[8] = {};
        for (int r = t; r < NPTS; r += 256) {
            const float4 v0 = *(const float4*)&A[(size_t)r * 8];
            const float4 v1 = *(const float4*)&A[(size_t)r * 8 + 4];
            acc[0]+=v0.x; acc[1]+=v0.y; acc[2]+=v0.z; acc[3]+=v0.w;
            acc[4]+=v1.x; acc[5]+=v1.y; acc[6]+=v1.z; acc[7]+=v1.w;
        }
#pragma unroll
        for (int o = 0; o < 8; ++o) {
            float v = acc[o];
            for (int offs = 32; offs; offs >>= 1) v += __shfl_xor(v, offs, 64);
            if (l == 0) S4[w][o] = v;
        }
        __syncthreads();
        if (t < 8) {
            const float s = S4[0][t] + S4[1][t] + S4[2][t] + S4[3][t];
            out[off0 + t] = s * (1.f / 4096.f);
        }
    } else {
        __shared__ float S[20][8];
        __shared__ float cnt[20];
        if (t < 160) ((float*)S)[t] = 0.f;
        if (t < 20) cnt[t] = 0.f;
        __syncthreads();
        for (int r = t; r < NPTS; r += 256) {
            const int c = roi_class[r];
            atomicAdd(&cnt[c], 1.0f);
            const float4 v0 = *(const float4*)&A_roi_c[(size_t)r * 8];
            const float4 v1 = *(const float4*)&A_roi_c[(size_t)r * 8 + 4];
            atomicAdd(&S[c][0], v0.x); atomicAdd(&S[c][1], v0.y);
            atomicAdd(&S[c][2], v0.z); atomicAdd(&S[c][3], v0.w);
            atomicAdd(&S[c][4], v1.x); atomicAdd(&S[c][5], v1.y);
            atomicAdd(&S[c][6], v1.z); atomicAdd(&S[c][7], v1.w);
        }
        __syncthreads();
        if (t < 160) {
            const int c = t >> 3;
            out[16 + t] = S[c][t & 7] / fmaxf(cnt[c], 1.f);
        }
    }
}

// ---------------------------------------------------------------------------
extern "C" void kernel_launch(void* const* d_in, const int* in_sizes, int n_in,
                              void* d_out, int out_size, void* d_ws, size_t ws_size,
                              hipStream_t stream)
{
    const float* rpn_feat  = (const float*)d_in[0];
    const float* rpn_del   = (const float*)d_in[1];
    const float* rpn_scale = (const float*)d_in[2];
    const float* roi_feat  = (const float*)d_in[3];
    const float* roi_del   = (const float*)d_in[4];
    const float* roi_scale = (const float*)d_in[5];
    const int*   rpn_class = (const int*)d_in[6];
    const int*   roi_class = (const int*)d_in[7];
    const float* W_rpn_feat = (const float*)d_in[8];  const float* b_rpn_feat = (const float*)d_in[9];
    const float* W_rpn_del  = (const float*)d_in[10]; const float* b_rpn_del  = (const float*)d_in[11];
    const float* W_rpn_sc   = (const float*)d_in[12]; const float* b_rpn_sc   = (const float*)d_in[13];
    const float* W_roi_feat = (const float*)d_in[14]; const float* b_roi_feat = (const float*)d_in[15];
    const float* W_roi_del  = (const float*)d_in[16]; const float* b_roi_del  = (const float*)d_in[17];
    const float* W_roi_sc   = (const float*)d_in[18]; const float* b_roi_sc   = (const float*)d_in[19];
    const float* rpn_cls_W1  = (const float*)d_in[20]; const float* rpn_cls_b1  = (const float*)d_in[21];
    const float* rpn_cls_W2  = (const float*)d_in[22]; const float* rpn_cls_b2  = (const float*)d_in[23];
    const float* rpn_bbox_W1 = (const float*)d_in[24]; const float* rpn_bbox_b1 = (const float*)d_in[25];
    const float* rpn_bbox_W2 = (const float*)d_in[26]; const float* rpn_bbox_b2 = (const float*)d_in[27];
    const float* roi_cls_W1  = (const float*)d_in[28]; const float* roi_cls_b1  = (const float*)d_in[29];
    const float* roi_cls_W2  = (const float*)d_in[30]; const float* roi_cls_b2  = (const float*)d_in[31];
    const int* iter_ptr = (const int*)d_in[32];
    float* out = (float*)d_out;
    char*  wsb = (char*)d_ws;

    // ---- workspace layout (byte offsets) ----
    unsigned short* roi_feat_b   = (unsigned short*)(wsb + 0);          // 4096x1024
    unsigned short* Ab_all       = (unsigned short*)(wsb + 0);          // 4 x 4096x32 (launch 4+)
    unsigned short* W_roi_feat_b = (unsigned short*)(wsb + 8388608);    // 2048x1024
    unsigned short* roi_sum_b    = (unsigned short*)(wsb + 12582912);   // 4096x2048
    unsigned short* roi_W1_b     = (unsigned short*)(wsb + 29360128);   // 256x1024
    unsigned short* h_roi_c      = (unsigned short*)(wsb + 29884416);   // 4096x256
    unsigned short* h_roi_b      = (unsigned short*)(wsb + 31981568);   // 4096x256
    unsigned short* rpn_feat_b   = (unsigned short*)(wsb + 34078720);   // 4096x256
    unsigned short* W_rpn_feat_b = (unsigned short*)(wsb + 36175872);   // 512x256
    unsigned short* rpn_sum_b    = (unsigned short*)(wsb + 36438016);   // 4096x512
    unsigned short* rpn_cW1_b    = (unsigned short*)(wsb + 40632320);   // 128x256 padded
    unsigned short* rpn_bW1_b    = (unsigned short*)(wsb + 40697856);   // 128x256 padded
    unsigned short* h_rpn_c      = (unsigned short*)(wsb + 40763392);   // 4096x128
    unsigned short* h_rpn_b      = (unsigned short*)(wsb + 41811968);   // 4096x128
    float* bias_pad_c = (float*)(wsb + 42860544);                       // 128
    float* bias_pad_b = (float*)(wsb + 42861056);                       // 128
    float* A_rpn_c    = (float*)(wsb + 42861568);                       // 4096x8
    float* A_rpn_b    = (float*)(wsb + 42992640);
    float* A_roi_c    = (float*)(wsb + 43123712);
    float* A_roi_b    = (float*)(wsb + 43254784);
    unsigned short* Db_roi = (unsigned short*)(wsb + 43385856);         // 4096x32
    unsigned short* Db_rpn = (unsigned short*)(wsb + 43648000);         // 4096x32

    // ---- 1: prep ----
    prep_kernel<<<dim3(7649), 256, 0, stream>>>(
        roi_feat, W_roi_feat, roi_cls_W1, rpn_feat, W_rpn_feat,
        rpn_cls_W1, rpn_bbox_W1, rpn_cls_b1, rpn_bbox_b1,
        roi_del, rpn_del,
        roi_feat_b, W_roi_feat_b, roi_W1_b, rpn_feat_b, W_rpn_feat_b,
        rpn_cW1_b, rpn_bW1_b, Db_roi, Db_rpn, bias_pad_c, bias_pad_b, out);

    // ---- 2: both big GEMMs (extras fused) ----
    {
        GemmJobs js;
        js.n = 2;
        js.j[0] = { rpn_feat_b, W_rpn_feat_b, rpn_sum_b, b_rpn_feat,
                    rpn_del, W_rpn_del, b_rpn_del, rpn_scale, W_rpn_sc, b_rpn_sc,
                    256, 256, 512, 256, 4, 0 };
        js.j[1] = { roi_feat_b, W_roi_feat_b, roi_sum_b, b_roi_feat,
                    roi_del, W_roi_del, b_roi_del, roi_scale, W_roi_sc, b_roi_sc,
                    1024, 1024, 2048, 1024, 16, 128 };
        js.j[2] = js.j[0]; js.j[3] = js.j[0];
        gemm_mfma<true, false><<<dim3(640), 256, 0, stream>>>(js);
    }

    // ---- 3: all 4 hidden GEMMs (relu fused) ----
    {
        GemmJobs js;
        js.n = 4;
        js.j[0] = { rpn_sum_b,        rpn_cW1_b, h_rpn_c, bias_pad_c,
                    nullptr, nullptr, nullptr, nullptr, nullptr, nullptr,
                    512, 256, 128, 256, 1, 0 };
        js.j[1] = { rpn_sum_b + 256,  rpn_bW1_b, h_rpn_b, bias_pad_b,
                    nullptr, nullptr, nullptr, nullptr, nullptr, nullptr,
                    512, 256, 128, 256, 1, 32 };
        js.j[2] = { roi_sum_b,        roi_W1_b, h_roi_c, roi_cls_b1,
                    nullptr, nullptr, nullptr, nullptr, nullptr, nullptr,
                    2048, 1024, 256, 1024, 2, 64 };
        // reference bug: bbox half also uses roi_cls W1/b1 (and W2/b2 below)
        js.j[3] = { roi_sum_b + 1024, roi_W1_b, h_roi_b, roi_cls_b1,
                    nullptr, nullptr, nullptr, nullptr, nullptr, nullptr,
                    2048, 1024, 256, 1024, 2, 128 };
        gemm_mfma<false, true><<<dim3(192), 256, 0, stream>>>(js);
    }

    // ---- 4: all 4 alphas (f32 + padded bf16) ----
    alphas_all<<<dim3(4096), 256, 0, stream>>>(
        h_rpn_c, h_rpn_b, h_roi_c, h_roi_b,
        rpn_cls_W2, rpn_bbox_W2, roi_cls_W2,
        rpn_cls_b2, rpn_bbox_b2, roi_cls_b2,
        iter_ptr, A_rpn_c, A_rpn_b, A_roi_c, A_roi_b, Ab_all);

    // ---- 5: MFMA losses + means ----
    finale_kernel<<<dim3(516), 256, 0, stream>>>(
        Ab_all, Db_roi, Db_rpn,
        A_roi_c, A_rpn_c, A_roi_b, A_rpn_b,
        roi_class, rpn_class, out);
}

// Round 7
// 171.391 us; speedup vs baseline: 3.7230x; 1.0163x over previous
//
#include <hip/hip_runtime.h>
#include <math.h>

#define NPTS 4096
#define NEPS 4.096e-4f                 // 4096 * 1e-7
#define E2   7.3890560989306495f       // exp(2)

typedef float  f32x4 __attribute__((ext_vector_type(4)));
typedef short  s16x8 __attribute__((ext_vector_type(8)));

static __device__ __forceinline__ unsigned short f2b(float x) {
    unsigned u = __builtin_bit_cast(unsigned, x);
    return (unsigned short)((u + 0x7fffu + ((u >> 16) & 1u)) >> 16);
}
static __device__ __forceinline__ float b2f(unsigned short h) {
    return __builtin_bit_cast(float, (unsigned)h << 16);
}

static __device__ __forceinline__ void gload16(const unsigned short* g, unsigned short* lds) {
    __builtin_amdgcn_global_load_lds(
        (const __attribute__((address_space(1))) void*)g,
        (__attribute__((address_space(3))) void*)lds, 16, 0, 0);
}

// ---------------------------------------------------------------------------
// prep: f32->bf16 converts + rpn W1 pads + bias pads + delta pads + loss zero
// ---------------------------------------------------------------------------
__global__ __launch_bounds__(256) void prep_kernel(
    const float* __restrict__ roi_feat, const float* __restrict__ W_roi_feat,
    const float* __restrict__ roi_cls_W1,
    const float* __restrict__ rpn_feat, const float* __restrict__ W_rpn_feat,
    const float* __restrict__ rpn_cls_W1, const float* __restrict__ rpn_bbox_W1,
    const float* __restrict__ rpn_cls_b1, const float* __restrict__ rpn_bbox_b1,
    const float* __restrict__ roi_del, const float* __restrict__ rpn_del,
    unsigned short* __restrict__ roi_feat_b, unsigned short* __restrict__ W_roi_feat_b,
    unsigned short* __restrict__ roi_W1_b,
    unsigned short* __restrict__ rpn_feat_b, unsigned short* __restrict__ W_rpn_feat_b,
    unsigned short* __restrict__ rpn_cW1_b, unsigned short* __restrict__ rpn_bW1_b,
    unsigned short* __restrict__ Db_roi, unsigned short* __restrict__ Db_rpn,
    float* __restrict__ bias_pad_c, float* __restrict__ bias_pad_b,
    float* __restrict__ out)
{
    const int b = blockIdx.x, t = threadIdx.x;
    if (b < 7552) {
        const float* in; unsigned short* o; int base;
        if      (b < 4096) { in = roi_feat;   o = roi_feat_b;   base = b; }
        else if (b < 6144) { in = W_roi_feat; o = W_roi_feat_b; base = b - 4096; }
        else if (b < 6400) { in = roi_cls_W1; o = roi_W1_b;     base = b - 6144; }
        else if (b < 7424) { in = rpn_feat;   o = rpn_feat_b;   base = b - 6400; }
        else               { in = W_rpn_feat; o = W_rpn_feat_b; base = b - 7424; }
        const int i = base * 1024 + t * 4;
        const float4 v = *(const float4*)&in[i];
        ushort4 ov;
        ov.x = f2b(v.x); ov.y = f2b(v.y); ov.z = f2b(v.z); ov.w = f2b(v.w);
        *(ushort4*)&o[i] = ov;
    } else if (b < 7616) {
        const bool cls = b < 7584;
        const float* W = cls ? rpn_cls_W1 : rpn_bbox_W1;
        unsigned short* o = cls ? rpn_cW1_b : rpn_bW1_b;
        const int local = b - (cls ? 7552 : 7584);
        const int i0 = local * 1024 + t * 4;
#pragma unroll
        for (int u = 0; u < 4; ++u) {
            const int i = i0 + u;
            const int r = i >> 8, c = i & 255;
            o[i] = (r < 64) ? f2b(W[r * 256 + c]) : (unsigned short)0;
        }
    } else if (b == 7616) {
        if (t < 128)      bias_pad_c[t] = (t < 64) ? rpn_cls_b1[t] : 0.f;
        else              bias_pad_b[t - 128] = ((t - 128) < 64) ? rpn_bbox_b1[t - 128] : 0.f;
        if (t < 4) out[184 + t] = 0.f;
    } else {
        // delta pad: Db[4096][32] bf16, cols 0..3 = deltas, rest 0
        const int row = (b - 7617) * 256 + t;
        const int mat = row >> 12, r = row & 4095;
        const float* D = mat ? rpn_del : roi_del;
        unsigned short* o = mat ? Db_rpn : Db_roi;
        const float4 dv = *(const float4*)&D[(size_t)r * 4];
        ushort4 d4; d4.x = f2b(dv.x); d4.y = f2b(dv.y); d4.z = f2b(dv.z); d4.w = f2b(dv.w);
        unsigned short* p = o + (size_t)r * 32;
        ushort4 z4 = {0,0,0,0};
        *(ushort4*)p = d4;
        *(ushort4*)(p + 4)  = z4;
        *(ushort4*)(p + 8)  = z4; *(ushort4*)(p + 12) = z4;
        *(ushort4*)(p + 16) = z4; *(ushort4*)(p + 20) = z4;
        *(ushort4*)(p + 24) = z4; *(ushort4*)(p + 28) = z4;
    }
}

// ---------------------------------------------------------------------------
// MFMA GEMM, 3-stage pipeline with counted vmcnt + raw barriers (T3+T4):
//   prologue STAGE(t0,b0) STAGE(t1,b1)
//   iter t:  vmcnt(4) [tile t done, t+1 in flight] ; s_barrier ;
//            STAGE(t+2 -> buf (t+2)%3) ; ds_read+MFMA tile t
//   last iter peeled with vmcnt(0). Never full-drain in steady state.
// Conflict-free subtile LDS layout (chunk l = T[s*16+(l&15)][(l>>4)*8..+8)).
// Job-local XCD-bijective block swizzle (all job sizes divisible by 8).
// ---------------------------------------------------------------------------
struct GemmJob {
    const unsigned short *A, *W;
    unsigned short *C;
    const float *bias;
    const float *del, *Wd, *bd, *sc, *Wsc, *bs;
    int lda, ldw, ldc, K, nbx, bstart;
};
struct GemmJobs { GemmJob j[4]; int n; };

template<bool EXTRAS, bool RELU>
__global__ __launch_bounds__(256) void gemm_mfma(GemmJobs jobs)
{
    __shared__ __align__(16) unsigned short As[3 * 4096];
    __shared__ __align__(16) unsigned short Bs[3 * 4096];
    const int bid = blockIdx.x;
    int ji = 0;
#pragma unroll
    for (int i = 1; i < 4; ++i)
        if (i < jobs.n && bid >= jobs.j[i].bstart) ji = i;
    const GemmJob jb = jobs.j[ji];
    int local = bid - jb.bstart;
    const int nb = jb.nbx << 5;                       // nbx * 32 row-tiles
    local = (local & 7) * (nb >> 3) + (local >> 3);   // XCD-contiguous chunks
    const int bx = local % jb.nbx, by = local / jb.nbx;
    const int row0 = by * 128, col0 = bx * 128;

    const int t = threadIdx.x, l = t & 63, w = t >> 6;
    const int wr = w >> 1, wc = w & 1;
    const int fr = l & 15, fq = l >> 4;

    const int s0 = 2 * w, s1 = 2 * w + 1;
    const unsigned short* gA0 = jb.A + (size_t)(row0 + s0 * 16 + fr) * jb.lda + fq * 8;
    const unsigned short* gA1 = jb.A + (size_t)(row0 + s1 * 16 + fr) * jb.lda + fq * 8;
    const unsigned short* gW0 = jb.W + (size_t)(col0 + s0 * 16 + fr) * jb.ldw + fq * 8;
    const unsigned short* gW1 = jb.W + (size_t)(col0 + s1 * 16 + fr) * jb.ldw + fq * 8;

    const int lA0 = s0 * 512, lA1 = s1 * 512;

    f32x4 acc[4][4] = {};
    const int niter = jb.K >> 5;

    // prologue: stage tiles 0 and 1
    gload16(gA0,      As + lA0);
    gload16(gA1,      As + lA1);
    gload16(gW0,      Bs + lA0);
    gload16(gW1,      Bs + lA1);
    gload16(gA0 + 32, As + 4096 + lA0);
    gload16(gA1 + 32, As + 4096 + lA1);
    gload16(gW0 + 32, Bs + 4096 + lA0);
    gload16(gW1 + 32, Bs + 4096 + lA1);

    int cur = 0;
    for (int it = 0; it < niter - 1; ++it) {
        asm volatile("s_waitcnt vmcnt(4)" ::: "memory");
        __builtin_amdgcn_s_barrier();
        // stage tile t+2 into buf (cur+2)%3 (its readers finished before this barrier)
        const int k2 = (it + 2) << 5;
        if (k2 < jb.K) {
            const int stg = (cur == 0) ? 2 : cur - 1;
            const int sb = stg * 4096;
            gload16(gA0 + k2, As + sb + lA0);
            gload16(gA1 + k2, As + sb + lA1);
            gload16(gW0 + k2, Bs + sb + lA0);
            gload16(gW1 + k2, Bs + sb + lA1);
        }
        const unsigned short* Asc = As + cur * 4096;
        const unsigned short* Bsc = Bs + cur * 4096;
        s16x8 af[4], bf[4];
#pragma unroll
        for (int m = 0; m < 4; ++m)
            af[m] = *(const s16x8*)&Asc[(wr * 4 + m) * 512 + l * 8];
#pragma unroll
        for (int n = 0; n < 4; ++n)
            bf[n] = *(const s16x8*)&Bsc[(wc * 4 + n) * 512 + l * 8];
#pragma unroll
        for (int m = 0; m < 4; ++m)
#pragma unroll
            for (int n = 0; n < 4; ++n)
                acc[m][n] = __builtin_amdgcn_mfma_f32_16x16x32_bf16(
                    af[m], bf[n], acc[m][n], 0, 0, 0);
        cur = (cur == 2) ? 0 : cur + 1;
    }
    // final iteration: drain remaining loads fully
    {
        asm volatile("s_waitcnt vmcnt(0)" ::: "memory");
        __builtin_amdgcn_s_barrier();
        const unsigned short* Asc = As + cur * 4096;
        const unsigned short* Bsc = Bs + cur * 4096;
        s16x8 af[4], bf[4];
#pragma unroll
        for (int m = 0; m < 4; ++m)
            af[m] = *(const s16x8*)&Asc[(wr * 4 + m) * 512 + l * 8];
#pragma unroll
        for (int n = 0; n < 4; ++n)
            bf[n] = *(const s16x8*)&Bsc[(wc * 4 + n) * 512 + l * 8];
#pragma unroll
        for (int m = 0; m < 4; ++m)
#pragma unroll
            for (int n = 0; n < 4; ++n)
                acc[m][n] = __builtin_amdgcn_mfma_f32_16x16x32_bf16(
                    af[m], bf[n], acc[m][n], 0, 0, 0);
    }

    // epilogue: row = row0+wr*64+m*16+fq*4+j ; col = col0+wc*64+n*16+fr
#pragma unroll
    for (int n = 0; n < 4; ++n) {
        const int col = col0 + wc * 64 + n * 16 + fr;
        float cadd = jb.bias[col];
        float wd0 = 0.f, wd1 = 0.f, wd2 = 0.f, wd3 = 0.f, wscv = 0.f;
        if (EXTRAS) {
            cadd += jb.bd[col] + jb.bs[col];
            const float4 w4 = *(const float4*)&jb.Wd[col * 4];
            wd0 = w4.x; wd1 = w4.y; wd2 = w4.z; wd3 = w4.w;
            wscv = jb.Wsc[col];
        }
#pragma unroll
        for (int m = 0; m < 4; ++m) {
#pragma unroll
            for (int j = 0; j < 4; ++j) {
                const int row = row0 + wr * 64 + m * 16 + fq * 4 + j;
                float v = acc[m][n][j] + cadd;
                if (EXTRAS) {
                    const float4 dm = *(const float4*)&jb.del[row * 4];
                    v += dm.x * wd0 + dm.y * wd1 + dm.z * wd2 + dm.w * wd3
                       + jb.sc[row] * wscv;
                }
                if (RELU) v = fmaxf(v, 0.f);
                jb.C[(size_t)row * jb.ldc + col] = f2b(v);
            }
        }
    }
}

// ---------------------------------------------------------------------------
// alphas for all 4 matrices; writes f32 A[4096][8] and bf16 Ab[mat][4096][32]
// ---------------------------------------------------------------------------
__global__ __launch_bounds__(256) void alphas_all(
    const unsigned short* __restrict__ h_rpn_c, const unsigned short* __restrict__ h_rpn_b,
    const unsigned short* __restrict__ h_roi_c, const unsigned short* __restrict__ h_roi_b,
    const float* __restrict__ W2_rc, const float* __restrict__ W2_rb,
    const float* __restrict__ W2_oc,
    const float* __restrict__ b2_rc, const float* __restrict__ b2_rb,
    const float* __restrict__ b2_oc,
    const int* __restrict__ iter_ptr,
    float* __restrict__ A_rpn_c, float* __restrict__ A_rpn_b,
    float* __restrict__ A_roi_c, float* __restrict__ A_roi_b,
    unsigned short* __restrict__ Ab_all)
{
    const int vrow = blockIdx.x * 4 + (threadIdx.x >> 6);
    const int mat = vrow >> 12, row = vrow & 4095;
    const unsigned short* H; const float *W2, *b2; float* Ao; int ldh, Hd;
    if (mat == 0)      { H = h_rpn_c; W2 = W2_rc; b2 = b2_rc; Ao = A_rpn_c; ldh = 128; Hd = 64; }
    else if (mat == 1) { H = h_rpn_b; W2 = W2_rb; b2 = b2_rb; Ao = A_rpn_b; ldh = 128; Hd = 64; }
    else if (mat == 2) { H = h_roi_c; W2 = W2_oc; b2 = b2_oc; Ao = A_roi_c; ldh = 256; Hd = 256; }
    else               { H = h_roi_b; W2 = W2_oc; b2 = b2_oc; Ao = A_roi_b; ldh = 256; Hd = 256; }

    const int l = threadIdx.x & 63;
    float acc[8] = {};
    for (int m = l * 4; m < Hd; m += 256) {
        const ushort4 h4 = *(const ushort4*)&H[(size_t)row * ldh + m];
        const float h0 = b2f(h4.x), h1 = b2f(h4.y), h2 = b2f(h4.z), h3 = b2f(h4.w);
#pragma unroll
        for (int o = 0; o < 8; ++o) {
            const float4 w4 = *(const float4*)&W2[o * Hd + m];
            acc[o] += h0 * w4.x + h1 * w4.y + h2 * w4.z + h3 * w4.w;
        }
    }
#pragma unroll
    for (int o = 0; o < 8; ++o)
        for (int off = 32; off; off >>= 1)
            acc[o] += __shfl_xor(acc[o], off, 64);

    const int it = *iter_ptr;
    const float temp = fmaxf(1.0f, 30.0f * (float)(90000 - it) / 90000.0f);
    float lg[8], mx = -1e30f;
#pragma unroll
    for (int o = 0; o < 8; ++o) { lg[o] = (acc[o] + b2[o]) / temp; mx = fmaxf(mx, lg[o]); }
    float s = 0.f;
#pragma unroll
    for (int o = 0; o < 8; ++o) { lg[o] = __expf(lg[o] - mx); s += lg[o]; }
    const float inv = 1.0f / s;
    if (l < 8) Ao[(size_t)row * 8 + l] = lg[l] * inv;
    unsigned short* Ab = Ab_all + (size_t)mat * 131072 + (size_t)row * 32;
    if (l == 0) {
        ushort4 o0, o1;
        o0.x = f2b(lg[0]*inv); o0.y = f2b(lg[1]*inv); o0.z = f2b(lg[2]*inv); o0.w = f2b(lg[3]*inv);
        o1.x = f2b(lg[4]*inv); o1.y = f2b(lg[5]*inv); o1.z = f2b(lg[6]*inv); o1.w = f2b(lg[7]*inv);
        *(ushort4*)Ab = o0; *(ushort4*)(Ab + 4) = o1;
    } else if (l < 4) {
        ushort4 z = {0,0,0,0};
        *(ushort4*)(Ab + l * 8)     = z;
        *(ushort4*)(Ab + l * 8 + 4) = z;
    }
}

// ---------------------------------------------------------------------------
// finale: MFMA losses + means (unchanged)
// ---------------------------------------------------------------------------
__global__ __launch_bounds__(256) void finale_kernel(
    const unsigned short* __restrict__ Ab_all,
    const unsigned short* __restrict__ Db_roi, const unsigned short* __restrict__ Db_rpn,
    const float* __restrict__ A_roi_c, const float* __restrict__ A_rpn_c,
    const float* __restrict__ A_roi_b, const float* __restrict__ A_rpn_b,
    const int* __restrict__ roi_class, const int* __restrict__ rpn_class,
    float* __restrict__ out)
{
    const int b = blockIdx.x, t = threadIdx.x;
    const int w = t >> 6, l = t & 63;
    const int fr = l & 15, fq = l >> 4;

    if (b < 512) {
        __shared__ float sh[4][2][16][3];
        __shared__ float lsum[32];
        const bool is_cls = b < 256;
        const int li = b >> 7;
        const int blk = b & 127;
        const int j0 = blk * 32;
        const int mat = (li == 0) ? 2 : (li == 1) ? 0 : (li == 2) ? 3 : 1;
        const unsigned short* Ab = Ab_all + (size_t)mat * 131072;
        const unsigned short* Db = (li == 2) ? Db_roi : Db_rpn;
        const int* cls = (li == 0) ? roi_class : rpn_class;
        float* outp = out + 184 + li;

        s16x8 bj[2], dj[2];
        int cj[2];
#pragma unroll
        for (int jt = 0; jt < 2; ++jt) {
            const int j = j0 + jt * 16;
            bj[jt] = *(const s16x8*)&Ab[(size_t)(j + fr) * 32 + fq * 8];
            if (is_cls) cj[jt] = cls[j + fr];
            else        dj[jt] = *(const s16x8*)&Db[(size_t)(j + fr) * 32 + fq * 8];
        }

        float Sx[2] = {}, W2s[2] = {}, U[2] = {};
        const int kbase0 = w * 1024;
        const f32x4 zc = {0.f, 0.f, 0.f, 0.f};

        for (int ch = 0; ch < 64; ++ch) {
            const int kb = kbase0 + ch * 16;
            const s16x8 afr = *(const s16x8*)&Ab[(size_t)(kb + fr) * 32 + fq * 8];
            if (is_cls) {
                const int4 ck = *(const int4*)&cls[kb + fq * 4];
                const int ckr[4] = {ck.x, ck.y, ck.z, ck.w};
#pragma unroll
                for (int jt = 0; jt < 2; ++jt) {
                    const f32x4 g = __builtin_amdgcn_mfma_f32_16x16x32_bf16(afr, bj[jt], zc, 0, 0, 0);
#pragma unroll
                    for (int r = 0; r < 4; ++r) {
                        const float gv = g[r];
                        Sx[jt] += __expf(2.f * gv);
                        const float wgt = (ckr[r] == cj[jt]) ? E2 : 1.0f;
                        U[jt] = fmaf(wgt, gv, U[jt]);
                        W2s[jt] += wgt;
                    }
                }
            } else {
                const s16x8 dfr = *(const s16x8*)&Db[(size_t)(kb + fr) * 32 + fq * 8];
#pragma unroll
                for (int jt = 0; jt < 2; ++jt) {
                    const f32x4 g  = __builtin_amdgcn_mfma_f32_16x16x32_bf16(afr, bj[jt], zc, 0, 0, 0);
                    const f32x4 gd = __builtin_amdgcn_mfma_f32_16x16x32_bf16(dfr, dj[jt], zc, 0, 0, 0);
#pragma unroll
                    for (int r = 0; r < 4; ++r) {
                        const float gv = g[r];
                        const float ed = __expf(2.f * gd[r]);
                        Sx[jt] += __expf(2.f * gv);
                        W2s[jt] += ed;
                        U[jt] = fmaf(ed, gv, U[jt]);
                    }
                }
            }
        }

#pragma unroll
        for (int jt = 0; jt < 2; ++jt) {
            float vx = Sx[jt], vg = W2s[jt], vu = U[jt];
            for (int off = 16; off <= 32; off <<= 1) {
                vx += __shfl_xor(vx, off, 64);
                vg += __shfl_xor(vg, off, 64);
                vu += __shfl_xor(vu, off, 64);
            }
            if (fq == 0) {
                sh[w][jt][fr][0] = vx; sh[w][jt][fr][1] = vg; sh[w][jt][fr][2] = vu;
            }
        }
        __syncthreads();
        if (t < 32) {
            const int jt = t >> 4, jl = t & 15;
            float vx = 0.f, vg = 0.f, vu = 0.f;
#pragma unroll
            for (int wv = 0; wv < 4; ++wv) {
                vx += sh[wv][jt][jl][0]; vg += sh[wv][jt][jl][1]; vu += sh[wv][jt][jl][2];
            }
            lsum[t] = (2.f * vu - __logf(vx + NEPS) * vg) / (vg + NEPS);
        }
        __syncthreads();
        if (t == 0) {
            float s = 0.f;
            for (int i = 0; i < 32; ++i) s += lsum[i];
            atomicAdd(outp, -s / 4096.f);
        }
    } else if (b < 515) {
        __shared__ float S4[4][8];
        const float* A = (b == 512) ? A_rpn_c : (b == 513) ? A_rpn_b : A_roi_b;
        const int off0 = (b == 512) ? 0 : (b == 513) ? 8 : 176;
        float acc[8] = {};
        for (int r = t; r < NPTS; r += 256) {
            const float4 v0 = *(const float4*)&A[(size_t)r * 8];
            const float4 v1 = *(const float4*)&A[(size_t)r * 8 + 4];
            acc[0]+=v0.x; acc[1]+=v0.y; acc[2]+=v0.z; acc[3]+=v0.w;
            acc[4]+=v1.x; acc[5]+=v1.y; acc[6]+=v1.z; acc[7]+=v1.w;
        }
#pragma unroll
        for (int o = 0; o < 8; ++o) {
            float v = acc[o];
            for (int offs = 32; offs; offs >>= 1) v += __shfl_xor(v, offs, 64);
            if (l == 0) S4[w][o] = v;
        }
        __syncthreads();
        if (t < 8) {
            const float s = S4[0][t] + S4[1][t] + S4[2][t] + S4[3][t];
            out[off0 + t] = s * (1.f / 4096.f);
        }
    } else {
        __shared__ float S[20][8];
        __shared__ float cnt[20];
        if (t < 160) ((float*)S)[t] = 0.f;
        if (t < 20) cnt[t] = 0.f;
        __syncthreads();
        for (int r = t; r < NPTS; r += 256) {
            const int c = roi_class[r];
            atomicAdd(&cnt[c], 1.0f);
            const float4 v0 = *(const float4*)&A_roi_c[(size_t)r * 8];
            const float4 v1 = *(const float4*)&A_roi_c[(size_t)r * 8 + 4];
            atomicAdd(&S[c][0], v0.x); atomicAdd(&S[c][1], v0.y);
            atomicAdd(&S[c][2], v0.z); atomicAdd(&S[c][3], v0.w);
            atomicAdd(&S[c][4], v1.x); atomicAdd(&S[c][5], v1.y);
            atomicAdd(&S[c][6], v1.z); atomicAdd(&S[c][7], v1.w);
        }
        __syncthreads();
        if (t < 160) {
            const int c = t >> 3;
            out[16 + t] = S[c][t & 7] / fmaxf(cnt[c], 1.f);
        }
    }
}

// ---------------------------------------------------------------------------
extern "C" void kernel_launch(void* const* d_in, const int* in_sizes, int n_in,
                              void* d_out, int out_size, void* d_ws, size_t ws_size,
                              hipStream_t stream)
{
    const float* rpn_feat  = (const float*)d_in[0];
    const float* rpn_del   = (const float*)d_in[1];
    const float* rpn_scale = (const float*)d_in[2];
    const float* roi_feat  = (const float*)d_in[3];
    const float* roi_del   = (const float*)d_in[4];
    const float* roi_scale = (const float*)d_in[5];
    const int*   rpn_class = (const int*)d_in[6];
    const int*   roi_class = (const int*)d_in[7];
    const float* W_rpn_feat = (const float*)d_in[8];  const float* b_rpn_feat = (const float*)d_in[9];
    const float* W_rpn_del  = (const float*)d_in[10]; const float* b_rpn_del  = (const float*)d_in[11];
    const float* W_rpn_sc   = (const float*)d_in[12]; const float* b_rpn_sc   = (const float*)d_in[13];
    const float* W_roi_feat = (const float*)d_in[14]; const float* b_roi_feat = (const float*)d_in[15];
    const float* W_roi_del  = (const float*)d_in[16]; const float* b_roi_del  = (const float*)d_in[17];
    const float* W_roi_sc   = (const float*)d_in[18]; const float* b_roi_sc   = (const float*)d_in[19];
    const float* rpn_cls_W1  = (const float*)d_in[20]; const float* rpn_cls_b1  = (const float*)d_in[21];
    const float* rpn_cls_W2  = (const float*)d_in[22]; const float* rpn_cls_b2  = (const float*)d_in[23];
    const float* rpn_bbox_W1 = (const float*)d_in[24]; const float* rpn_bbox_b1 = (const float*)d_in[25];
    const float* rpn_bbox_W2 = (const float*)d_in[26]; const float* rpn_bbox_b2 = (const float*)d_in[27];
    const float* roi_cls_W1  = (const float*)d_in[28]; const float* roi_cls_b1  = (const float*)d_in[29];
    const float* roi_cls_W2  = (const float*)d_in[30]; const float* roi_cls_b2  = (const float*)d_in[31];
    const int* iter_ptr = (const int*)d_in[32];
    float* out = (float*)d_out;
    char*  wsb = (char*)d_ws;

    // ---- workspace layout (byte offsets) ----
    unsigned short* roi_feat_b   = (unsigned short*)(wsb + 0);          // 4096x1024
    unsigned short* Ab_all       = (unsigned short*)(wsb + 0);          // 4 x 4096x32 (launch 4+)
    unsigned short* W_roi_feat_b = (unsigned short*)(wsb + 8388608);    // 2048x1024
    unsigned short* roi_sum_b    = (unsigned short*)(wsb + 12582912);   // 4096x2048
    unsigned short* roi_W1_b     = (unsigned short*)(wsb + 29360128);   // 256x1024
    unsigned short* h_roi_c      = (unsigned short*)(wsb + 29884416);   // 4096x256
    unsigned short* h_roi_b      = (unsigned short*)(wsb + 31981568);   // 4096x256
    unsigned short* rpn_feat_b   = (unsigned short*)(wsb + 34078720);   // 4096x256
    unsigned short* W_rpn_feat_b = (unsigned short*)(wsb + 36175872);   // 512x256
    unsigned short* rpn_sum_b    = (unsigned short*)(wsb + 36438016);   // 4096x512
    unsigned short* rpn_cW1_b    = (unsigned short*)(wsb + 40632320);   // 128x256 padded
    unsigned short* rpn_bW1_b    = (unsigned short*)(wsb + 40697856);   // 128x256 padded
    unsigned short* h_rpn_c      = (unsigned short*)(wsb + 40763392);   // 4096x128
    unsigned short* h_rpn_b      = (unsigned short*)(wsb + 41811968);   // 4096x128
    float* bias_pad_c = (float*)(wsb + 42860544);                       // 128
    float* bias_pad_b = (float*)(wsb + 42861056);                       // 128
    float* A_rpn_c    = (float*)(wsb + 42861568);                       // 4096x8
    float* A_rpn_b    = (float*)(wsb + 42992640);
    float* A_roi_c    = (float*)(wsb + 43123712);
    float* A_roi_b    = (float*)(wsb + 43254784);
    unsigned short* Db_roi = (unsigned short*)(wsb + 43385856);         // 4096x32
    unsigned short* Db_rpn = (unsigned short*)(wsb + 43648000);         // 4096x32

    // ---- 1: prep ----
    prep_kernel<<<dim3(7649), 256, 0, stream>>>(
        roi_feat, W_roi_feat, roi_cls_W1, rpn_feat, W_rpn_feat,
        rpn_cls_W1, rpn_bbox_W1, rpn_cls_b1, rpn_bbox_b1,
        roi_del, rpn_del,
        roi_feat_b, W_roi_feat_b, roi_W1_b, rpn_feat_b, W_rpn_feat_b,
        rpn_cW1_b, rpn_bW1_b, Db_roi, Db_rpn, bias_pad_c, bias_pad_b, out);

    // ---- 2: both big GEMMs (extras fused) ----
    {
        GemmJobs js;
        js.n = 2;
        js.j[0] = { rpn_feat_b, W_rpn_feat_b, rpn_sum_b, b_rpn_feat,
                    rpn_del, W_rpn_del, b_rpn_del, rpn_scale, W_rpn_sc, b_rpn_sc,
                    256, 256, 512, 256, 4, 0 };
        js.j[1] = { roi_feat_b, W_roi_feat_b, roi_sum_b, b_roi_feat,
                    roi_del, W_roi_del, b_roi_del, roi_scale, W_roi_sc, b_roi_sc,
                    1024, 1024, 2048, 1024, 16, 128 };
        js.j[2] = js.j[0]; js.j[3] = js.j[0];
        gemm_mfma<true, false><<<dim3(640), 256, 0, stream>>>(js);
    }

    // ---- 3: all 4 hidden GEMMs (relu fused) ----
    {
        GemmJobs js;
        js.n = 4;
        js.j[0] = { rpn_sum_b,        rpn_cW1_b, h_rpn_c, bias_pad_c,
                    nullptr, nullptr, nullptr, nullptr, nullptr, nullptr,
                    512, 256, 128, 256, 1, 0 };
        js.j[1] = { rpn_sum_b + 256,  rpn_bW1_b, h_rpn_b, bias_pad_b,
                    nullptr, nullptr, nullptr, nullptr, nullptr, nullptr,
                    512, 256, 128, 256, 1, 32 };
        js.j[2] = { roi_sum_b,        roi_W1_b, h_roi_c, roi_cls_b1,
                    nullptr, nullptr, nullptr, nullptr, nullptr, nullptr,
                    2048, 1024, 256, 1024, 2, 64 };
        // reference bug: bbox half also uses roi_cls W1/b1 (and W2/b2 below)
        js.j[3] = { roi_sum_b + 1024, roi_W1_b, h_roi_b, roi_cls_b1,
                    nullptr, nullptr, nullptr, nullptr, nullptr, nullptr,
                    2048, 1024, 256, 1024, 2, 128 };
        gemm_mfma<false, true><<<dim3(192), 256, 0, stream>>>(js);
    }

    // ---- 4: all 4 alphas (f32 + padded bf16) ----
    alphas_all<<<dim3(4096), 256, 0, stream>>>(
        h_rpn_c, h_rpn_b, h_roi_c, h_roi_b,
        rpn_cls_W2, rpn_bbox_W2, roi_cls_W2,
        rpn_cls_b2, rpn_bbox_b2, roi_cls_b2,
        iter_ptr, A_rpn_c, A_rpn_b, A_roi_c, A_roi_b, Ab_all);

    // ---- 5: MFMA losses + means ----
    finale_kernel<<<dim3(516), 256, 0, stream>>>(
        Ab_all, Db_roi, Db_rpn,
        A_roi_c, A_rpn_c, A_roi_b, A_rpn_b,
        roi_class, rpn_class, out);
}

// Round 8
// 149.866 us; speedup vs baseline: 4.2577x; 1.1436x over previous
//
#include <hip/hip_runtime.h>
#include <math.h>

#define NPTS 4096
#define NEPS 4.096e-4f                 // 4096 * 1e-7
#define E2   7.3890560989306495f       // exp(2)

typedef float  f32x4 __attribute__((ext_vector_type(4)));
typedef short  s16x8 __attribute__((ext_vector_type(8)));

static __device__ __forceinline__ unsigned short f2b(float x) {
    unsigned u = __builtin_bit_cast(unsigned, x);
    return (unsigned short)((u + 0x7fffu + ((u >> 16) & 1u)) >> 16);
}
static __device__ __forceinline__ float b2f(unsigned short h) {
    return __builtin_bit_cast(float, (unsigned)h << 16);
}

// fragment-order (swizzled) element offset for element (r,c) of an R-row matrix:
// subtile (r/16, c/32) is 512 contiguous elements (kj-major, si-minor);
// chunk l = (r%16) + ((c%32)/8)*16 holds cols ((c%32)&~7)..+8 of row r%16.
static __device__ __forceinline__ size_t swz(int r, int c, int R16) {
    return (((size_t)((c >> 5) * R16 + (r >> 4))) << 9)
         + ((size_t)((r & 15) + (((c & 31) >> 3) << 4)) << 3) + (c & 7);
}

// ---------------------------------------------------------------------------
// prep: f32 -> bf16 fragment-order converts + rpn W1 pads + bias + deltas + zero
// convert blocks: 2048 elements (256 thr x 8, one 16B chunk store per thread)
// ---------------------------------------------------------------------------
__global__ __launch_bounds__(256) void prep_kernel(
    const float* __restrict__ roi_feat, const float* __restrict__ W_roi_feat,
    const float* __restrict__ roi_cls_W1,
    const float* __restrict__ rpn_feat, const float* __restrict__ W_rpn_feat,
    const float* __restrict__ rpn_cls_W1, const float* __restrict__ rpn_bbox_W1,
    const float* __restrict__ rpn_cls_b1, const float* __restrict__ rpn_bbox_b1,
    const float* __restrict__ roi_del, const float* __restrict__ rpn_del,
    unsigned short* __restrict__ roi_feat_sw, unsigned short* __restrict__ W_roi_feat_sw,
    unsigned short* __restrict__ roi_W1_sw,
    unsigned short* __restrict__ rpn_feat_sw, unsigned short* __restrict__ W_rpn_feat_sw,
    unsigned short* __restrict__ rpn_cW1_sw, unsigned short* __restrict__ rpn_bW1_sw,
    unsigned short* __restrict__ Db_roi, unsigned short* __restrict__ Db_rpn,
    float* __restrict__ bias_pad_c, float* __restrict__ bias_pad_b,
    float* __restrict__ out)
{
    const int b = blockIdx.x, t = threadIdx.x;
    if (b < 3776) {
        const float* in; unsigned short* o; int base, cshift, R16;
        if      (b < 2048) { in = roi_feat;   o = roi_feat_sw;   base = b;        cshift = 10; R16 = 256; }
        else if (b < 3072) { in = W_roi_feat; o = W_roi_feat_sw; base = b - 2048; cshift = 10; R16 = 128; }
        else if (b < 3200) { in = roi_cls_W1; o = roi_W1_sw;     base = b - 3072; cshift = 10; R16 = 16;  }
        else if (b < 3712) { in = rpn_feat;   o = rpn_feat_sw;   base = b - 3200; cshift = 8;  R16 = 256; }
        else               { in = W_rpn_feat; o = W_rpn_feat_sw; base = b - 3712; cshift = 8;  R16 = 32;  }
        const int i = base * 2048 + t * 8;
        const int r = i >> cshift, c = i & ((1 << cshift) - 1);
        const float4 v0 = *(const float4*)&in[i];
        const float4 v1 = *(const float4*)&in[i + 4];
        s16x8 pk;
        pk[0] = (short)f2b(v0.x); pk[1] = (short)f2b(v0.y);
        pk[2] = (short)f2b(v0.z); pk[3] = (short)f2b(v0.w);
        pk[4] = (short)f2b(v1.x); pk[5] = (short)f2b(v1.y);
        pk[6] = (short)f2b(v1.z); pk[7] = (short)f2b(v1.w);
        *(s16x8*)(o + swz(r, c, R16)) = pk;
    } else if (b < 3808) {
        // rpn W1 pad to 128x256, fragment order (R16=8); rows >=64 are zero
        const bool cls = b < 3792;
        const float* W = cls ? rpn_cls_W1 : rpn_bbox_W1;
        unsigned short* o = cls ? rpn_cW1_sw : rpn_bW1_sw;
        const int local = b - (cls ? 3776 : 3792);
        const int i = local * 2048 + t * 8;
        const int r = i >> 8, c = i & 255;
        s16x8 pk;
#pragma unroll
        for (int u = 0; u < 8; ++u)
            pk[u] = (r < 64) ? (short)f2b(W[r * 256 + c + u]) : (short)0;
        *(s16x8*)(o + swz(r, c, 8)) = pk;
    } else if (b == 3808) {
        if (t < 128)      bias_pad_c[t] = (t < 64) ? rpn_cls_b1[t] : 0.f;
        else              bias_pad_b[t - 128] = ((t - 128) < 64) ? rpn_bbox_b1[t - 128] : 0.f;
        if (t < 4) out[184 + t] = 0.f;
    } else {
        // delta pad: Db[4096][32] bf16, cols 0..3 = deltas, rest 0
        const int row = (b - 3809) * 256 + t;
        const int mat = row >> 12, r = row & 4095;
        const float* D = mat ? rpn_del : roi_del;
        unsigned short* o = mat ? Db_rpn : Db_roi;
        const float4 dv = *(const float4*)&D[(size_t)r * 4];
        ushort4 d4; d4.x = f2b(dv.x); d4.y = f2b(dv.y); d4.z = f2b(dv.z); d4.w = f2b(dv.w);
        unsigned short* p = o + (size_t)r * 32;
        ushort4 z4 = {0, 0, 0, 0};
        *(ushort4*)p = d4;
        *(ushort4*)(p + 4)  = z4;
        *(ushort4*)(p + 8)  = z4; *(ushort4*)(p + 12) = z4;
        *(ushort4*)(p + 16) = z4; *(ushort4*)(p + 20) = z4;
        *(ushort4*)(p + 24) = z4; *(ushort4*)(p + 28) = z4;
    }
}

// ---------------------------------------------------------------------------
// Register-direct MFMA GEMM: no LDS, no barriers. Operands in fragment order;
// each wave streams its own fragments straight to VGPRs (coalesced: uniform
// base + lane*16, imm offsets), 2-deep register double-buffer, 16 MFMA/iter.
// 128x128 block tile, 4 waves (2x2 of 64x64). C written fragment-order (big
// GEMMs, consumed by hidden GEMM) or linear (hidden GEMMs, consumed by alphas).
// ---------------------------------------------------------------------------
struct GemmJob {
    const unsigned short *A, *W;
    unsigned short *C;
    const float *bias;
    const float *del, *Wd, *bd, *sc, *Wsc, *bs;
    int strideA, strideB;   // elements per K-step (= R16*512)
    int M16;                // C fragment-order rows/16 (CSWZ)
    int ldc;                // C linear stride (!CSWZ)
    int K, nbx, bstart;
};
struct GemmJobs { GemmJob j[4]; int n; };

template<bool EXTRAS, bool CSWZ, bool RELU>
__global__ __launch_bounds__(256) void gemm_reg(GemmJobs jobs)
{
    const int bid = blockIdx.x;
    int ji = 0;
#pragma unroll
    for (int i = 1; i < 4; ++i)
        if (i < jobs.n && bid >= jobs.j[i].bstart) ji = i;
    const GemmJob jb = jobs.j[ji];
    int local = bid - jb.bstart;
    const int nb = jb.nbx << 5;                       // 32 row-tiles per job
    local = (local & 7) * (nb >> 3) + (local >> 3);   // XCD-contiguous chunks
    const int bx = local % jb.nbx, by = local / jb.nbx;

    const int t = threadIdx.x, l = t & 63, w = t >> 6;
    const int wr = w >> 1, wc = w & 1;
    const int fr = l & 15, fq = l >> 4;

    const int sA0 = by * 8 + wr * 4;                  // A subtile-row base
    const int sB0 = bx * 8 + wc * 4;                  // B subtile-row base
    const unsigned short* pa = jb.A + ((size_t)sA0 << 9) + (size_t)(l * 8);
    const unsigned short* pb = jb.W + ((size_t)sB0 << 9) + (size_t)(l * 8);

    f32x4 acc[4][4] = {};
    s16x8 aX[4], bX[4], aY[4], bY[4];

#pragma unroll
    for (int m = 0; m < 4; ++m) {
        aX[m] = *(const s16x8*)(pa + (m << 9));
        bX[m] = *(const s16x8*)(pb + (m << 9));
    }

    const int niter = jb.K >> 5;   // even for all jobs (8 or 32)
    for (int it = 0; it < niter; it += 2) {
        pa += jb.strideA; pb += jb.strideB;
#pragma unroll
        for (int m = 0; m < 4; ++m) {
            aY[m] = *(const s16x8*)(pa + (m << 9));
            bY[m] = *(const s16x8*)(pb + (m << 9));
        }
#pragma unroll
        for (int m = 0; m < 4; ++m)
#pragma unroll
            for (int n = 0; n < 4; ++n)
                acc[m][n] = __builtin_amdgcn_mfma_f32_16x16x32_bf16(aX[m], bX[n], acc[m][n], 0, 0, 0);
        if (it + 2 < niter) {
            pa += jb.strideA; pb += jb.strideB;
#pragma unroll
            for (int m = 0; m < 4; ++m) {
                aX[m] = *(const s16x8*)(pa + (m << 9));
                bX[m] = *(const s16x8*)(pb + (m << 9));
            }
        }
#pragma unroll
        for (int m = 0; m < 4; ++m)
#pragma unroll
            for (int n = 0; n < 4; ++n)
                acc[m][n] = __builtin_amdgcn_mfma_f32_16x16x32_bf16(aY[m], bY[n], acc[m][n], 0, 0, 0);
    }

    // epilogue: lane holds C[row=(sA0+m)*16+fq*4+j][c=(sB0+n)*16+fr]
#pragma unroll
    for (int n = 0; n < 4; ++n) {
        const int c = (sB0 + n) * 16 + fr;
        float cadd = jb.bias[c];
        float wd0 = 0.f, wd1 = 0.f, wd2 = 0.f, wd3 = 0.f, wscv = 0.f;
        if (EXTRAS) {
            cadd += jb.bd[c] + jb.bs[c];
            const float4 w4 = *(const float4*)&jb.Wd[c * 4];
            wd0 = w4.x; wd1 = w4.y; wd2 = w4.z; wd3 = w4.w;
            wscv = jb.Wsc[c];
        }
#pragma unroll
        for (int m = 0; m < 4; ++m) {
            const int si = sA0 + m;
            unsigned short* cp;
            if (CSWZ) {
                const int kj = c >> 5;
                cp = jb.C + (((size_t)(kj * jb.M16 + si)) << 9)
                   + (((size_t)((c & 31) >> 3)) << 7) + (c & 7);
            }
#pragma unroll
            for (int j = 0; j < 4; ++j) {
                const int rr = fq * 4 + j;
                const int row = si * 16 + rr;
                float v = acc[m][n][j] + cadd;
                if (EXTRAS) {
                    const float4 dm = *(const float4*)&jb.del[row * 4];
                    v += dm.x * wd0 + dm.y * wd1 + dm.z * wd2 + dm.w * wd3
                       + jb.sc[row] * wscv;
                }
                if (RELU) v = fmaxf(v, 0.f);
                if (CSWZ) cp[(size_t)rr << 3] = f2b(v);
                else      jb.C[(size_t)row * jb.ldc + c] = f2b(v);
            }
        }
    }
}

// ---------------------------------------------------------------------------
// alphas for all 4 matrices; writes f32 A[4096][8] and bf16 Ab[mat][4096][32]
// ---------------------------------------------------------------------------
__global__ __launch_bounds__(256) void alphas_all(
    const unsigned short* __restrict__ h_rpn_c, const unsigned short* __restrict__ h_rpn_b,
    const unsigned short* __restrict__ h_roi_c, const unsigned short* __restrict__ h_roi_b,
    const float* __restrict__ W2_rc, const float* __restrict__ W2_rb,
    const float* __restrict__ W2_oc,
    const float* __restrict__ b2_rc, const float* __restrict__ b2_rb,
    const float* __restrict__ b2_oc,
    const int* __restrict__ iter_ptr,
    float* __restrict__ A_rpn_c, float* __restrict__ A_rpn_b,
    float* __restrict__ A_roi_c, float* __restrict__ A_roi_b,
    unsigned short* __restrict__ Ab_all)
{
    const int vrow = blockIdx.x * 4 + (threadIdx.x >> 6);
    const int mat = vrow >> 12, row = vrow & 4095;
    const unsigned short* H; const float *W2, *b2; float* Ao; int ldh, Hd;
    if (mat == 0)      { H = h_rpn_c; W2 = W2_rc; b2 = b2_rc; Ao = A_rpn_c; ldh = 128; Hd = 64; }
    else if (mat == 1) { H = h_rpn_b; W2 = W2_rb; b2 = b2_rb; Ao = A_rpn_b; ldh = 128; Hd = 64; }
    else if (mat == 2) { H = h_roi_c; W2 = W2_oc; b2 = b2_oc; Ao = A_roi_c; ldh = 256; Hd = 256; }
    else               { H = h_roi_b; W2 = W2_oc; b2 = b2_oc; Ao = A_roi_b; ldh = 256; Hd = 256; }

    const int l = threadIdx.x & 63;
    float acc[8] = {};
    for (int m = l * 4; m < Hd; m += 256) {
        const ushort4 h4 = *(const ushort4*)&H[(size_t)row * ldh + m];
        const float h0 = b2f(h4.x), h1 = b2f(h4.y), h2 = b2f(h4.z), h3 = b2f(h4.w);
#pragma unroll
        for (int o = 0; o < 8; ++o) {
            const float4 w4 = *(const float4*)&W2[o * Hd + m];
            acc[o] += h0 * w4.x + h1 * w4.y + h2 * w4.z + h3 * w4.w;
        }
    }
#pragma unroll
    for (int o = 0; o < 8; ++o)
        for (int off = 32; off; off >>= 1)
            acc[o] += __shfl_xor(acc[o], off, 64);

    const int it = *iter_ptr;
    const float temp = fmaxf(1.0f, 30.0f * (float)(90000 - it) / 90000.0f);
    float lg[8], mx = -1e30f;
#pragma unroll
    for (int o = 0; o < 8; ++o) { lg[o] = (acc[o] + b2[o]) / temp; mx = fmaxf(mx, lg[o]); }
    float s = 0.f;
#pragma unroll
    for (int o = 0; o < 8; ++o) { lg[o] = __expf(lg[o] - mx); s += lg[o]; }
    const float inv = 1.0f / s;
    if (l < 8) Ao[(size_t)row * 8 + l] = lg[l] * inv;
    unsigned short* Ab = Ab_all + (size_t)mat * 131072 + (size_t)row * 32;
    if (l == 0) {
        ushort4 o0, o1;
        o0.x = f2b(lg[0]*inv); o0.y = f2b(lg[1]*inv); o0.z = f2b(lg[2]*inv); o0.w = f2b(lg[3]*inv);
        o1.x = f2b(lg[4]*inv); o1.y = f2b(lg[5]*inv); o1.z = f2b(lg[6]*inv); o1.w = f2b(lg[7]*inv);
        *(ushort4*)Ab = o0; *(ushort4*)(Ab + 4) = o1;
    } else if (l < 4) {
        ushort4 z = {0,0,0,0};
        *(ushort4*)(Ab + l * 8)     = z;
        *(ushort4*)(Ab + l * 8 + 4) = z;
    }
}

// ---------------------------------------------------------------------------
// finale: MFMA losses + means (unchanged)
// ---------------------------------------------------------------------------
__global__ __launch_bounds__(256) void finale_kernel(
    const unsigned short* __restrict__ Ab_all,
    const unsigned short* __restrict__ Db_roi, const unsigned short* __restrict__ Db_rpn,
    const float* __restrict__ A_roi_c, const float* __restrict__ A_rpn_c,
    const float* __restrict__ A_roi_b, const float* __restrict__ A_rpn_b,
    const int* __restrict__ roi_class, const int* __restrict__ rpn_class,
    float* __restrict__ out)
{
    const int b = blockIdx.x, t = threadIdx.x;
    const int w = t >> 6, l = t & 63;
    const int fr = l & 15, fq = l >> 4;

    if (b < 512) {
        __shared__ float sh[4][2][16][3];
        __shared__ float lsum[32];
        const bool is_cls = b < 256;
        const int li = b >> 7;
        const int blk = b & 127;
        const int j0 = blk * 32;
        const int mat = (li == 0) ? 2 : (li == 1) ? 0 : (li == 2) ? 3 : 1;
        const unsigned short* Ab = Ab_all + (size_t)mat * 131072;
        const unsigned short* Db = (li == 2) ? Db_roi : Db_rpn;
        const int* cls = (li == 0) ? roi_class : rpn_class;
        float* outp = out + 184 + li;

        s16x8 bj[2], dj[2];
        int cj[2];
#pragma unroll
        for (int jt = 0; jt < 2; ++jt) {
            const int j = j0 + jt * 16;
            bj[jt] = *(const s16x8*)&Ab[(size_t)(j + fr) * 32 + fq * 8];
            if (is_cls) cj[jt] = cls[j + fr];
            else        dj[jt] = *(const s16x8*)&Db[(size_t)(j + fr) * 32 + fq * 8];
        }

        float Sx[2] = {}, W2s[2] = {}, U[2] = {};
        const int kbase0 = w * 1024;
        const f32x4 zc = {0.f, 0.f, 0.f, 0.f};

        for (int ch = 0; ch < 64; ++ch) {
            const int kb = kbase0 + ch * 16;
            const s16x8 afr = *(const s16x8*)&Ab[(size_t)(kb + fr) * 32 + fq * 8];
            if (is_cls) {
                const int4 ck = *(const int4*)&cls[kb + fq * 4];
                const int ckr[4] = {ck.x, ck.y, ck.z, ck.w};
#pragma unroll
                for (int jt = 0; jt < 2; ++jt) {
                    const f32x4 g = __builtin_amdgcn_mfma_f32_16x16x32_bf16(afr, bj[jt], zc, 0, 0, 0);
#pragma unroll
                    for (int r = 0; r < 4; ++r) {
                        const float gv = g[r];
                        Sx[jt] += __expf(2.f * gv);
                        const float wgt = (ckr[r] == cj[jt]) ? E2 : 1.0f;
                        U[jt] = fmaf(wgt, gv, U[jt]);
                        W2s[jt] += wgt;
                    }
                }
            } else {
                const s16x8 dfr = *(const s16x8*)&Db[(size_t)(kb + fr) * 32 + fq * 8];
#pragma unroll
                for (int jt = 0; jt < 2; ++jt) {
                    const f32x4 g  = __builtin_amdgcn_mfma_f32_16x16x32_bf16(afr, bj[jt], zc, 0, 0, 0);
                    const f32x4 gd = __builtin_amdgcn_mfma_f32_16x16x32_bf16(dfr, dj[jt], zc, 0, 0, 0);
#pragma unroll
                    for (int r = 0; r < 4; ++r) {
                        const float gv = g[r];
                        const float ed = __expf(2.f * gd[r]);
                        Sx[jt] += __expf(2.f * gv);
                        W2s[jt] += ed;
                        U[jt] = fmaf(ed, gv, U[jt]);
                    }
                }
            }
        }

#pragma unroll
        for (int jt = 0; jt < 2; ++jt) {
            float vx = Sx[jt], vg = W2s[jt], vu = U[jt];
            for (int off = 16; off <= 32; off <<= 1) {
                vx += __shfl_xor(vx, off, 64);
                vg += __shfl_xor(vg, off, 64);
                vu += __shfl_xor(vu, off, 64);
            }
            if (fq == 0) {
                sh[w][jt][fr][0] = vx; sh[w][jt][fr][1] = vg; sh[w][jt][fr][2] = vu;
            }
        }
        __syncthreads();
        if (t < 32) {
            const int jt = t >> 4, jl = t & 15;
            float vx = 0.f, vg = 0.f, vu = 0.f;
#pragma unroll
            for (int wv = 0; wv < 4; ++wv) {
                vx += sh[wv][jt][jl][0]; vg += sh[wv][jt][jl][1]; vu += sh[wv][jt][jl][2];
            }
            lsum[t] = (2.f * vu - __logf(vx + NEPS) * vg) / (vg + NEPS);
        }
        __syncthreads();
        if (t == 0) {
            float s = 0.f;
            for (int i = 0; i < 32; ++i) s += lsum[i];
            atomicAdd(outp, -s / 4096.f);
        }
    } else if (b < 515) {
        __shared__ float S4[4][8];
        const float* A = (b == 512) ? A_rpn_c : (b == 513) ? A_rpn_b : A_roi_b;
        const int off0 = (b == 512) ? 0 : (b == 513) ? 8 : 176;
        float acc[8] = {};
        for (int r = t; r < NPTS; r += 256) {
            const float4 v0 = *(const float4*)&A[(size_t)r * 8];
            const float4 v1 = *(const float4*)&A[(size_t)r * 8 + 4];
            acc[0]+=v0.x; acc[1]+=v0.y; acc[2]+=v0.z; acc[3]+=v0.w;
            acc[4]+=v1.x; acc[5]+=v1.y; acc[6]+=v1.z; acc[7]+=v1.w;
        }
#pragma unroll
        for (int o = 0; o < 8; ++o) {
            float v = acc[o];
            for (int offs = 32; offs; offs >>= 1) v += __shfl_xor(v, offs, 64);
            if (l == 0) S4[w][o] = v;
        }
        __syncthreads();
        if (t < 8) {
            const float s = S4[0][t] + S4[1][t] + S4[2][t] + S4[3][t];
            out[off0 + t] = s * (1.f / 4096.f);
        }
    } else {
        __shared__ float S[20][8];
        __shared__ float cnt[20];
        if (t < 160) ((float*)S)[t] = 0.f;
        if (t < 20) cnt[t] = 0.f;
        __syncthreads();
        for (int r = t; r < NPTS; r += 256) {
            const int c = roi_class[r];
            atomicAdd(&cnt[c], 1.0f);
            const float4 v0 = *(const float4*)&A_roi_c[(size_t)r * 8];
            const float4 v1 = *(const float4*)&A_roi_c[(size_t)r * 8 + 4];
            atomicAdd(&S[c][0], v0.x); atomicAdd(&S[c][1], v0.y);
            atomicAdd(&S[c][2], v0.z); atomicAdd(&S[c][3], v0.w);
            atomicAdd(&S[c][4], v1.x); atomicAdd(&S[c][5], v1.y);
            atomicAdd(&S[c][6], v1.z); atomicAdd(&S[c][7], v1.w);
        }
        __syncthreads();
        if (t < 160) {
            const int c = t >> 3;
            out[16 + t] = S[c][t & 7] / fmaxf(cnt[c], 1.f);
        }
    }
}

// ---------------------------------------------------------------------------
extern "C" void kernel_launch(void* const* d_in, const int* in_sizes, int n_in,
                              void* d_out, int out_size, void* d_ws, size_t ws_size,
                              hipStream_t stream)
{
    const float* rpn_feat  = (const float*)d_in[0];
    const float* rpn_del   = (const float*)d_in[1];
    const float* rpn_scale = (const float*)d_in[2];
    const float* roi_feat  = (const float*)d_in[3];
    const float* roi_del   = (const float*)d_in[4];
    const float* roi_scale = (const float*)d_in[5];
    const int*   rpn_class = (const int*)d_in[6];
    const int*   roi_class = (const int*)d_in[7];
    const float* W_rpn_feat = (const float*)d_in[8];  const float* b_rpn_feat = (const float*)d_in[9];
    const float* W_rpn_del  = (const float*)d_in[10]; const float* b_rpn_del  = (const float*)d_in[11];
    const float* W_rpn_sc   = (const float*)d_in[12]; const float* b_rpn_sc   = (const float*)d_in[13];
    const float* W_roi_feat = (const float*)d_in[14]; const float* b_roi_feat = (const float*)d_in[15];
    const float* W_roi_del  = (const float*)d_in[16]; const float* b_roi_del  = (const float*)d_in[17];
    const float* W_roi_sc   = (const float*)d_in[18]; const float* b_roi_sc   = (const float*)d_in[19];
    const float* rpn_cls_W1  = (const float*)d_in[20]; const float* rpn_cls_b1  = (const float*)d_in[21];
    const float* rpn_cls_W2  = (const float*)d_in[22]; const float* rpn_cls_b2  = (const float*)d_in[23];
    const float* rpn_bbox_W1 = (const float*)d_in[24]; const float* rpn_bbox_b1 = (const float*)d_in[25];
    const float* rpn_bbox_W2 = (const float*)d_in[26]; const float* rpn_bbox_b2 = (const float*)d_in[27];
    const float* roi_cls_W1  = (const float*)d_in[28]; const float* roi_cls_b1  = (const float*)d_in[29];
    const float* roi_cls_W2  = (const float*)d_in[30]; const float* roi_cls_b2  = (const float*)d_in[31];
    const int* iter_ptr = (const int*)d_in[32];
    float* out = (float*)d_out;
    char*  wsb = (char*)d_ws;

    // ---- workspace layout (byte offsets; sizes unchanged, layouts fragment-order) ----
    unsigned short* roi_feat_sw   = (unsigned short*)(wsb + 0);          // 4096x1024
    unsigned short* Ab_all        = (unsigned short*)(wsb + 0);          // 4 x 4096x32 (launch 4+)
    unsigned short* W_roi_feat_sw = (unsigned short*)(wsb + 8388608);    // 2048x1024
    unsigned short* roi_sum_sw    = (unsigned short*)(wsb + 12582912);   // 4096x2048
    unsigned short* roi_W1_sw     = (unsigned short*)(wsb + 29360128);   // 256x1024
    unsigned short* h_roi_c       = (unsigned short*)(wsb + 29884416);   // 4096x256 linear
    unsigned short* h_roi_b       = (unsigned short*)(wsb + 31981568);   // 4096x256 linear
    unsigned short* rpn_feat_sw   = (unsigned short*)(wsb + 34078720);   // 4096x256
    unsigned short* W_rpn_feat_sw = (unsigned short*)(wsb + 36175872);   // 512x256
    unsigned short* rpn_sum_sw    = (unsigned short*)(wsb + 36438016);   // 4096x512
    unsigned short* rpn_cW1_sw    = (unsigned short*)(wsb + 40632320);   // 128x256 padded
    unsigned short* rpn_bW1_sw    = (unsigned short*)(wsb + 40697856);   // 128x256 padded
    unsigned short* h_rpn_c       = (unsigned short*)(wsb + 40763392);   // 4096x128 linear
    unsigned short* h_rpn_b       = (unsigned short*)(wsb + 41811968);   // 4096x128 linear
    float* bias_pad_c = (float*)(wsb + 42860544);                        // 128
    float* bias_pad_b = (float*)(wsb + 42861056);                        // 128
    float* A_rpn_c    = (float*)(wsb + 42861568);                        // 4096x8
    float* A_rpn_b    = (float*)(wsb + 42992640);
    float* A_roi_c    = (float*)(wsb + 43123712);
    float* A_roi_b    = (float*)(wsb + 43254784);
    unsigned short* Db_roi = (unsigned short*)(wsb + 43385856);          // 4096x32
    unsigned short* Db_rpn = (unsigned short*)(wsb + 43648000);          // 4096x32

    // ---- 1: prep ----
    prep_kernel<<<dim3(3841), 256, 0, stream>>>(
        roi_feat, W_roi_feat, roi_cls_W1, rpn_feat, W_rpn_feat,
        rpn_cls_W1, rpn_bbox_W1, rpn_cls_b1, rpn_bbox_b1,
        roi_del, rpn_del,
        roi_feat_sw, W_roi_feat_sw, roi_W1_sw, rpn_feat_sw, W_rpn_feat_sw,
        rpn_cW1_sw, rpn_bW1_sw, Db_roi, Db_rpn, bias_pad_c, bias_pad_b, out);

    // ---- 2: both big GEMMs (extras fused; C fragment-order) ----
    {
        GemmJobs js;
        js.n = 2;
        js.j[0] = { rpn_feat_sw, W_rpn_feat_sw, rpn_sum_sw, b_rpn_feat,
                    rpn_del, W_rpn_del, b_rpn_del, rpn_scale, W_rpn_sc, b_rpn_sc,
                    131072, 16384, 256, 0, 256, 4, 0 };
        js.j[1] = { roi_feat_sw, W_roi_feat_sw, roi_sum_sw, b_roi_feat,
                    roi_del, W_roi_del, b_roi_del, roi_scale, W_roi_sc, b_roi_sc,
                    131072, 65536, 256, 0, 1024, 16, 128 };
        js.j[2] = js.j[0]; js.j[3] = js.j[0];
        gemm_reg<true, true, false><<<dim3(640), 256, 0, stream>>>(js);
    }

    // ---- 3: all 4 hidden GEMMs (relu fused; C linear) ----
    {
        GemmJobs js;
        js.n = 4;
        js.j[0] = { rpn_sum_sw,           rpn_cW1_sw, h_rpn_c, bias_pad_c,
                    nullptr, nullptr, nullptr, nullptr, nullptr, nullptr,
                    131072, 4096, 0, 128, 256, 1, 0 };
        js.j[1] = { rpn_sum_sw + 1048576, rpn_bW1_sw, h_rpn_b, bias_pad_b,
                    nullptr, nullptr, nullptr, nullptr, nullptr, nullptr,
                    131072, 4096, 0, 128, 256, 1, 32 };
        js.j[2] = { roi_sum_sw,           roi_W1_sw, h_roi_c, roi_cls_b1,
                    nullptr, nullptr, nullptr, nullptr, nullptr, nullptr,
                    131072, 8192, 0, 256, 1024, 2, 64 };
        // reference bug: bbox half also uses roi_cls W1/b1 (and W2/b2 below)
        js.j[3] = { roi_sum_sw + 4194304, roi_W1_sw, h_roi_b, roi_cls_b1,
                    nullptr, nullptr, nullptr, nullptr, nullptr, nullptr,
                    131072, 8192, 0, 256, 1024, 2, 128 };
        gemm_reg<false, false, true><<<dim3(192), 256, 0, stream>>>(js);
    }

    // ---- 4: all 4 alphas (f32 + padded bf16) ----
    alphas_all<<<dim3(4096), 256, 0, stream>>>(
        h_rpn_c, h_rpn_b, h_roi_c, h_roi_b,
        rpn_cls_W2, rpn_bbox_W2, roi_cls_W2,
        rpn_cls_b2, rpn_bbox_b2, roi_cls_b2,
        iter_ptr, A_rpn_c, A_rpn_b, A_roi_c, A_roi_b, Ab_all);

    // ---- 5: MFMA losses + means ----
    finale_kernel<<<dim3(516), 256, 0, stream>>>(
        Ab_all, Db_roi, Db_rpn,
        A_roi_c, A_rpn_c, A_roi_b, A_rpn_b,
        roi_class, rpn_class, out);
}

// Round 9
// 132.023 us; speedup vs baseline: 4.8331x; 1.1351x over previous
//
#include <hip/hip_runtime.h>
#include <math.h>

#define NPTS 4096
#define NEPS 4.096e-4f                 // 4096 * 1e-7
#define E2   7.3890560989306495f       // exp(2)

typedef float  f32x4 __attribute__((ext_vector_type(4)));
typedef short  s16x8 __attribute__((ext_vector_type(8)));

static __device__ __forceinline__ unsigned short f2b(float x) {
    unsigned u = __builtin_bit_cast(unsigned, x);
    return (unsigned short)((u + 0x7fffu + ((u >> 16) & 1u)) >> 16);
}
static __device__ __forceinline__ float b2f(unsigned short h) {
    return __builtin_bit_cast(float, (unsigned)h << 16);
}

// fragment-order (swizzled) element offset for element (r,c) of an R-row matrix:
// subtile (r/16, c/32) is 512 contiguous elements (kj-major, si-minor);
// chunk l = (r%16) + ((c%32)/8)*16 holds cols ((c%32)&~7)..+8 of row r%16.
static __device__ __forceinline__ size_t swz(int r, int c, int R16) {
    return (((size_t)((c >> 5) * R16 + (r >> 4))) << 9)
         + ((size_t)((r & 15) + (((c & 31) >> 3) << 4)) << 3) + (c & 7);
}

// ---------------------------------------------------------------------------
// prep: f32 -> bf16 fragment-order converts + rpn W1 pads + bias + deltas + zero
// ---------------------------------------------------------------------------
__global__ __launch_bounds__(256) void prep_kernel(
    const float* __restrict__ roi_feat, const float* __restrict__ W_roi_feat,
    const float* __restrict__ roi_cls_W1,
    const float* __restrict__ rpn_feat, const float* __restrict__ W_rpn_feat,
    const float* __restrict__ rpn_cls_W1, const float* __restrict__ rpn_bbox_W1,
    const float* __restrict__ rpn_cls_b1, const float* __restrict__ rpn_bbox_b1,
    const float* __restrict__ roi_del, const float* __restrict__ rpn_del,
    unsigned short* __restrict__ roi_feat_sw, unsigned short* __restrict__ W_roi_feat_sw,
    unsigned short* __restrict__ roi_W1_sw,
    unsigned short* __restrict__ rpn_feat_sw, unsigned short* __restrict__ W_rpn_feat_sw,
    unsigned short* __restrict__ rpn_cW1_sw, unsigned short* __restrict__ rpn_bW1_sw,
    unsigned short* __restrict__ Db_roi, unsigned short* __restrict__ Db_rpn,
    float* __restrict__ bias_pad_c, float* __restrict__ bias_pad_b,
    float* __restrict__ out)
{
    const int b = blockIdx.x, t = threadIdx.x;
    if (b < 3776) {
        const float* in; unsigned short* o; int base, cshift, R16;
        if      (b < 2048) { in = roi_feat;   o = roi_feat_sw;   base = b;        cshift = 10; R16 = 256; }
        else if (b < 3072) { in = W_roi_feat; o = W_roi_feat_sw; base = b - 2048; cshift = 10; R16 = 128; }
        else if (b < 3200) { in = roi_cls_W1; o = roi_W1_sw;     base = b - 3072; cshift = 10; R16 = 16;  }
        else if (b < 3712) { in = rpn_feat;   o = rpn_feat_sw;   base = b - 3200; cshift = 8;  R16 = 256; }
        else               { in = W_rpn_feat; o = W_rpn_feat_sw; base = b - 3712; cshift = 8;  R16 = 32;  }
        const int i = base * 2048 + t * 8;
        const int r = i >> cshift, c = i & ((1 << cshift) - 1);
        const float4 v0 = *(const float4*)&in[i];
        const float4 v1 = *(const float4*)&in[i + 4];
        s16x8 pk;
        pk[0] = (short)f2b(v0.x); pk[1] = (short)f2b(v0.y);
        pk[2] = (short)f2b(v0.z); pk[3] = (short)f2b(v0.w);
        pk[4] = (short)f2b(v1.x); pk[5] = (short)f2b(v1.y);
        pk[6] = (short)f2b(v1.z); pk[7] = (short)f2b(v1.w);
        *(s16x8*)(o + swz(r, c, R16)) = pk;
    } else if (b < 3808) {
        const bool cls = b < 3792;
        const float* W = cls ? rpn_cls_W1 : rpn_bbox_W1;
        unsigned short* o = cls ? rpn_cW1_sw : rpn_bW1_sw;
        const int local = b - (cls ? 3776 : 3792);
        const int i = local * 2048 + t * 8;
        const int r = i >> 8, c = i & 255;
        s16x8 pk;
#pragma unroll
        for (int u = 0; u < 8; ++u)
            pk[u] = (r < 64) ? (short)f2b(W[r * 256 + c + u]) : (short)0;
        *(s16x8*)(o + swz(r, c, 8)) = pk;
    } else if (b == 3808) {
        if (t < 128)      bias_pad_c[t] = (t < 64) ? rpn_cls_b1[t] : 0.f;
        else              bias_pad_b[t - 128] = ((t - 128) < 64) ? rpn_bbox_b1[t - 128] : 0.f;
        if (t < 4) out[184 + t] = 0.f;
    } else {
        const int row = (b - 3809) * 256 + t;
        const int mat = row >> 12, r = row & 4095;
        const float* D = mat ? rpn_del : roi_del;
        unsigned short* o = mat ? Db_rpn : Db_roi;
        const float4 dv = *(const float4*)&D[(size_t)r * 4];
        ushort4 d4; d4.x = f2b(dv.x); d4.y = f2b(dv.y); d4.z = f2b(dv.z); d4.w = f2b(dv.w);
        unsigned short* p = o + (size_t)r * 32;
        ushort4 z4 = {0, 0, 0, 0};
        *(ushort4*)p = d4;
        *(ushort4*)(p + 4)  = z4;
        *(ushort4*)(p + 8)  = z4; *(ushort4*)(p + 12) = z4;
        *(ushort4*)(p + 16) = z4; *(ushort4*)(p + 20) = z4;
        *(ushort4*)(p + 24) = z4; *(ushort4*)(p + 28) = z4;
    }
}

// ---------------------------------------------------------------------------
// Register-direct MFMA GEMM, depth-4 pipeline: no LDS, no barriers. Four named
// operand buffer sets; a load set is issued 48 MFMAs (~230+ cyc) before use,
// covering L2 latency at 2 waves/SIMD. All buffer indexing is static (rule #20).
// ---------------------------------------------------------------------------
struct GemmJob {
    const unsigned short *A, *W;
    unsigned short *C;
    const float *bias;
    const float *del, *Wd, *bd, *sc, *Wsc, *bs;
    int strideA, strideB;   // elements per K-step (= R16*512)
    int M16;                // C fragment-order rows/16 (CSWZ)
    int ldc;                // C linear stride (!CSWZ)
    int K, nbx, bstart;
};
struct GemmJobs { GemmJob j[4]; int n; };

#define LDSET(Av, Bv)                                          \
    {                                                          \
        _Pragma("unroll")                                      \
        for (int m = 0; m < 4; ++m) {                          \
            Av[m] = *(const s16x8*)(pa + (m << 9));            \
            Bv[m] = *(const s16x8*)(pb + (m << 9));            \
        }                                                      \
        pa += jb.strideA; pb += jb.strideB;                    \
    }

#define MMSET(Av, Bv)                                          \
    {                                                          \
        _Pragma("unroll")                                      \
        for (int m = 0; m < 4; ++m)                            \
            _Pragma("unroll")                                  \
            for (int n = 0; n < 4; ++n)                        \
                acc[m][n] = __builtin_amdgcn_mfma_f32_16x16x32_bf16( \
                    Av[m], Bv[n], acc[m][n], 0, 0, 0);         \
    }

template<bool EXTRAS, bool CSWZ, bool RELU>
__global__ __launch_bounds__(256) void gemm_reg(GemmJobs jobs)
{
    const int bid = blockIdx.x;
    int ji = 0;
#pragma unroll
    for (int i = 1; i < 4; ++i)
        if (i < jobs.n && bid >= jobs.j[i].bstart) ji = i;
    const GemmJob jb = jobs.j[ji];
    int local = bid - jb.bstart;
    const int nb = jb.nbx << 5;
    local = (local & 7) * (nb >> 3) + (local >> 3);   // XCD-contiguous chunks
    const int bx = local % jb.nbx, by = local / jb.nbx;

    const int t = threadIdx.x, l = t & 63, w = t >> 6;
    const int wr = w >> 1, wc = w & 1;
    const int fr = l & 15, fq = l >> 4;

    const int sA0 = by * 8 + wr * 4;
    const int sB0 = bx * 8 + wc * 4;
    const unsigned short* pa = jb.A + ((size_t)sA0 << 9) + (size_t)(l * 8);
    const unsigned short* pb = jb.W + ((size_t)sB0 << 9) + (size_t)(l * 8);

    f32x4 acc[4][4] = {};
    s16x8 A0[4], B0[4], A1[4], B1[4], A2[4], B2[4], A3[4], B3[4];

    const int niter = jb.K >> 5;   // 8 or 32 (divisible by 4)
    LDSET(A0, B0);
    LDSET(A1, B1);
    LDSET(A2, B2);

    for (int it = 0; it < niter; it += 4) {
        if (it + 3 < niter) LDSET(A3, B3);
        MMSET(A0, B0);
        if (it + 4 < niter) LDSET(A0, B0);
        MMSET(A1, B1);
        if (it + 5 < niter) LDSET(A1, B1);
        MMSET(A2, B2);
        if (it + 6 < niter) LDSET(A2, B2);
        MMSET(A3, B3);
    }

    // epilogue: lane holds C[row=(sA0+m)*16+fq*4+j][c=(sB0+n)*16+fr]
#pragma unroll
    for (int n = 0; n < 4; ++n) {
        const int c = (sB0 + n) * 16 + fr;
        float cadd = jb.bias[c];
        float wd0 = 0.f, wd1 = 0.f, wd2 = 0.f, wd3 = 0.f, wscv = 0.f;
        if (EXTRAS) {
            cadd += jb.bd[c] + jb.bs[c];
            const float4 w4 = *(const float4*)&jb.Wd[c * 4];
            wd0 = w4.x; wd1 = w4.y; wd2 = w4.z; wd3 = w4.w;
            wscv = jb.Wsc[c];
        }
#pragma unroll
        for (int m = 0; m < 4; ++m) {
            const int si = sA0 + m;
            unsigned short* cp;
            if (CSWZ) {
                const int kj = c >> 5;
                cp = jb.C + (((size_t)(kj * jb.M16 + si)) << 9)
                   + (((size_t)((c & 31) >> 3)) << 7) + (c & 7);
            }
#pragma unroll
            for (int j = 0; j < 4; ++j) {
                const int rr = fq * 4 + j;
                const int row = si * 16 + rr;
                float v = acc[m][n][j] + cadd;
                if (EXTRAS) {
                    const float4 dm = *(const float4*)&jb.del[row * 4];
                    v += dm.x * wd0 + dm.y * wd1 + dm.z * wd2 + dm.w * wd3
                       + jb.sc[row] * wscv;
                }
                if (RELU) v = fmaxf(v, 0.f);
                if (CSWZ) cp[(size_t)rr << 3] = f2b(v);
                else      jb.C[(size_t)row * jb.ldc + c] = f2b(v);
            }
        }
    }
}

// ---------------------------------------------------------------------------
// alphas for all 4 matrices; writes f32 A[4096][8] and bf16 Ab[mat][4096][32]
// ---------------------------------------------------------------------------
__global__ __launch_bounds__(256) void alphas_all(
    const unsigned short* __restrict__ h_rpn_c, const unsigned short* __restrict__ h_rpn_b,
    const unsigned short* __restrict__ h_roi_c, const unsigned short* __restrict__ h_roi_b,
    const float* __restrict__ W2_rc, const float* __restrict__ W2_rb,
    const float* __restrict__ W2_oc,
    const float* __restrict__ b2_rc, const float* __restrict__ b2_rb,
    const float* __restrict__ b2_oc,
    const int* __restrict__ iter_ptr,
    float* __restrict__ A_rpn_c, float* __restrict__ A_rpn_b,
    float* __restrict__ A_roi_c, float* __restrict__ A_roi_b,
    unsigned short* __restrict__ Ab_all)
{
    const int vrow = blockIdx.x * 4 + (threadIdx.x >> 6);
    const int mat = vrow >> 12, row = vrow & 4095;
    const unsigned short* H; const float *W2, *b2; float* Ao; int ldh, Hd;
    if (mat == 0)      { H = h_rpn_c; W2 = W2_rc; b2 = b2_rc; Ao = A_rpn_c; ldh = 128; Hd = 64; }
    else if (mat == 1) { H = h_rpn_b; W2 = W2_rb; b2 = b2_rb; Ao = A_rpn_b; ldh = 128; Hd = 64; }
    else if (mat == 2) { H = h_roi_c; W2 = W2_oc; b2 = b2_oc; Ao = A_roi_c; ldh = 256; Hd = 256; }
    else               { H = h_roi_b; W2 = W2_oc; b2 = b2_oc; Ao = A_roi_b; ldh = 256; Hd = 256; }

    const int l = threadIdx.x & 63;
    float acc[8] = {};
    for (int m = l * 4; m < Hd; m += 256) {
        const ushort4 h4 = *(const ushort4*)&H[(size_t)row * ldh + m];
        const float h0 = b2f(h4.x), h1 = b2f(h4.y), h2 = b2f(h4.z), h3 = b2f(h4.w);
#pragma unroll
        for (int o = 0; o < 8; ++o) {
            const float4 w4 = *(const float4*)&W2[o * Hd + m];
            acc[o] += h0 * w4.x + h1 * w4.y + h2 * w4.z + h3 * w4.w;
        }
    }
#pragma unroll
    for (int o = 0; o < 8; ++o)
        for (int off = 32; off; off >>= 1)
            acc[o] += __shfl_xor(acc[o], off, 64);

    const int it = *iter_ptr;
    const float temp = fmaxf(1.0f, 30.0f * (float)(90000 - it) / 90000.0f);
    float lg[8], mx = -1e30f;
#pragma unroll
    for (int o = 0; o < 8; ++o) { lg[o] = (acc[o] + b2[o]) / temp; mx = fmaxf(mx, lg[o]); }
    float s = 0.f;
#pragma unroll
    for (int o = 0; o < 8; ++o) { lg[o] = __expf(lg[o] - mx); s += lg[o]; }
    const float inv = 1.0f / s;
    if (l < 8) Ao[(size_t)row * 8 + l] = lg[l] * inv;
    unsigned short* Ab = Ab_all + (size_t)mat * 131072 + (size_t)row * 32;
    if (l == 0) {
        ushort4 o0, o1;
        o0.x = f2b(lg[0]*inv); o0.y = f2b(lg[1]*inv); o0.z = f2b(lg[2]*inv); o0.w = f2b(lg[3]*inv);
        o1.x = f2b(lg[4]*inv); o1.y = f2b(lg[5]*inv); o1.z = f2b(lg[6]*inv); o1.w = f2b(lg[7]*inv);
        *(ushort4*)Ab = o0; *(ushort4*)(Ab + 4) = o1;
    } else if (l < 4) {
        ushort4 z = {0,0,0,0};
        *(ushort4*)(Ab + l * 8)     = z;
        *(ushort4*)(Ab + l * 8 + 4) = z;
    }
}

// ---------------------------------------------------------------------------
// finale: MFMA losses + means (unchanged)
// ---------------------------------------------------------------------------
__global__ __launch_bounds__(256) void finale_kernel(
    const unsigned short* __restrict__ Ab_all,
    const unsigned short* __restrict__ Db_roi, const unsigned short* __restrict__ Db_rpn,
    const float* __restrict__ A_roi_c, const float* __restrict__ A_rpn_c,
    const float* __restrict__ A_roi_b, const float* __restrict__ A_rpn_b,
    const int* __restrict__ roi_class, const int* __restrict__ rpn_class,
    float* __restrict__ out)
{
    const int b = blockIdx.x, t = threadIdx.x;
    const int w = t >> 6, l = t & 63;
    const int fr = l & 15, fq = l >> 4;

    if (b < 512) {
        __shared__ float sh[4][2][16][3];
        __shared__ float lsum[32];
        const bool is_cls = b < 256;
        const int li = b >> 7;
        const int blk = b & 127;
        const int j0 = blk * 32;
        const int mat = (li == 0) ? 2 : (li == 1) ? 0 : (li == 2) ? 3 : 1;
        const unsigned short* Ab = Ab_all + (size_t)mat * 131072;
        const unsigned short* Db = (li == 2) ? Db_roi : Db_rpn;
        const int* cls = (li == 0) ? roi_class : rpn_class;
        float* outp = out + 184 + li;

        s16x8 bj[2], dj[2];
        int cj[2];
#pragma unroll
        for (int jt = 0; jt < 2; ++jt) {
            const int j = j0 + jt * 16;
            bj[jt] = *(const s16x8*)&Ab[(size_t)(j + fr) * 32 + fq * 8];
            if (is_cls) cj[jt] = cls[j + fr];
            else        dj[jt] = *(const s16x8*)&Db[(size_t)(j + fr) * 32 + fq * 8];
        }

        float Sx[2] = {}, W2s[2] = {}, U[2] = {};
        const int kbase0 = w * 1024;
        const f32x4 zc = {0.f, 0.f, 0.f, 0.f};

        for (int ch = 0; ch < 64; ++ch) {
            const int kb = kbase0 + ch * 16;
            const s16x8 afr = *(const s16x8*)&Ab[(size_t)(kb + fr) * 32 + fq * 8];
            if (is_cls) {
                const int4 ck = *(const int4*)&cls[kb + fq * 4];
                const int ckr[4] = {ck.x, ck.y, ck.z, ck.w};
#pragma unroll
                for (int jt = 0; jt < 2; ++jt) {
                    const f32x4 g = __builtin_amdgcn_mfma_f32_16x16x32_bf16(afr, bj[jt], zc, 0, 0, 0);
#pragma unroll
                    for (int r = 0; r < 4; ++r) {
                        const float gv = g[r];
                        Sx[jt] += __expf(2.f * gv);
                        const float wgt = (ckr[r] == cj[jt]) ? E2 : 1.0f;
                        U[jt] = fmaf(wgt, gv, U[jt]);
                        W2s[jt] += wgt;
                    }
                }
            } else {
                const s16x8 dfr = *(const s16x8*)&Db[(size_t)(kb + fr) * 32 + fq * 8];
#pragma unroll
                for (int jt = 0; jt < 2; ++jt) {
                    const f32x4 g  = __builtin_amdgcn_mfma_f32_16x16x32_bf16(afr, bj[jt], zc, 0, 0, 0);
                    const f32x4 gd = __builtin_amdgcn_mfma_f32_16x16x32_bf16(dfr, dj[jt], zc, 0, 0, 0);
#pragma unroll
                    for (int r = 0; r < 4; ++r) {
                        const float gv = g[r];
                        const float ed = __expf(2.f * gd[r]);
                        Sx[jt] += __expf(2.f * gv);
                        W2s[jt] += ed;
                        U[jt] = fmaf(ed, gv, U[jt]);
                    }
                }
            }
        }

#pragma unroll
        for (int jt = 0; jt < 2; ++jt) {
            float vx = Sx[jt], vg = W2s[jt], vu = U[jt];
            for (int off = 16; off <= 32; off <<= 1) {
                vx += __shfl_xor(vx, off, 64);
                vg += __shfl_xor(vg, off, 64);
                vu += __shfl_xor(vu, off, 64);
            }
            if (fq == 0) {
                sh[w][jt][fr][0] = vx; sh[w][jt][fr][1] = vg; sh[w][jt][fr][2] = vu;
            }
        }
        __syncthreads();
        if (t < 32) {
            const int jt = t >> 4, jl = t & 15;
            float vx = 0.f, vg = 0.f, vu = 0.f;
#pragma unroll
            for (int wv = 0; wv < 4; ++wv) {
                vx += sh[wv][jt][jl][0]; vg += sh[wv][jt][jl][1]; vu += sh[wv][jt][jl][2];
            }
            lsum[t] = (2.f * vu - __logf(vx + NEPS) * vg) / (vg + NEPS);
        }
        __syncthreads();
        if (t == 0) {
            float s = 0.f;
            for (int i = 0; i < 32; ++i) s += lsum[i];
            atomicAdd(outp, -s / 4096.f);
        }
    } else if (b < 515) {
        __shared__ float S4[4][8];
        const float* A = (b == 512) ? A_rpn_c : (b == 513) ? A_rpn_b : A_roi_b;
        const int off0 = (b == 512) ? 0 : (b == 513) ? 8 : 176;
        float acc[8] = {};
        for (int r = t; r < NPTS; r += 256) {
            const float4 v0 = *(const float4*)&A[(size_t)r * 8];
            const float4 v1 = *(const float4*)&A[(size_t)r * 8 + 4];
            acc[0]+=v0.x; acc[1]+=v0.y; acc[2]+=v0.z; acc[3]+=v0.w;
            acc[4]+=v1.x; acc[5]+=v1.y; acc[6]+=v1.z; acc[7]+=v1.w;
        }
#pragma unroll
        for (int o = 0; o < 8; ++o) {
            float v = acc[o];
            for (int offs = 32; offs; offs >>= 1) v += __shfl_xor(v, offs, 64);
            if (l == 0) S4[w][o] = v;
        }
        __syncthreads();
        if (t < 8) {
            const float s = S4[0][t] + S4[1][t] + S4[2][t] + S4[3][t];
            out[off0 + t] = s * (1.f / 4096.f);
        }
    } else {
        __shared__ float S[20][8];
        __shared__ float cnt[20];
        if (t < 160) ((float*)S)[t] = 0.f;
        if (t < 20) cnt[t] = 0.f;
        __syncthreads();
        for (int r = t; r < NPTS; r += 256) {
            const int c = roi_class[r];
            atomicAdd(&cnt[c], 1.0f);
            const float4 v0 = *(const float4*)&A_roi_c[(size_t)r * 8];
            const float4 v1 = *(const float4*)&A_roi_c[(size_t)r * 8 + 4];
            atomicAdd(&S[c][0], v0.x); atomicAdd(&S[c][1], v0.y);
            atomicAdd(&S[c][2], v0.z); atomicAdd(&S[c][3], v0.w);
            atomicAdd(&S[c][4], v1.x); atomicAdd(&S[c][5], v1.y);
            atomicAdd(&S[c][6], v1.z); atomicAdd(&S[c][7], v1.w);
        }
        __syncthreads();
        if (t < 160) {
            const int c = t >> 3;
            out[16 + t] = S[c][t & 7] / fmaxf(cnt[c], 1.f);
        }
    }
}

// ---------------------------------------------------------------------------
extern "C" void kernel_launch(void* const* d_in, const int* in_sizes, int n_in,
                              void* d_out, int out_size, void* d_ws, size_t ws_size,
                              hipStream_t stream)
{
    const float* rpn_feat  = (const float*)d_in[0];
    const float* rpn_del   = (const float*)d_in[1];
    const float* rpn_scale = (const float*)d_in[2];
    const float* roi_feat  = (const float*)d_in[3];
    const float* roi_del   = (const float*)d_in[4];
    const float* roi_scale = (const float*)d_in[5];
    const int*   rpn_class = (const int*)d_in[6];
    const int*   roi_class = (const int*)d_in[7];
    const float* W_rpn_feat = (const float*)d_in[8];  const float* b_rpn_feat = (const float*)d_in[9];
    const float* W_rpn_del  = (const float*)d_in[10]; const float* b_rpn_del  = (const float*)d_in[11];
    const float* W_rpn_sc   = (const float*)d_in[12]; const float* b_rpn_sc   = (const float*)d_in[13];
    const float* W_roi_feat = (const float*)d_in[14]; const float* b_roi_feat = (const float*)d_in[15];
    const float* W_roi_del  = (const float*)d_in[16]; const float* b_roi_del  = (const float*)d_in[17];
    const float* W_roi_sc   = (const float*)d_in[18]; const float* b_roi_sc   = (const float*)d_in[19];
    const float* rpn_cls_W1  = (const float*)d_in[20]; const float* rpn_cls_b1  = (const float*)d_in[21];
    const float* rpn_cls_W2  = (const float*)d_in[22]; const float* rpn_cls_b2  = (const float*)d_in[23];
    const float* rpn_bbox_W1 = (const float*)d_in[24]; const float* rpn_bbox_b1 = (const float*)d_in[25];
    const float* rpn_bbox_W2 = (const float*)d_in[26]; const float* rpn_bbox_b2 = (const float*)d_in[27];
    const float* roi_cls_W1  = (const float*)d_in[28]; const float* roi_cls_b1  = (const float*)d_in[29];
    const float* roi_cls_W2  = (const float*)d_in[30]; const float* roi_cls_b2  = (const float*)d_in[31];
    const int* iter_ptr = (const int*)d_in[32];
    float* out = (float*)d_out;
    char*  wsb = (char*)d_ws;

    // ---- workspace layout (byte offsets; layouts fragment-order) ----
    unsigned short* roi_feat_sw   = (unsigned short*)(wsb + 0);          // 4096x1024
    unsigned short* Ab_all        = (unsigned short*)(wsb + 0);          // 4 x 4096x32 (launch 4+)
    unsigned short* W_roi_feat_sw = (unsigned short*)(wsb + 8388608);    // 2048x1024
    unsigned short* roi_sum_sw    = (unsigned short*)(wsb + 12582912);   // 4096x2048
    unsigned short* roi_W1_sw     = (unsigned short*)(wsb + 29360128);   // 256x1024
    unsigned short* h_roi_c       = (unsigned short*)(wsb + 29884416);   // 4096x256 linear
    unsigned short* h_roi_b       = (unsigned short*)(wsb + 31981568);   // 4096x256 linear
    unsigned short* rpn_feat_sw   = (unsigned short*)(wsb + 34078720);   // 4096x256
    unsigned short* W_rpn_feat_sw = (unsigned short*)(wsb + 36175872);   // 512x256
    unsigned short* rpn_sum_sw    = (unsigned short*)(wsb + 36438016);   // 4096x512
    unsigned short* rpn_cW1_sw    = (unsigned short*)(wsb + 40632320);   // 128x256 padded
    unsigned short* rpn_bW1_sw    = (unsigned short*)(wsb + 40697856);   // 128x256 padded
    unsigned short* h_rpn_c       = (unsigned short*)(wsb + 40763392);   // 4096x128 linear
    unsigned short* h_rpn_b       = (unsigned short*)(wsb + 41811968);   // 4096x128 linear
    float* bias_pad_c = (float*)(wsb + 42860544);                        // 128
    float* bias_pad_b = (float*)(wsb + 42861056);                        // 128
    float* A_rpn_c    = (float*)(wsb + 42861568);                        // 4096x8
    float* A_rpn_b    = (float*)(wsb + 42992640);
    float* A_roi_c    = (float*)(wsb + 43123712);
    float* A_roi_b    = (float*)(wsb + 43254784);
    unsigned short* Db_roi = (unsigned short*)(wsb + 43385856);          // 4096x32
    unsigned short* Db_rpn = (unsigned short*)(wsb + 43648000);          // 4096x32

    // ---- 1: prep ----
    prep_kernel<<<dim3(3841), 256, 0, stream>>>(
        roi_feat, W_roi_feat, roi_cls_W1, rpn_feat, W_rpn_feat,
        rpn_cls_W1, rpn_bbox_W1, rpn_cls_b1, rpn_bbox_b1,
        roi_del, rpn_del,
        roi_feat_sw, W_roi_feat_sw, roi_W1_sw, rpn_feat_sw, W_rpn_feat_sw,
        rpn_cW1_sw, rpn_bW1_sw, Db_roi, Db_rpn, bias_pad_c, bias_pad_b, out);

    // ---- 2: both big GEMMs (extras fused; C fragment-order) ----
    {
        GemmJobs js;
        js.n = 2;
        js.j[0] = { rpn_feat_sw, W_rpn_feat_sw, rpn_sum_sw, b_rpn_feat,
                    rpn_del, W_rpn_del, b_rpn_del, rpn_scale, W_rpn_sc, b_rpn_sc,
                    131072, 16384, 256, 0, 256, 4, 0 };
        js.j[1] = { roi_feat_sw, W_roi_feat_sw, roi_sum_sw, b_roi_feat,
                    roi_del, W_roi_del, b_roi_del, roi_scale, W_roi_sc, b_roi_sc,
                    131072, 65536, 256, 0, 1024, 16, 128 };
        js.j[2] = js.j[0]; js.j[3] = js.j[0];
        gemm_reg<true, true, false><<<dim3(640), 256, 0, stream>>>(js);
    }

    // ---- 3: all 4 hidden GEMMs (relu fused; C linear) ----
    {
        GemmJobs js;
        js.n = 4;
        js.j[0] = { rpn_sum_sw,           rpn_cW1_sw, h_rpn_c, bias_pad_c,
                    nullptr, nullptr, nullptr, nullptr, nullptr, nullptr,
                    131072, 4096, 0, 128, 256, 1, 0 };
        js.j[1] = { rpn_sum_sw + 1048576, rpn_bW1_sw, h_rpn_b, bias_pad_b,
                    nullptr, nullptr, nullptr, nullptr, nullptr, nullptr,
                    131072, 4096, 0, 128, 256, 1, 32 };
        js.j[2] = { roi_sum_sw,           roi_W1_sw, h_roi_c, roi_cls_b1,
                    nullptr, nullptr, nullptr, nullptr, nullptr, nullptr,
                    131072, 8192, 0, 256, 1024, 2, 64 };
        // reference bug: bbox half also uses roi_cls W1/b1 (and W2/b2 below)
        js.j[3] = { roi_sum_sw + 4194304, roi_W1_sw, h_roi_b, roi_cls_b1,
                    nullptr, nullptr, nullptr, nullptr, nullptr, nullptr,
                    131072, 8192, 0, 256, 1024, 2, 128 };
        gemm_reg<false, false, true><<<dim3(192), 256, 0, stream>>>(js);
    }

    // ---- 4: all 4 alphas (f32 + padded bf16) ----
    alphas_all<<<dim3(4096), 256, 0, stream>>>(
        h_rpn_c, h_rpn_b, h_roi_c, h_roi_b,
        rpn_cls_W2, rpn_bbox_W2, roi_cls_W2,
        rpn_cls_b2, rpn_bbox_b2, roi_cls_b2,
        iter_ptr, A_rpn_c, A_rpn_b, A_roi_c, A_roi_b, Ab_all);

    // ---- 5: MFMA losses + means ----
    finale_kernel<<<dim3(516), 256, 0, stream>>>(
        Ab_all, Db_roi, Db_rpn,
        A_roi_c, A_rpn_c, A_roi_b, A_rpn_b,
        roi_class, rpn_class, out);
}